// Round 7
// baseline (794.763 us; speedup 1.0000x reference)
//
#include <hip/hip_runtime.h>
#include <math.h>

#define NB 8
#define NT1 2048
#define NT2 512
#define NC 384
#define ND 192
#define NF 1536
#define NKI 3456   // 9*384 implicit-GEMM K for conv
#define TPAD 2056  // 2048 + 4 guard rows top and bottom

typedef __attribute__((ext_vector_type(8))) short bf16x8;
typedef __attribute__((ext_vector_type(4))) float f32x4;

#define GLOAD16(gsrc, ldst) \
  __builtin_amdgcn_global_load_lds((const __attribute__((address_space(1))) void*)(gsrc), \
                                   (__attribute__((address_space(3))) void*)(ldst), 16, 0, 0)

static __device__ __forceinline__ unsigned short f2bf(float f) {
  unsigned int u = __float_as_uint(f);
  unsigned int r = (u + 0x7fffu + ((u >> 16) & 1u)) >> 16;
  return (unsigned short)r;
}

static __device__ __forceinline__ float warp_sum(float v) {
#pragma unroll
  for (int off = 32; off > 0; off >>= 1) v += __shfl_xor(v, off);
  return v;
}

// x += alpha * sin-pos; thread handles (t,j) pair: sin at c=j, cos at c=j+192
__global__ __launch_bounds__(256) void k_add_pos2(const float* __restrict__ x,
    const float* __restrict__ alpha_p, float* __restrict__ y, int T, int total2) {
  int i = blockIdx.x * 256 + threadIdx.x;
  if (i >= total2) return;
  int j = i % 192;
  int row = i / 192;
  int t = row % T;
  float freq = __expf(-0.0482216773f * (float)j);   // ln(10000)/191
  float ang = (float)(t + 1) * freq;
  float sn, cs;
  __sincosf(ang, &sn, &cs);
  float a = alpha_p[0];
  size_t base = (size_t)row * NC;
  y[base + j] = x[base + j] + a * sn;
  y[base + j + 192] = x[base + j + 192] + a * cs;
}

__global__ __launch_bounds__(256) void k_add_pos2_bf16(const float* __restrict__ x,
    const float* __restrict__ alpha_p, unsigned short* __restrict__ y, int T, int total2) {
  int i = blockIdx.x * 256 + threadIdx.x;
  if (i >= total2) return;
  int j = i % 192;
  int row = i / 192;
  int t = row % T;
  float freq = __expf(-0.0482216773f * (float)j);
  float ang = (float)(t + 1) * freq;
  float sn, cs;
  __sincosf(ang, &sn, &cs);
  float a = alpha_p[0];
  size_t base = (size_t)row * NC;
  y[base + j] = f2bf(x[base + j] + a * sn);
  y[base + j + 192] = f2bf(x[base + j + 192] + a * cs);
}

// LayerNorm over last dim (384). One wave per row. fp32 out (final LN).
__global__ __launch_bounds__(256) void k_ln(const float* __restrict__ x,
    const float* __restrict__ g, const float* __restrict__ b,
    float* __restrict__ y, int nrows) {
  int row = blockIdx.x * 4 + (threadIdx.x >> 6);
  int lane = threadIdx.x & 63;
  if (row >= nrows) return;
  const float* xr = x + (size_t)row * NC;
  float v[6];
  float s = 0.f, s2 = 0.f;
#pragma unroll
  for (int i = 0; i < 6; ++i) {
    float t = xr[lane + 64 * i];
    v[i] = t; s += t; s2 += t * t;
  }
  s = warp_sum(s); s2 = warp_sum(s2);
  float mean = s * (1.f / NC);
  float var = s2 * (1.f / NC) - mean * mean;
  float rs = rsqrtf(var + 1e-5f);
  float* yr = y + (size_t)row * NC;
#pragma unroll
  for (int i = 0; i < 6; ++i) {
    int cc = lane + 64 * i;
    yr[cc] = (v[i] - mean) * rs * g[cc] + b[cc];
  }
}

// LayerNorm -> bf16 (unpadded), feeds MFMA projections
__global__ __launch_bounds__(256) void k_ln_bf16(const float* __restrict__ x,
    const float* __restrict__ g, const float* __restrict__ b,
    unsigned short* __restrict__ y) {
  int row = blockIdx.x * 4 + (threadIdx.x >> 6);
  int lane = threadIdx.x & 63;
  const float* xr = x + (size_t)row * NC;
  float v[6];
  float s = 0.f, s2 = 0.f;
#pragma unroll
  for (int i = 0; i < 6; ++i) {
    float t = xr[lane + 64 * i];
    v[i] = t; s += t; s2 += t * t;
  }
  s = warp_sum(s); s2 = warp_sum(s2);
  float mean = s * (1.f / NC);
  float var = s2 * (1.f / NC) - mean * mean;
  float rs = rsqrtf(var + 1e-5f);
  unsigned short* yr = y + (size_t)row * NC;
#pragma unroll
  for (int i = 0; i < 6; ++i) {
    int cc = lane + 64 * i;
    yr[cc] = f2bf((v[i] - mean) * rs * g[cc] + b[cc]);
  }
}

// LayerNorm -> bf16 into guard-padded [8][2056][384] buffer (row t -> t+4)
__global__ __launch_bounds__(256) void k_ln_bf16p(const float* __restrict__ x,
    const float* __restrict__ g, const float* __restrict__ b,
    unsigned short* __restrict__ ypad) {
  int row = blockIdx.x * 4 + (threadIdx.x >> 6);
  int lane = threadIdx.x & 63;
  const float* xr = x + (size_t)row * NC;
  float v[6];
  float s = 0.f, s2 = 0.f;
#pragma unroll
  for (int i = 0; i < 6; ++i) {
    float t = xr[lane + 64 * i];
    v[i] = t; s += t; s2 += t * t;
  }
  s = warp_sum(s); s2 = warp_sum(s2);
  float mean = s * (1.f / NC);
  float var = s2 * (1.f / NC) - mean * mean;
  float rs = rsqrtf(var + 1e-5f);
  int bb = row >> 11, t = row & 2047;
  unsigned short* yr = ypad + ((size_t)(bb * TPAD + t + 4)) * NC;
#pragma unroll
  for (int i = 0; i < 6; ++i) {
    int cc = lane + 64 * i;
    yr[cc] = f2bf((v[i] - mean) * rs * g[cc] + b[cc]);
  }
}

// zero the 4 guard rows top+bottom of each batch slab in ypad
__global__ __launch_bounds__(256) void k_zero_guard(unsigned short* __restrict__ ypad) {
  int i = blockIdx.x * 256 + threadIdx.x;   // 8*8*384 = 24576
  if (i >= 24576) return;
  int c = i % NC;
  int r = (i / NC) % 8;
  int b = i / (NC * 8);
  int t = (r < 4) ? r : (2048 + r);         // rows 0..3 and 2052..2055
  ypad[((size_t)b * TPAD + t) * NC + c] = 0;
}

// pack + convert cw[f][c][kk] -> cwp[f][kk*384+c] bf16. One block per f-row,
// coalesced load -> LDS -> coalesced store (LDS read stride 9: conflict-free).
__global__ __launch_bounds__(256) void k_pack_cw2(const float* __restrict__ cw,
    unsigned short* __restrict__ cwp) {
  __shared__ float s[NKI];
  int f = blockIdx.x;
  const float* src = cw + (size_t)f * NKI;
  for (int i = threadIdx.x; i < NKI; i += 256) s[i] = src[i];
  __syncthreads();
  unsigned short* dst = cwp + (size_t)f * NKI;
  for (int i = threadIdx.x; i < NKI; i += 256) {
    int kk = i / NC, cc = i - kk * NC;
    dst[i] = f2bf(s[cc * 9 + kk]);
  }
}

// fused qkvo weight convert: dst = [qwb|kwb|vwb|owb] contiguous, q scaled
__global__ __launch_bounds__(256) void k_cvt_qkvo(const float* __restrict__ qw,
    const float* __restrict__ kw, const float* __restrict__ vw,
    const float* __restrict__ ow, unsigned short* __restrict__ dst, float qscale) {
  int i = blockIdx.x * 256 + threadIdx.x;
  if (i >= 4 * 294912) return;
  int w = i / 294912;
  int j = i - w * 294912;
  const float* s = (w == 0) ? qw : (w == 1) ? kw : (w == 2) ? vw : ow;
  float sc = (w == 0) ? qscale : 1.f;
  dst[i] = f2bf(s[j] * sc);
}

// fp32 -> bf16 plain
__global__ __launch_bounds__(256) void k_cvt(const float* __restrict__ x,
    unsigned short* __restrict__ y, int n) {
  int i = blockIdx.x * 256 + threadIdx.x;
  if (i < n) y[i] = f2bf(x[i]);
}

// Projection GEMM: A[M,K]bf16 @ W[N=384,K]bf16^T. 128x128 tile, m97 structure.
// mode 0: bf16 row write to Cb. mode 1: Cf += acc (fused residual, o-proj).
__global__ __launch_bounds__(256) void k_pgemm_mfma(
    const unsigned short* __restrict__ A,
    const unsigned short* __restrict__ W,
    unsigned short* __restrict__ Cb,
    float* __restrict__ Cf,
    int K, int mode) {
  __shared__ unsigned short As[128 * 32];
  __shared__ unsigned short Bs[128 * 32];
  const int bn = blockIdx.x * 128;
  const int bm = blockIdx.y * 128;
  const int tid = threadIdx.x;
  const int lane = tid & 63, wv = tid >> 6;
  const int wr = (wv >> 1) * 64, wc = (wv & 1) * 64;
  f32x4 acc[4][4] = {};

  const int chunk = wv * 2;
  const int rloc = chunk * 16 + (lane >> 2);
  const int slot = (lane & 3) * 8;
  const size_t abase = ((size_t)(bm + rloc)) * K + slot;
  const size_t bbase = ((size_t)(bn + rloc)) * K + slot;
  unsigned short* AsW0 = &As[chunk * 512];
  unsigned short* AsW1 = &As[(chunk + 1) * 512];
  unsigned short* BsW0 = &Bs[chunk * 512];
  unsigned short* BsW1 = &Bs[(chunk + 1) * 512];

  const int rsel = lane & 15, ksel = (lane >> 4) * 8;

  for (int kt = 0; kt < K; kt += 32) {
    GLOAD16(A + abase + kt, AsW0);
    GLOAD16(A + abase + kt + (size_t)16 * K, AsW1);
    GLOAD16(W + bbase + kt, BsW0);
    GLOAD16(W + bbase + kt + (size_t)16 * K, BsW1);
    __syncthreads();
    bf16x8 af[4], bfr[4];
#pragma unroll
    for (int m = 0; m < 4; ++m)
      af[m] = *(const bf16x8*)&As[(wr + m * 16 + rsel) * 32 + ksel];
#pragma unroll
    for (int n = 0; n < 4; ++n)
      bfr[n] = *(const bf16x8*)&Bs[(wc + n * 16 + rsel) * 32 + ksel];
#pragma unroll
    for (int m = 0; m < 4; ++m)
#pragma unroll
      for (int n = 0; n < 4; ++n)
        acc[m][n] = __builtin_amdgcn_mfma_f32_16x16x32_bf16(af[m], bfr[n], acc[m][n], 0, 0, 0);
    __syncthreads();
  }

  const int col0 = bn + wc + (lane & 15);
  const int row0 = bm + wr + (lane >> 4) * 4;
#pragma unroll
  for (int m = 0; m < 4; ++m) {
#pragma unroll
    for (int n = 0; n < 4; ++n) {
      int col = col0 + n * 16;
#pragma unroll
      for (int r = 0; r < 4; ++r) {
        int row = row0 + m * 16 + r;
        if (mode == 0) {
          Cb[(size_t)row * NC + col] = f2bf(acc[m][n][r]);
        } else {
          size_t oi = (size_t)row * NC + col;
          Cf[oi] = acc[m][n][r] + Cf[oi];
        }
      }
    }
  }
}

// Fused K and V projections (z=0: k -> kbb row layout; z=1: v -> vtb transposed)
__global__ __launch_bounds__(256) void k_pgemm_kv(
    const unsigned short* __restrict__ A,
    const unsigned short* __restrict__ Wk,
    const unsigned short* __restrict__ Wv,
    unsigned short* __restrict__ Kb,
    unsigned short* __restrict__ Vtb) {
  __shared__ unsigned short As[128 * 32];
  __shared__ unsigned short Bs[128 * 32];
  const int z = blockIdx.z;
  const unsigned short* W = z ? Wv : Wk;
  const int bn = blockIdx.x * 128;
  const int bm = blockIdx.y * 128;
  const int tid = threadIdx.x;
  const int lane = tid & 63, wv = tid >> 6;
  const int wr = (wv >> 1) * 64, wc = (wv & 1) * 64;
  f32x4 acc[4][4] = {};

  const int chunk = wv * 2;
  const int rloc = chunk * 16 + (lane >> 2);
  const int slot = (lane & 3) * 8;
  const size_t abase = ((size_t)(bm + rloc)) * NC + slot;
  const size_t bbase = ((size_t)(bn + rloc)) * NC + slot;
  unsigned short* AsW0 = &As[chunk * 512];
  unsigned short* AsW1 = &As[(chunk + 1) * 512];
  unsigned short* BsW0 = &Bs[chunk * 512];
  unsigned short* BsW1 = &Bs[(chunk + 1) * 512];

  const int rsel = lane & 15, ksel = (lane >> 4) * 8;

  for (int kt = 0; kt < NC; kt += 32) {
    GLOAD16(A + abase + kt, AsW0);
    GLOAD16(A + abase + kt + (size_t)16 * NC, AsW1);
    GLOAD16(W + bbase + kt, BsW0);
    GLOAD16(W + bbase + kt + (size_t)16 * NC, BsW1);
    __syncthreads();
    bf16x8 af[4], bfr[4];
#pragma unroll
    for (int m = 0; m < 4; ++m)
      af[m] = *(const bf16x8*)&As[(wr + m * 16 + rsel) * 32 + ksel];
#pragma unroll
    for (int n = 0; n < 4; ++n)
      bfr[n] = *(const bf16x8*)&Bs[(wc + n * 16 + rsel) * 32 + ksel];
#pragma unroll
    for (int m = 0; m < 4; ++m)
#pragma unroll
      for (int n = 0; n < 4; ++n)
        acc[m][n] = __builtin_amdgcn_mfma_f32_16x16x32_bf16(af[m], bfr[n], acc[m][n], 0, 0, 0);
    __syncthreads();
  }

  const int col0 = bn + wc + (lane & 15);
  const int row0 = bm + wr + (lane >> 4) * 4;
#pragma unroll
  for (int m = 0; m < 4; ++m) {
#pragma unroll
    for (int n = 0; n < 4; ++n) {
      int col = col0 + n * 16;
#pragma unroll
      for (int r = 0; r < 4; ++r) {
        int row = row0 + m * 16 + r;
        if (z == 0) {
          Kb[(size_t)row * NC + col] = f2bf(acc[m][n][r]);
        } else {
          // vtb[(b*384 + col)*512 + j], b = row>>9, j = row&511
          Vtb[((size_t)((row >> 9) * 384 + col)) * 512 + (row & 511)] = f2bf(acc[m][n][r]);
        }
      }
    }
  }
}

// Conv1d(C->4C,k=9,SAME) implicit GEMM — 8-phase m201-template port.
// 256x256 tile, BK=64, 8 waves interleaved 16-row granularity (wvM 2 x wvN 4):
// A-half0 = m-frags 0-3 of EVERY wave, B-half0 = n-frags 0-1 of every wave.
// LDS [2 dbuf][2 half][128][64] per operand = 128 KB. Per K-tile, 4 phases
// (C-quadrants), 1 half-tile stage per phase rotating [A1(T+1), A0(T+2),
// B0(T+2), B1(T+2)] — each stage targets a region whose reads died >=1
// barrier earlier. vmcnt(6) once per K-tile (3 halves in flight, never 0).
// Granule-XOR swizzle, pre-swizzled source + XOR'd ds_read. Fused gelu epi.
__global__ __launch_bounds__(512) void k_conv_mfma(
    const unsigned short* __restrict__ Ypad,
    const unsigned short* __restrict__ Wp,
    const float* __restrict__ cb,
    unsigned short* __restrict__ H) {
  __shared__ unsigned short As[2][2][8192];   // [dbuf][half][128][64]
  __shared__ unsigned short Bs[2][2][8192];
  const int bm = blockIdx.x * 256;            // bm-fastest: XCD=id%8 keeps A L2-hot
  const int bn = blockIdx.y * 256;
  const int b = bm >> 11, t0 = bm & 2047;
  const int tid = threadIdx.x;
  const int lane = tid & 63, wv = tid >> 6;
  const int wvM = wv >> 2, wvN = wv & 3;
  const int rsel = lane & 15, ghi = lane >> 4;
  const int l8 = lane >> 3, g8 = lane & 7;
  const int gsrc = (g8 ^ l8) * 8;             // pre-swizzled source granule (shorts)
  const int x0 = (ghi ^ (rsel & 7)) * 8;      // ds-read XOR offsets, kstep 0/1
  const int x1 = ((4 + ghi) ^ (rsel & 7)) * 8;

  f32x4 acc[8][4] = {};                       // [m-frag][n-frag]

  const size_t aglob = (size_t)(b * TPAD + t0 + wv * 16 + l8);  // + h*128 + kk
  const size_t bglob = (size_t)(bn + wv * 16 + l8);             // + h*128

#define STAGE_A(T, h, d)                                                      \
  {                                                                           \
    const int kt_ = (T) * 64;                                                 \
    const int kk_ = kt_ / NC;                                                 \
    const int c0_ = kt_ - kk_ * NC;                                           \
    const size_t s_ = (aglob + (h) * 128 + kk_) * NC + c0_ + gsrc;            \
    GLOAD16(Ypad + s_, &As[d][h][(wv * 16) * 64]);                            \
    GLOAD16(Ypad + s_ + (size_t)8 * NC, &As[d][h][(wv * 16 + 8) * 64]);       \
  }
#define STAGE_B(T, h, d)                                                      \
  {                                                                           \
    const size_t s_ = (bglob + (h) * 128) * NKI + (T) * 64 + gsrc;            \
    GLOAD16(Wp + s_, &Bs[d][h][(wv * 16) * 64]);                              \
    GLOAD16(Wp + s_ + (size_t)8 * NKI, &Bs[d][h][(wv * 16 + 8) * 64]);        \
  }

  // prologue: 7 halves oldest-first (tile0 complete, then A0,B0,B1 of tile1)
  STAGE_A(0, 0, 0); STAGE_B(0, 0, 0); STAGE_B(0, 1, 0); STAGE_A(0, 1, 0);
  STAGE_A(1, 0, 1); STAGE_B(1, 0, 1); STAGE_B(1, 1, 1);
  asm volatile("s_waitcnt vmcnt(6)" ::: "memory");   // tile 0 resident
  __builtin_amdgcn_sched_barrier(0);
  __builtin_amdgcn_s_barrier();

  const int arow_base = wvM * 16 + rsel;   // + f*32 within half
  const int brow_base = wvN * 16 + rsel;   // + g*64 within half

  for (int T = 0; T < 54; ++T) {
    const int d = T & 1;
    const unsigned short* A0p = As[d][0];
    const unsigned short* A1p = As[d][1];
    const unsigned short* B0p = Bs[d][0];
    const unsigned short* B1p = Bs[d][1];
    bf16x8 a[4][2], b0[2][2], b1[2][2];

    // ---- phase 1: ds A0-sub + B0-sub (12 reads), stage A1(T+1) ----
#pragma unroll
    for (int f = 0; f < 4; ++f) {
      int r = f * 32 + arow_base;
      a[f][0] = *(const bf16x8*)&A0p[r * 64 + x0];
      a[f][1] = *(const bf16x8*)&A0p[r * 64 + x1];
    }
#pragma unroll
    for (int g = 0; g < 2; ++g) {
      int r = g * 64 + brow_base;
      b0[g][0] = *(const bf16x8*)&B0p[r * 64 + x0];
      b0[g][1] = *(const bf16x8*)&B0p[r * 64 + x1];
    }
    if (T + 1 < 54) STAGE_A(T + 1, 1, (T + 1) & 1);
    asm volatile("s_waitcnt lgkmcnt(8)" ::: "memory");
    __builtin_amdgcn_sched_barrier(0);
    __builtin_amdgcn_s_barrier();
    asm volatile("s_waitcnt lgkmcnt(0)" ::: "memory");
    __builtin_amdgcn_sched_barrier(0);
    __builtin_amdgcn_s_setprio(1);
#pragma unroll
    for (int k = 0; k < 2; ++k)
#pragma unroll
      for (int f = 0; f < 4; ++f)
#pragma unroll
        for (int g = 0; g < 2; ++g)
          acc[f][g] = __builtin_amdgcn_mfma_f32_16x16x32_bf16(a[f][k], b0[g][k], acc[f][g], 0, 0, 0);
    __builtin_amdgcn_s_setprio(0);
    __builtin_amdgcn_sched_barrier(0);
    __builtin_amdgcn_s_barrier();

    // ---- phase 2: ds B1-sub (4 reads), stage A0(T+2) [A0 cur died ph1] ----
#pragma unroll
    for (int g = 0; g < 2; ++g) {
      int r = g * 64 + brow_base;
      b1[g][0] = *(const bf16x8*)&B1p[r * 64 + x0];
      b1[g][1] = *(const bf16x8*)&B1p[r * 64 + x1];
    }
    if (T + 2 < 54) STAGE_A(T + 2, 0, d);
    __builtin_amdgcn_sched_barrier(0);
    __builtin_amdgcn_s_barrier();
    asm volatile("s_waitcnt lgkmcnt(0)" ::: "memory");
    __builtin_amdgcn_sched_barrier(0);
    __builtin_amdgcn_s_setprio(1);
#pragma unroll
    for (int k = 0; k < 2; ++k)
#pragma unroll
      for (int f = 0; f < 4; ++f)
#pragma unroll
        for (int g = 0; g < 2; ++g)
          acc[f][2 + g] = __builtin_amdgcn_mfma_f32_16x16x32_bf16(a[f][k], b1[g][k], acc[f][2 + g], 0, 0, 0);
    __builtin_amdgcn_s_setprio(0);
    __builtin_amdgcn_sched_barrier(0);
    __builtin_amdgcn_s_barrier();

    // ---- phase 3: ds A1-sub (8 reads), stage B0(T+2) [B0 cur died ph1] ----
#pragma unroll
    for (int f = 0; f < 4; ++f) {
      int r = f * 32 + arow_base;
      a[f][0] = *(const bf16x8*)&A1p[r * 64 + x0];
      a[f][1] = *(const bf16x8*)&A1p[r * 64 + x1];
    }
    if (T + 2 < 54) STAGE_B(T + 2, 0, d);
    __builtin_amdgcn_sched_barrier(0);
    __builtin_amdgcn_s_barrier();
    asm volatile("s_waitcnt lgkmcnt(0)" ::: "memory");
    __builtin_amdgcn_sched_barrier(0);
    __builtin_amdgcn_s_setprio(1);
#pragma unroll
    for (int k = 0; k < 2; ++k)
#pragma unroll
      for (int f = 0; f < 4; ++f)
#pragma unroll
        for (int g = 0; g < 2; ++g)
          acc[4 + f][g] = __builtin_amdgcn_mfma_f32_16x16x32_bf16(a[f][k], b0[g][k], acc[4 + f][g], 0, 0, 0);
    __builtin_amdgcn_s_setprio(0);
    __builtin_amdgcn_sched_barrier(0);
    __builtin_amdgcn_s_barrier();

    // ---- phase 4: no ds, stage B1(T+2) [B1 cur died ph2]; vmcnt per K-tile ----
    if (T + 2 < 54) STAGE_B(T + 2, 1, d);
    __builtin_amdgcn_sched_barrier(0);
    __builtin_amdgcn_s_barrier();
    __builtin_amdgcn_s_setprio(1);
#pragma unroll
    for (int k = 0; k < 2; ++k)
#pragma unroll
      for (int f = 0; f < 4; ++f)
#pragma unroll
        for (int g = 0; g < 2; ++g)
          acc[4 + f][2 + g] = __builtin_amdgcn_mfma_f32_16x16x32_bf16(a[f][k], b1[g][k], acc[4 + f][2 + g], 0, 0, 0);
    __builtin_amdgcn_s_setprio(0);
    __builtin_amdgcn_sched_barrier(0);
    if (T + 2 < 54) {
      asm volatile("s_waitcnt vmcnt(6)" ::: "memory");   // tile T+1 fully landed
    } else if (T + 1 < 54) {
      asm volatile("s_waitcnt vmcnt(0)" ::: "memory");   // drain for final tile
    }
    __builtin_amdgcn_sched_barrier(0);
    __builtin_amdgcn_s_barrier();
  }
#undef STAGE_A
#undef STAGE_B

  const int row00 = bm + wvM * 16 + ghi * 4;
  const int col00 = bn + wvN * 16 + rsel;
#pragma unroll
  for (int mf = 0; mf < 8; ++mf) {
    int rowb = row00 + (mf >> 2) * 128 + (mf & 3) * 32;
#pragma unroll
    for (int g = 0; g < 4; ++g) {
      int col = col00 + (g >> 1) * 128 + (g & 1) * 64;
      float cbv = cb[col];
#pragma unroll
      for (int r = 0; r < 4; ++r) {
        int row = rowb + r;
        float xv = (acc[mf][g][r] + cbv) * 0.33333333333333333f;
        float ge = 0.5f * xv * (1.f + erff(xv * 0.70710678118654752f));
        H[(size_t)row * NF + col] = f2bf(ge);
      }
    }
  }
}

// FFN linear: x1a[m][n] += H[m][:]@lw[n][:] + lb[n].  bf16 MFMA, m97 structure.
__global__ __launch_bounds__(256) void k_lin_mfma(
    const unsigned short* __restrict__ H,
    const unsigned short* __restrict__ Wb,
    const float* __restrict__ lb,
    float* __restrict__ x1a) {
  __shared__ unsigned short As[128 * 32];
  __shared__ unsigned short Bs[128 * 32];
  const int bn = blockIdx.x * 128;
  const int bm = blockIdx.y * 128;
  const int tid = threadIdx.x;
  const int lane = tid & 63, wv = tid >> 6;
  const int wr = (wv >> 1) * 64, wc = (wv & 1) * 64;
  f32x4 acc[4][4] = {};

  const int chunk = wv * 2;
  const int rloc = chunk * 16 + (lane >> 2);
  const int slot = (lane & 3) * 8;
  const size_t abase = ((size_t)(bm + rloc)) * NF + slot;
  const size_t bbase = ((size_t)(bn + rloc)) * NF + slot;
  unsigned short* AsW0 = &As[chunk * 512];
  unsigned short* AsW1 = &As[(chunk + 1) * 512];
  unsigned short* BsW0 = &Bs[chunk * 512];
  unsigned short* BsW1 = &Bs[(chunk + 1) * 512];

  const int rsel = lane & 15, ksel = (lane >> 4) * 8;

  for (int kt = 0; kt < NF; kt += 32) {
    GLOAD16(H + abase + kt, AsW0);
    GLOAD16(H + abase + kt + (size_t)16 * NF, AsW1);
    GLOAD16(Wb + bbase + kt, BsW0);
    GLOAD16(Wb + bbase + kt + (size_t)16 * NF, BsW1);
    __syncthreads();
    bf16x8 af[4], bfr[4];
#pragma unroll
    for (int m = 0; m < 4; ++m)
      af[m] = *(const bf16x8*)&As[(wr + m * 16 + rsel) * 32 + ksel];
#pragma unroll
    for (int n = 0; n < 4; ++n)
      bfr[n] = *(const bf16x8*)&Bs[(wc + n * 16 + rsel) * 32 + ksel];
#pragma unroll
    for (int m = 0; m < 4; ++m)
#pragma unroll
      for (int n = 0; n < 4; ++n)
        acc[m][n] = __builtin_amdgcn_mfma_f32_16x16x32_bf16(af[m], bfr[n], acc[m][n], 0, 0, 0);
    __syncthreads();
  }

  const int col0 = bn + wc + (lane & 15);
  const int row0 = bm + wr + (lane >> 4) * 4;
#pragma unroll
  for (int m = 0; m < 4; ++m) {
#pragma unroll
    for (int n = 0; n < 4; ++n) {
      int col = col0 + n * 16;
      float lbv = lb[col];
#pragma unroll
      for (int r = 0; r < 4; ++r) {
        int row = row0 + m * 16 + r;
        size_t oi = (size_t)row * NC + col;
        x1a[oi] = acc[m][n][r] + lbv + x1a[oi];
      }
    }
  }
}

// Windowed cross-attention, MFMA flash-style. bf16 output (feeds o-projection).
__global__ __launch_bounds__(256) void k_attn_mfma(
    const unsigned short* __restrict__ qbb,   // [8*2048][384] bf16 (q*scaling folded in W)
    const unsigned short* __restrict__ kbb,   // [8*512][384] bf16
    const unsigned short* __restrict__ vtb,   // [(b*2+h)*192+d][512] bf16
    unsigned short* __restrict__ o, int guided, float* __restrict__ gl) {
  __shared__ unsigned short lds[32768];
  const int tid = threadIdx.x;
  const int lane = tid & 63, wv = tid >> 6;
  const int rsel = lane & 15, ghi = lane >> 4;
  const int idx = blockIdx.x;
  const int tg = idx & 31;
  const int bh = idx >> 5;
  const int h = bh & 1, b = bh >> 1;
  const int t0 = tg * 64;
  const int c0 = t0 >> 2;
  int klo = c0 - 51; if (klo < 0) klo = 0;
  klo &= ~7;                       // 16B-align for global_load_lds on vtb
  if (klo > 384) klo = 384;        // keep window inside [0,512)

  // Q fragments: A-operand layout, row = lane&15, k = ghi*8 (+32 per step)
  const unsigned short* qrow = qbb + (size_t)(b * NT1 + t0 + wv * 16 + rsel) * NC + h * ND;
  bf16x8 qf[6];
#pragma unroll
  for (int kk = 0; kk < 6; ++kk)
    qf[kk] = *(const bf16x8*)(qrow + kk * 32 + ghi * 8);

  // stage K window [128 keys][192] bf16, source pre-swizzled (granule ^ row&7)
  {
    const size_t kbase = (size_t)(b * NT2 + klo) * NC + h * ND;
#pragma unroll
    for (int it = 0; it < 12; ++it) {
      int g = it * 256 + tid;
      int row = g / 24, go = g % 24;
      int gs = go ^ (row & 7);
      GLOAD16(kbb + kbase + (size_t)row * NC + gs * 8, &lds[(it * 256 + wv * 64) * 8]);
    }
  }
  __syncthreads();

  // QK^T: 16 queries x 128 keys per wave
  f32x4 accs[8] = {};
#pragma unroll
  for (int kk = 0; kk < 6; ++kk) {
#pragma unroll
    for (int n = 0; n < 8; ++n) {
      int row = n * 16 + rsel;
      bf16x8 bfr = *(const bf16x8*)&lds[row * 192 + (((kk * 4 + ghi) ^ (rsel & 7)) * 8)];
      accs[n] = __builtin_amdgcn_mfma_f32_16x16x32_bf16(qf[kk], bfr, accs[n], 0, 0, 0);
    }
  }

  // masked softmax per query row; rows live on 16-lane groups (row=ghi*4+r, col=rsel)
  unsigned short* pl = &lds[24576 + wv * 2048];
  float gacc = 0.f;
  const int t0w = t0 + wv * 16;
#pragma unroll
  for (int r = 0; r < 4; ++r) {
    int t = t0w + ghi * 4 + r;
    int c = t >> 2;
    int loq = c - 51; if (loq < 0) loq = 0;
    int hiq = c + 51; if (hiq > NT2) hiq = NT2;
    float sv[8];
    float mx = -1e30f;
#pragma unroll
    for (int n = 0; n < 8; ++n) {
      int j = klo + n * 16 + rsel;
      float s = (j >= loq && j < hiq) ? accs[n][r] : -1e30f;
      sv[n] = s; mx = fmaxf(mx, s);
    }
#pragma unroll
    for (int off = 1; off < 16; off <<= 1) mx = fmaxf(mx, __shfl_xor(mx, off));
    float e[8]; float se = 0.f;
#pragma unroll
    for (int n = 0; n < 8; ++n) { e[n] = __expf(sv[n] - mx); se += e[n]; }
#pragma unroll
    for (int off = 1; off < 16; off <<= 1) se += __shfl_xor(se, off);
    float inv = 1.f / se;
    int q = ghi * 4 + r;
#pragma unroll
    for (int n = 0; n < 8; ++n) {
      float pv = e[n] * inv;
      int klocal = n * 16 + rsel;
      pl[q * 128 + (((klocal >> 3) ^ (q & 7)) * 8) + (klocal & 7)] = f2bf(pv);
      if (guided) {
        int j = klo + klocal;
        float d = (float)j * (1.f / NT2) - (float)t * (1.f / NT1);
        gacc += pv * (1.f - __expf(-(d * d) * 5.5555555556f));
      }
    }
  }
  if (guided) {
    gacc = warp_sum(gacc);
    if (lane == 0) atomicAdd(gl, gacc * (1.f / 16777216.f));
  }
  __syncthreads();

  // stage VT window [192 chans][128 keys] bf16 into the K buffer (reuse)
  {
    const size_t vbase = ((size_t)(b * 2 + h) * ND) * NT2 + klo;
#pragma unroll
    for (int it = 0; it < 12; ++it) {
      int g = it * 256 + tid;
      int row = g >> 4, go = g & 15;
      int gs = go ^ (row & 7);
      GLOAD16(vtb + vbase + (size_t)row * NT2 + gs * 8, &lds[(it * 256 + wv * 64) * 8]);
    }
  }
  __syncthreads();

  // PV: P[16x128] @ V[128x192] -> O[16x192]
  f32x4 acco[12] = {};
#pragma unroll
  for (int kt = 0; kt < 4; ++kt) {
    bf16x8 pa = *(const bf16x8*)&pl[rsel * 128 + (((kt * 4 + ghi) ^ (rsel & 7)) * 8)];
#pragma unroll
    for (int n = 0; n < 12; ++n) {
      int row = n * 16 + rsel;
      bf16x8 bfr = *(const bf16x8*)&lds[row * 128 + (((kt * 4 + ghi) ^ (rsel & 7)) * 8)];
      acco[n] = __builtin_amdgcn_mfma_f32_16x16x32_bf16(pa, bfr, acco[n], 0, 0, 0);
    }
  }

  unsigned short* obase = o + (size_t)(b * NT1 + t0w + ghi * 4) * NC + h * ND;
#pragma unroll
  for (int n = 0; n < 12; ++n) {
#pragma unroll
    for (int r = 0; r < 4; ++r) {
      obase[(size_t)r * NC + n * 16 + rsel] = f2bf(acco[n][r]);
    }
  }
}

extern "C" void kernel_launch(void* const* d_in, const int* in_sizes, int n_in,
                              void* d_out, int out_size, void* d_ws, size_t ws_size,
                              hipStream_t stream) {
  (void)in_sizes; (void)n_in; (void)out_size; (void)ws_size;
  const float* x1    = (const float*)d_in[0];
  const float* x2    = (const float*)d_in[1];
  const float* alpha = (const float*)d_in[2];
  const float* ln1_g = (const float*)d_in[3];
  const float* ln1_b = (const float*)d_in[4];
  const float* qw    = (const float*)d_in[5];
  const float* kw    = (const float*)d_in[6];
  const float* vw    = (const float*)d_in[7];
  const float* ow    = (const float*)d_in[8];
  const float* ln2_g = (const float*)d_in[9];
  const float* ln2_b = (const float*)d_in[10];
  const float* cw    = (const float*)d_in[11];
  const float* cb    = (const float*)d_in[12];
  const float* lw    = (const float*)d_in[13];
  const float* lb    = (const float*)d_in[14];
  const float* lnf_g = (const float*)d_in[15];
  const float* lnf_b = (const float*)d_in[16];
  float* out = (float*)d_out;
  float* gl = out + 6291456;   // guided-loss scalar slot

  float* p = (float*)d_ws;
  float* x1a = p; p += 6291456;    // x1 state [16384,384] f32
  // bf16 region (16B-aligned)
  unsigned short* us = (unsigned short*)p;
  unsigned short* x2b  = us; us += 1572864;            // x2+pos bf16 [4096][384]
  unsigned short* tmpb = us; us += 6291456;            // LN1 out / attn out bf16
  unsigned short* ypad = us; us += 8 * TPAD * NC;      // 6316032
  unsigned short* cwpb = us; us += 2 * (size_t)NF * NKI;   // 10616832 (both layers)
  unsigned short* lwb  = us; us += 2 * (size_t)NC * NF;    // 1179648 (both layers)
  unsigned short* hb   = us; us += (size_t)16384 * NF; // 25165824
  unsigned short* qbb  = us; us += 6291456;            // q bf16 [16384][384]
  unsigned short* kbb  = us; us += 1572864;            // k bf16 [4096][384]
  unsigned short* vtb  = us; us += 1572864;            // v^T bf16 [32*192][512]
  unsigned short* qwb  = us; us += 294912;             // weights bf16 (contiguous qkvo)
  unsigned short* kwb  = us; us += 294912;
  unsigned short* vwb  = us; us += 294912;
  unsigned short* owb  = us; us += 294912;

  hipMemsetAsync(gl, 0, sizeof(float), stream);  // atomic accumulator, re-zeroed every launch
  k_zero_guard<<<96, 256, 0, stream>>>(ypad);
  k_add_pos2<<<12288, 256, 0, stream>>>(x1, alpha, x1a, NT1, 3145728);
  k_add_pos2_bf16<<<3072, 256, 0, stream>>>(x2, alpha, x2b, NT2, 786432);

  const float scaling = 0.07216878364870323f;   // 192^-0.5
  // weight conversions, both layers, hoisted + fused
  k_cvt_qkvo<<<4608, 256, 0, stream>>>(qw, kw, vw, ow, qwb, scaling);
  k_cvt<<<4608, 256, 0, stream>>>(lw, lwb, 1179648);
  k_pack_cw2<<<3072, 256, 0, stream>>>(cw, cwpb);

  for (int l = 0; l < 2; ++l) {
    k_ln_bf16<<<4096, 256, 0, stream>>>(x1a, ln1_g + l * 384, ln1_b + l * 384, tmpb);
    k_pgemm_mfma<<<dim3(3, 128), 256, 0, stream>>>(tmpb, qwb + (size_t)l * 147456, qbb, nullptr, 384, 0);
    k_pgemm_kv<<<dim3(3, 32, 2), 256, 0, stream>>>(x2b, kwb + (size_t)l * 147456,
                                                   vwb + (size_t)l * 147456, kbb, vtb);
    k_attn_mfma<<<512, 256, 0, stream>>>(qbb, kbb, vtb, tmpb, l == 0 ? 1 : 0, gl);
    k_pgemm_mfma<<<dim3(3, 128), 256, 0, stream>>>(tmpb, owb + (size_t)l * 147456, nullptr, x1a, 384, 1);
    // FFN: ln2 -> bf16 padded, conv implicit GEMM (8-phase template), linear (MFMA)
    k_ln_bf16p<<<4096, 256, 0, stream>>>(x1a, ln2_g + l * 384, ln2_b + l * 384, ypad);
    k_conv_mfma<<<dim3(64, 6), 512, 0, stream>>>(ypad, cwpb + (size_t)l * 5308416, cb + l * 1536, hb);
    k_lin_mfma<<<dim3(3, 128), 256, 0, stream>>>(hb, lwb + (size_t)l * 589824, lb + l * 384, x1a);
  }
  k_ln<<<4096, 256, 0, stream>>>(x1a, lnf_g, lnf_b, out, 16384);
}

// Round 8
// 673.916 us; speedup vs baseline: 1.1793x; 1.1793x over previous
//
#include <hip/hip_runtime.h>
#include <math.h>

#define NB 8
#define NT1 2048
#define NT2 512
#define NC 384
#define ND 192
#define NF 1536
#define NKI 3456   // 9*384 implicit-GEMM K for conv
#define TPAD 2056  // 2048 + 4 guard rows top and bottom

typedef __attribute__((ext_vector_type(8))) short bf16x8;
typedef __attribute__((ext_vector_type(4))) float f32x4;

#define GLOAD16(gsrc, ldst) \
  __builtin_amdgcn_global_load_lds((const __attribute__((address_space(1))) void*)(gsrc), \
                                   (__attribute__((address_space(3))) void*)(ldst), 16, 0, 0)

static __device__ __forceinline__ unsigned short f2bf(float f) {
  unsigned int u = __float_as_uint(f);
  unsigned int r = (u + 0x7fffu + ((u >> 16) & 1u)) >> 16;
  return (unsigned short)r;
}

static __device__ __forceinline__ float warp_sum(float v) {
#pragma unroll
  for (int off = 32; off > 0; off >>= 1) v += __shfl_xor(v, off);
  return v;
}

// x += alpha * sin-pos; thread handles (t,j) pair: sin at c=j, cos at c=j+192
__global__ __launch_bounds__(256) void k_add_pos2(const float* __restrict__ x,
    const float* __restrict__ alpha_p, float* __restrict__ y, int T, int total2) {
  int i = blockIdx.x * 256 + threadIdx.x;
  if (i >= total2) return;
  int j = i % 192;
  int row = i / 192;
  int t = row % T;
  float freq = __expf(-0.0482216773f * (float)j);   // ln(10000)/191
  float ang = (float)(t + 1) * freq;
  float sn, cs;
  __sincosf(ang, &sn, &cs);
  float a = alpha_p[0];
  size_t base = (size_t)row * NC;
  y[base + j] = x[base + j] + a * sn;
  y[base + j + 192] = x[base + j + 192] + a * cs;
}

__global__ __launch_bounds__(256) void k_add_pos2_bf16(const float* __restrict__ x,
    const float* __restrict__ alpha_p, unsigned short* __restrict__ y, int T, int total2) {
  int i = blockIdx.x * 256 + threadIdx.x;
  if (i >= total2) return;
  int j = i % 192;
  int row = i / 192;
  int t = row % T;
  float freq = __expf(-0.0482216773f * (float)j);
  float ang = (float)(t + 1) * freq;
  float sn, cs;
  __sincosf(ang, &sn, &cs);
  float a = alpha_p[0];
  size_t base = (size_t)row * NC;
  y[base + j] = f2bf(x[base + j] + a * sn);
  y[base + j + 192] = f2bf(x[base + j + 192] + a * cs);
}

// LayerNorm over last dim (384). One wave per row. fp32 out (final LN).
__global__ __launch_bounds__(256) void k_ln(const float* __restrict__ x,
    const float* __restrict__ g, const float* __restrict__ b,
    float* __restrict__ y, int nrows) {
  int row = blockIdx.x * 4 + (threadIdx.x >> 6);
  int lane = threadIdx.x & 63;
  if (row >= nrows) return;
  const float* xr = x + (size_t)row * NC;
  float v[6];
  float s = 0.f, s2 = 0.f;
#pragma unroll
  for (int i = 0; i < 6; ++i) {
    float t = xr[lane + 64 * i];
    v[i] = t; s += t; s2 += t * t;
  }
  s = warp_sum(s); s2 = warp_sum(s2);
  float mean = s * (1.f / NC);
  float var = s2 * (1.f / NC) - mean * mean;
  float rs = rsqrtf(var + 1e-5f);
  float* yr = y + (size_t)row * NC;
#pragma unroll
  for (int i = 0; i < 6; ++i) {
    int cc = lane + 64 * i;
    yr[cc] = (v[i] - mean) * rs * g[cc] + b[cc];
  }
}

// LayerNorm -> bf16 (unpadded), feeds MFMA projections
__global__ __launch_bounds__(256) void k_ln_bf16(const float* __restrict__ x,
    const float* __restrict__ g, const float* __restrict__ b,
    unsigned short* __restrict__ y) {
  int row = blockIdx.x * 4 + (threadIdx.x >> 6);
  int lane = threadIdx.x & 63;
  const float* xr = x + (size_t)row * NC;
  float v[6];
  float s = 0.f, s2 = 0.f;
#pragma unroll
  for (int i = 0; i < 6; ++i) {
    float t = xr[lane + 64 * i];
    v[i] = t; s += t; s2 += t * t;
  }
  s = warp_sum(s); s2 = warp_sum(s2);
  float mean = s * (1.f / NC);
  float var = s2 * (1.f / NC) - mean * mean;
  float rs = rsqrtf(var + 1e-5f);
  unsigned short* yr = y + (size_t)row * NC;
#pragma unroll
  for (int i = 0; i < 6; ++i) {
    int cc = lane + 64 * i;
    yr[cc] = f2bf((v[i] - mean) * rs * g[cc] + b[cc]);
  }
}

// LayerNorm -> bf16 into guard-padded [8][2056][384] buffer (row t -> t+4)
__global__ __launch_bounds__(256) void k_ln_bf16p(const float* __restrict__ x,
    const float* __restrict__ g, const float* __restrict__ b,
    unsigned short* __restrict__ ypad) {
  int row = blockIdx.x * 4 + (threadIdx.x >> 6);
  int lane = threadIdx.x & 63;
  const float* xr = x + (size_t)row * NC;
  float v[6];
  float s = 0.f, s2 = 0.f;
#pragma unroll
  for (int i = 0; i < 6; ++i) {
    float t = xr[lane + 64 * i];
    v[i] = t; s += t; s2 += t * t;
  }
  s = warp_sum(s); s2 = warp_sum(s2);
  float mean = s * (1.f / NC);
  float var = s2 * (1.f / NC) - mean * mean;
  float rs = rsqrtf(var + 1e-5f);
  int bb = row >> 11, t = row & 2047;
  unsigned short* yr = ypad + ((size_t)(bb * TPAD + t + 4)) * NC;
#pragma unroll
  for (int i = 0; i < 6; ++i) {
    int cc = lane + 64 * i;
    yr[cc] = f2bf((v[i] - mean) * rs * g[cc] + b[cc]);
  }
}

// zero the 4 guard rows top+bottom of each batch slab in ypad
__global__ __launch_bounds__(256) void k_zero_guard(unsigned short* __restrict__ ypad) {
  int i = blockIdx.x * 256 + threadIdx.x;   // 8*8*384 = 24576
  if (i >= 24576) return;
  int c = i % NC;
  int r = (i / NC) % 8;
  int b = i / (NC * 8);
  int t = (r < 4) ? r : (2048 + r);         // rows 0..3 and 2052..2055
  ypad[((size_t)b * TPAD + t) * NC + c] = 0;
}

// pack + convert cw[f][c][kk] -> cwp[f][kk*384+c] bf16. One block per f-row,
// coalesced load -> LDS -> coalesced store (LDS read stride 9: conflict-free).
__global__ __launch_bounds__(256) void k_pack_cw2(const float* __restrict__ cw,
    unsigned short* __restrict__ cwp) {
  __shared__ float s[NKI];
  int f = blockIdx.x;
  const float* src = cw + (size_t)f * NKI;
  for (int i = threadIdx.x; i < NKI; i += 256) s[i] = src[i];
  __syncthreads();
  unsigned short* dst = cwp + (size_t)f * NKI;
  for (int i = threadIdx.x; i < NKI; i += 256) {
    int kk = i / NC, cc = i - kk * NC;
    dst[i] = f2bf(s[cc * 9 + kk]);
  }
}

// fused qkvo weight convert: dst = [qwb|kwb|vwb|owb] contiguous, q scaled
__global__ __launch_bounds__(256) void k_cvt_qkvo(const float* __restrict__ qw,
    const float* __restrict__ kw, const float* __restrict__ vw,
    const float* __restrict__ ow, unsigned short* __restrict__ dst, float qscale) {
  int i = blockIdx.x * 256 + threadIdx.x;
  if (i >= 4 * 294912) return;
  int w = i / 294912;
  int j = i - w * 294912;
  const float* s = (w == 0) ? qw : (w == 1) ? kw : (w == 2) ? vw : ow;
  float sc = (w == 0) ? qscale : 1.f;
  dst[i] = f2bf(s[j] * sc);
}

// fp32 -> bf16 plain
__global__ __launch_bounds__(256) void k_cvt(const float* __restrict__ x,
    unsigned short* __restrict__ y, int n) {
  int i = blockIdx.x * 256 + threadIdx.x;
  if (i < n) y[i] = f2bf(x[i]);
}

// Merged q/k/v projection GEMM, one launch. grid (3, 192):
//   y in [0,128): q = LN1(x1) @ qw^T  -> qbb row-major      (M=16384)
//   y in [128,160): k = x2b @ kw^T    -> kbb row-major      (M=4096)
//   y in [160,192): v = x2b @ vw^T    -> vtb transposed     (M=4096)
// All K=384, N=384, 128x128 tile, m97 structure. Selection is block-uniform.
__global__ __launch_bounds__(256) void k_pgemm_qkv(
    const unsigned short* __restrict__ Aq,
    const unsigned short* __restrict__ Akv,
    const unsigned short* __restrict__ Wq,
    const unsigned short* __restrict__ Wk,
    const unsigned short* __restrict__ Wv,
    unsigned short* __restrict__ Qb,
    unsigned short* __restrict__ Kb,
    unsigned short* __restrict__ Vtb) {
  __shared__ unsigned short As[128 * 32];
  __shared__ unsigned short Bs[128 * 32];
  const int y = blockIdx.y;
  const int which = (y < 128) ? 0 : (y < 160) ? 1 : 2;
  const unsigned short* A = (which == 0) ? Aq : Akv;
  const unsigned short* W = (which == 0) ? Wq : (which == 1) ? Wk : Wv;
  const int bm = ((which == 0) ? y : (which == 1) ? (y - 128) : (y - 160)) * 128;
  const int bn = blockIdx.x * 128;
  const int tid = threadIdx.x;
  const int lane = tid & 63, wv = tid >> 6;
  const int wr = (wv >> 1) * 64, wc = (wv & 1) * 64;
  f32x4 acc[4][4] = {};

  const int chunk = wv * 2;
  const int rloc = chunk * 16 + (lane >> 2);
  const int slot = (lane & 3) << 3;
  const size_t abase = ((size_t)(bm + rloc)) * NC + slot;
  const size_t bbase = ((size_t)(bn + rloc)) * NC + slot;
  unsigned short* AsW0 = &As[chunk * 512];
  unsigned short* AsW1 = &As[(chunk + 1) * 512];
  unsigned short* BsW0 = &Bs[chunk * 512];
  unsigned short* BsW1 = &Bs[(chunk + 1) * 512];

  const int rsel = lane & 15, ksel = (lane >> 4) * 8;

  for (int kt = 0; kt < NC; kt += 32) {
    GLOAD16(A + abase + kt, AsW0);
    GLOAD16(A + abase + kt + (size_t)16 * NC, AsW1);
    GLOAD16(W + bbase + kt, BsW0);
    GLOAD16(W + bbase + kt + (size_t)16 * NC, BsW1);
    __syncthreads();
    bf16x8 af[4], bfr[4];
#pragma unroll
    for (int m = 0; m < 4; ++m)
      af[m] = *(const bf16x8*)&As[(wr + m * 16 + rsel) * 32 + ksel];
#pragma unroll
    for (int n = 0; n < 4; ++n)
      bfr[n] = *(const bf16x8*)&Bs[(wc + n * 16 + rsel) * 32 + ksel];
#pragma unroll
    for (int m = 0; m < 4; ++m)
#pragma unroll
      for (int n = 0; n < 4; ++n)
        acc[m][n] = __builtin_amdgcn_mfma_f32_16x16x32_bf16(af[m], bfr[n], acc[m][n], 0, 0, 0);
    __syncthreads();
  }

  const int col0 = bn + wc + (lane & 15);
  const int row0 = bm + wr + (lane >> 4) * 4;
#pragma unroll
  for (int m = 0; m < 4; ++m) {
#pragma unroll
    for (int n = 0; n < 4; ++n) {
      int col = col0 + n * 16;
#pragma unroll
      for (int r = 0; r < 4; ++r) {
        int row = row0 + m * 16 + r;
        unsigned short bv = f2bf(acc[m][n][r]);
        if (which == 0) {
          Qb[(size_t)row * NC + col] = bv;
        } else if (which == 1) {
          Kb[(size_t)row * NC + col] = bv;
        } else {
          // vtb[(b*384 + col)*512 + j], b = row>>9, j = row&511
          Vtb[((size_t)((row >> 9) * 384 + col)) * 512 + (row & 511)] = bv;
        }
      }
    }
  }
}

// o-projection GEMM: x1a += attn @ ow^T (fused residual). 128x128, m97 structure.
__global__ __launch_bounds__(256) void k_pgemm_o(
    const unsigned short* __restrict__ A,
    const unsigned short* __restrict__ W,
    float* __restrict__ Cf) {
  __shared__ unsigned short As[128 * 32];
  __shared__ unsigned short Bs[128 * 32];
  const int bn = blockIdx.x * 128;
  const int bm = blockIdx.y * 128;
  const int tid = threadIdx.x;
  const int lane = tid & 63, wv = tid >> 6;
  const int wr = (wv >> 1) * 64, wc = (wv & 1) * 64;
  f32x4 acc[4][4] = {};

  const int chunk = wv * 2;
  const int rloc = chunk * 16 + (lane >> 2);
  const int slot = (lane & 3) << 3;
  const size_t abase = ((size_t)(bm + rloc)) * NC + slot;
  const size_t bbase = ((size_t)(bn + rloc)) * NC + slot;
  unsigned short* AsW0 = &As[chunk * 512];
  unsigned short* AsW1 = &As[(chunk + 1) * 512];
  unsigned short* BsW0 = &Bs[chunk * 512];
  unsigned short* BsW1 = &Bs[(chunk + 1) * 512];

  const int rsel = lane & 15, ksel = (lane >> 4) * 8;

  for (int kt = 0; kt < NC; kt += 32) {
    GLOAD16(A + abase + kt, AsW0);
    GLOAD16(A + abase + kt + (size_t)16 * NC, AsW1);
    GLOAD16(W + bbase + kt, BsW0);
    GLOAD16(W + bbase + kt + (size_t)16 * NC, BsW1);
    __syncthreads();
    bf16x8 af[4], bfr[4];
#pragma unroll
    for (int m = 0; m < 4; ++m)
      af[m] = *(const bf16x8*)&As[(wr + m * 16 + rsel) * 32 + ksel];
#pragma unroll
    for (int n = 0; n < 4; ++n)
      bfr[n] = *(const bf16x8*)&Bs[(wc + n * 16 + rsel) * 32 + ksel];
#pragma unroll
    for (int m = 0; m < 4; ++m)
#pragma unroll
      for (int n = 0; n < 4; ++n)
        acc[m][n] = __builtin_amdgcn_mfma_f32_16x16x32_bf16(af[m], bfr[n], acc[m][n], 0, 0, 0);
    __syncthreads();
  }

  const int col0 = bn + wc + (lane & 15);
  const int row0 = bm + wr + (lane >> 4) * 4;
#pragma unroll
  for (int m = 0; m < 4; ++m) {
#pragma unroll
    for (int n = 0; n < 4; ++n) {
      int col = col0 + n * 16;
#pragma unroll
      for (int r = 0; r < 4; ++r) {
        int row = row0 + m * 16 + r;
        size_t oi = (size_t)row * NC + col;
        Cf[oi] = acc[m][n][r] + Cf[oi];
      }
    }
  }
}

// Conv1d(C->4C,k=9,SAME) implicit GEMM. 256x128 tile, BK=64, 8 waves (4Mx2N),
// double-buffered LDS, distance-2 prefetch with counted vmcnt (never 0 mid-loop),
// granule-XOR swizzle (pre-swizzled global src + XOR'd ds_read).
// Fused (+cb)*9^-0.5 -> gelu(exact) -> bf16 store.  [R2 structure: 204 us]
__global__ __launch_bounds__(512) void k_conv_mfma(
    const unsigned short* __restrict__ Ypad,
    const unsigned short* __restrict__ Wp,
    const float* __restrict__ cb,
    unsigned short* __restrict__ H) {
  __shared__ unsigned short As[2][256 * 64];   // 64 KB
  __shared__ unsigned short Bs[2][128 * 64];   // 32 KB
  const int bm = blockIdx.x * 256;             // bm-fastest: XCD=id%8, A panels L2-hot
  const int bn = blockIdx.y * 128;
  const int b = bm >> 11, t0 = bm & 2047;
  const int tid = threadIdx.x;
  const int lane = tid & 63, wv = tid >> 6;
  const int wvM = wv >> 1, wvN = wv & 1;
  const int rsel = lane & 15, ghi = lane >> 4;
  const int l8 = lane >> 3, g8 = lane & 7;
  const int gsrc = (g8 ^ l8) * 8;              // pre-swizzled source granule (shorts)

  f32x4 acc[4][4] = {};

  const size_t arow0 = (size_t)(b * TPAD + t0 + wv * 32 + l8);   // A stage row (lane)
  const size_t brow0 = (size_t)(bn + wv * 16 + l8);              // B stage row (lane)

#define CONV_STAGE(T, DB)                                                     \
  {                                                                           \
    const int kt_ = (T) * 64;                                                 \
    const int kk_ = kt_ / NC;                                                 \
    const int c0_ = kt_ - kk_ * NC;                                           \
    const size_t asrc_ = (arow0 + kk_) * NC + c0_ + gsrc;                     \
    GLOAD16(Ypad + asrc_, &As[DB][(wv * 32) * 64]);                           \
    GLOAD16(Ypad + asrc_ + (size_t)8 * NC, &As[DB][(wv * 32 + 8) * 64]);      \
    GLOAD16(Ypad + asrc_ + (size_t)16 * NC, &As[DB][(wv * 32 + 16) * 64]);    \
    GLOAD16(Ypad + asrc_ + (size_t)24 * NC, &As[DB][(wv * 32 + 24) * 64]);    \
    const size_t bsrc_ = brow0 * NKI + kt_ + gsrc;                            \
    GLOAD16(Wp + bsrc_, &Bs[DB][(wv * 16) * 64]);                             \
    GLOAD16(Wp + bsrc_ + (size_t)8 * NKI, &Bs[DB][(wv * 16 + 8) * 64]);       \
  }

  // prologue: stage tiles 0 and 1 (12 loads); wait the 6 oldest = tile 0
  CONV_STAGE(0, 0);
  CONV_STAGE(1, 1);
  asm volatile("s_waitcnt vmcnt(6)" ::: "memory");
  __builtin_amdgcn_sched_barrier(0);
  __builtin_amdgcn_s_barrier();

  const int arow = wvM * 64;
  const int brow = wvN * 64;
  int db = 0;
  for (int t = 0; t < 54; ++t) {
    bf16x8 af[4][2], bfr[4][2];
#pragma unroll
    for (int m = 0; m < 4; ++m) {
      int r = arow + m * 16 + rsel;
#pragma unroll
      for (int k = 0; k < 2; ++k)
        af[m][k] = *(const bf16x8*)&As[db][r * 64 + (((k * 4 + ghi) ^ (r & 7)) * 8)];
    }
#pragma unroll
    for (int n = 0; n < 4; ++n) {
      int r = brow + n * 16 + rsel;
#pragma unroll
      for (int k = 0; k < 2; ++k)
        bfr[n][k] = *(const bf16x8*)&Bs[db][r * 64 + (((k * 4 + ghi) ^ (r & 7)) * 8)];
    }
    __builtin_amdgcn_s_setprio(1);
#pragma unroll
    for (int m = 0; m < 4; ++m)
#pragma unroll
      for (int n = 0; n < 4; ++n)
        acc[m][n] = __builtin_amdgcn_mfma_f32_16x16x32_bf16(af[m][0], bfr[n][0], acc[m][n], 0, 0, 0);
    __builtin_amdgcn_s_setprio(0);
    __builtin_amdgcn_sched_barrier(0);
    asm volatile("s_waitcnt lgkmcnt(0)" ::: "memory");   // all reads of buf[db] done
    __builtin_amdgcn_sched_barrier(0);
    __builtin_amdgcn_s_barrier();                        // ... in every wave
    if (t + 2 < 54) CONV_STAGE(t + 2, db);               // safe: buf[db] free now
    __builtin_amdgcn_s_setprio(1);
#pragma unroll
    for (int m = 0; m < 4; ++m)
#pragma unroll
      for (int n = 0; n < 4; ++n)
        acc[m][n] = __builtin_amdgcn_mfma_f32_16x16x32_bf16(af[m][1], bfr[n][1], acc[m][n], 0, 0, 0);
    __builtin_amdgcn_s_setprio(0);
    __builtin_amdgcn_sched_barrier(0);
    if (t + 2 < 54) {
      asm volatile("s_waitcnt vmcnt(6)" ::: "memory");   // all t+1 landed; t+2 in flight
    } else {
      asm volatile("s_waitcnt vmcnt(0)" ::: "memory");   // epilogue drain
    }
    __builtin_amdgcn_sched_barrier(0);
    __builtin_amdgcn_s_barrier();
    db ^= 1;
  }
#undef CONV_STAGE

  const int col0 = bn + wvN * 64 + rsel;
  const int row0 = bm + wvM * 64 + ghi * 4;
#pragma unroll
  for (int m = 0; m < 4; ++m) {
#pragma unroll
    for (int n = 0; n < 4; ++n) {
      int col = col0 + n * 16;
      float cbv = cb[col];
#pragma unroll
      for (int r = 0; r < 4; ++r) {
        int row = row0 + m * 16 + r;
        float xv = (acc[m][n][r] + cbv) * 0.33333333333333333f;
        float ge = 0.5f * xv * (1.f + erff(xv * 0.70710678118654752f));
        H[(size_t)row * NF + col] = f2bf(ge);
      }
    }
  }
}

// FFN linear: x1a[m][n] += H[m][:]@lw[n][:] + lb[n].  bf16 MFMA, m97 structure.
__global__ __launch_bounds__(256) void k_lin_mfma(
    const unsigned short* __restrict__ H,
    const unsigned short* __restrict__ Wb,
    const float* __restrict__ lb,
    float* __restrict__ x1a) {
  __shared__ unsigned short As[128 * 32];
  __shared__ unsigned short Bs[128 * 32];
  const int bn = blockIdx.x * 128;
  const int bm = blockIdx.y * 128;
  const int tid = threadIdx.x;
  const int lane = tid & 63, wv = tid >> 6;
  const int wr = (wv >> 1) * 64, wc = (wv & 1) * 64;
  f32x4 acc[4][4] = {};

  const int chunk = wv * 2;
  const int rloc = chunk * 16 + (lane >> 2);
  const int slot = (lane & 3) << 3;
  const size_t abase = ((size_t)(bm + rloc)) * NF + slot;
  const size_t bbase = ((size_t)(bn + rloc)) * NF + slot;
  unsigned short* AsW0 = &As[chunk * 512];
  unsigned short* AsW1 = &As[(chunk + 1) * 512];
  unsigned short* BsW0 = &Bs[chunk * 512];
  unsigned short* BsW1 = &Bs[(chunk + 1) * 512];

  const int rsel = lane & 15, ksel = (lane >> 4) * 8;

  for (int kt = 0; kt < NF; kt += 32) {
    GLOAD16(H + abase + kt, AsW0);
    GLOAD16(H + abase + kt + (size_t)16 * NF, AsW1);
    GLOAD16(Wb + bbase + kt, BsW0);
    GLOAD16(Wb + bbase + kt + (size_t)16 * NF, BsW1);
    __syncthreads();
    bf16x8 af[4], bfr[4];
#pragma unroll
    for (int m = 0; m < 4; ++m)
      af[m] = *(const bf16x8*)&As[(wr + m * 16 + rsel) * 32 + ksel];
#pragma unroll
    for (int n = 0; n < 4; ++n)
      bfr[n] = *(const bf16x8*)&Bs[(wc + n * 16 + rsel) * 32 + ksel];
#pragma unroll
    for (int m = 0; m < 4; ++m)
#pragma unroll
      for (int n = 0; n < 4; ++n)
        acc[m][n] = __builtin_amdgcn_mfma_f32_16x16x32_bf16(af[m], bfr[n], acc[m][n], 0, 0, 0);
    __syncthreads();
  }

  const int col0 = bn + wc + (lane & 15);
  const int row0 = bm + wr + (lane >> 4) * 4;
#pragma unroll
  for (int m = 0; m < 4; ++m) {
#pragma unroll
    for (int n = 0; n < 4; ++n) {
      int col = col0 + n * 16;
      float lbv = lb[col];
#pragma unroll
      for (int r = 0; r < 4; ++r) {
        int row = row0 + m * 16 + r;
        size_t oi = (size_t)row * NC + col;
        x1a[oi] = acc[m][n][r] + lbv + x1a[oi];
      }
    }
  }
}

// Windowed cross-attention, MFMA flash-style. bf16 output (feeds o-projection).
__global__ __launch_bounds__(256) void k_attn_mfma(
    const unsigned short* __restrict__ qbb,   // [8*2048][384] bf16 (q*scaling folded in W)
    const unsigned short* __restrict__ kbb,   // [8*512][384] bf16
    const unsigned short* __restrict__ vtb,   // [(b*2+h)*192+d][512] bf16
    unsigned short* __restrict__ o, int guided, float* __restrict__ gl) {
  __shared__ unsigned short lds[32768];
  const int tid = threadIdx.x;
  const int lane = tid & 63, wv = tid >> 6;
  const int rsel = lane & 15, ghi = lane >> 4;
  const int idx = blockIdx.x;
  const int tg = idx & 31;
  const int bh = idx >> 5;
  const int h = bh & 1, b = bh >> 1;
  const int t0 = tg * 64;
  const int c0 = t0 >> 2;
  int klo = c0 - 51; if (klo < 0) klo = 0;
  klo &= ~7;                       // 16B-align for global_load_lds on vtb
  if (klo > 384) klo = 384;        // keep window inside [0,512)

  // Q fragments: A-operand layout, row = lane&15, k = ghi*8 (+32 per step)
  const unsigned short* qrow = qbb + (size_t)(b * NT1 + t0 + wv * 16 + rsel) * NC + h * ND;
  bf16x8 qf[6];
#pragma unroll
  for (int kk = 0; kk < 6; ++kk)
    qf[kk] = *(const bf16x8*)(qrow + kk * 32 + ghi * 8);

  // stage K window [128 keys][192] bf16, source pre-swizzled (granule ^ row&7)
  {
    const size_t kbase = (size_t)(b * NT2 + klo) * NC + h * ND;
#pragma unroll
    for (int it = 0; it < 12; ++it) {
      int g = it * 256 + tid;
      int row = g / 24, go = g % 24;
      int gs = go ^ (row & 7);
      GLOAD16(kbb + kbase + (size_t)row * NC + gs * 8, &lds[(it * 256 + wv * 64) * 8]);
    }
  }
  __syncthreads();

  // QK^T: 16 queries x 128 keys per wave
  f32x4 accs[8] = {};
#pragma unroll
  for (int kk = 0; kk < 6; ++kk) {
#pragma unroll
    for (int n = 0; n < 8; ++n) {
      int row = n * 16 + rsel;
      bf16x8 bfr = *(const bf16x8*)&lds[row * 192 + (((kk * 4 + ghi) ^ (rsel & 7)) * 8)];
      accs[n] = __builtin_amdgcn_mfma_f32_16x16x32_bf16(qf[kk], bfr, accs[n], 0, 0, 0);
    }
  }

  // masked softmax per query row; rows live on 16-lane groups (row=ghi*4+r, col=rsel)
  unsigned short* pl = &lds[24576 + wv * 2048];
  float gacc = 0.f;
  const int t0w = t0 + wv * 16;
#pragma unroll
  for (int r = 0; r < 4; ++r) {
    int t = t0w + ghi * 4 + r;
    int c = t >> 2;
    int loq = c - 51; if (loq < 0) loq = 0;
    int hiq = c + 51; if (hiq > NT2) hiq = NT2;
    float sv[8];
    float mx = -1e30f;
#pragma unroll
    for (int n = 0; n < 8; ++n) {
      int j = klo + n * 16 + rsel;
      float s = (j >= loq && j < hiq) ? accs[n][r] : -1e30f;
      sv[n] = s; mx = fmaxf(mx, s);
    }
#pragma unroll
    for (int off = 1; off < 16; off <<= 1) mx = fmaxf(mx, __shfl_xor(mx, off));
    float e[8]; float se = 0.f;
#pragma unroll
    for (int n = 0; n < 8; ++n) { e[n] = __expf(sv[n] - mx); se += e[n]; }
#pragma unroll
    for (int off = 1; off < 16; off <<= 1) se += __shfl_xor(se, off);
    float inv = 1.f / se;
    int q = ghi * 4 + r;
#pragma unroll
    for (int n = 0; n < 8; ++n) {
      float pv = e[n] * inv;
      int klocal = n * 16 + rsel;
      pl[q * 128 + (((klocal >> 3) ^ (q & 7)) * 8) + (klocal & 7)] = f2bf(pv);
      if (guided) {
        int j = klo + klocal;
        float d = (float)j * (1.f / NT2) - (float)t * (1.f / NT1);
        gacc += pv * (1.f - __expf(-(d * d) * 5.5555555556f));
      }
    }
  }
  if (guided) {
    gacc = warp_sum(gacc);
    if (lane == 0) atomicAdd(gl, gacc * (1.f / 16777216.f));
  }
  __syncthreads();

  // stage VT window [192 chans][128 keys] bf16 into the K buffer (reuse)
  {
    const size_t vbase = ((size_t)(b * 2 + h) * ND) * NT2 + klo;
#pragma unroll
    for (int it = 0; it < 12; ++it) {
      int g = it * 256 + tid;
      int row = g >> 4, go = g & 15;
      int gs = go ^ (row & 7);
      GLOAD16(vtb + vbase + (size_t)row * NT2 + gs * 8, &lds[(it * 256 + wv * 64) * 8]);
    }
  }
  __syncthreads();

  // PV: P[16x128] @ V[128x192] -> O[16x192]
  f32x4 acco[12] = {};
#pragma unroll
  for (int kt = 0; kt < 4; ++kt) {
    bf16x8 pa = *(const bf16x8*)&pl[rsel * 128 + (((kt * 4 + ghi) ^ (rsel & 7)) * 8)];
#pragma unroll
    for (int n = 0; n < 12; ++n) {
      int row = n * 16 + rsel;
      bf16x8 bfr = *(const bf16x8*)&lds[row * 128 + (((kt * 4 + ghi) ^ (rsel & 7)) * 8)];
      acco[n] = __builtin_amdgcn_mfma_f32_16x16x32_bf16(pa, bfr, acco[n], 0, 0, 0);
    }
  }

  unsigned short* obase = o + (size_t)(b * NT1 + t0w + ghi * 4) * NC + h * ND;
#pragma unroll
  for (int n = 0; n < 12; ++n) {
#pragma unroll
    for (int r = 0; r < 4; ++r) {
      obase[(size_t)r * NC + n * 16 + rsel] = f2bf(acco[n][r]);
    }
  }
}

extern "C" void kernel_launch(void* const* d_in, const int* in_sizes, int n_in,
                              void* d_out, int out_size, void* d_ws, size_t ws_size,
                              hipStream_t stream) {
  (void)in_sizes; (void)n_in; (void)out_size; (void)ws_size;
  const float* x1    = (const float*)d_in[0];
  const float* x2    = (const float*)d_in[1];
  const float* alpha = (const float*)d_in[2];
  const float* ln1_g = (const float*)d_in[3];
  const float* ln1_b = (const float*)d_in[4];
  const float* qw    = (const float*)d_in[5];
  const float* kw    = (const float*)d_in[6];
  const float* vw    = (const float*)d_in[7];
  const float* ow    = (const float*)d_in[8];
  const float* ln2_g = (const float*)d_in[9];
  const float* ln2_b = (const float*)d_in[10];
  const float* cw    = (const float*)d_in[11];
  const float* cb    = (const float*)d_in[12];
  const float* lw    = (const float*)d_in[13];
  const float* lb    = (const float*)d_in[14];
  const float* lnf_g = (const float*)d_in[15];
  const float* lnf_b = (const float*)d_in[16];
  float* out = (float*)d_out;
  float* gl = out + 6291456;   // guided-loss scalar slot

  float* p = (float*)d_ws;
  float* x1a = p; p += 6291456;    // x1 state [16384,384] f32
  // bf16 region (16B-aligned)
  unsigned short* us = (unsigned short*)p;
  unsigned short* x2b  = us; us += 1572864;            // x2+pos bf16 [4096][384]
  unsigned short* tmpb = us; us += 6291456;            // LN1 out / attn out bf16
  unsigned short* ypad = us; us += 8 * TPAD * NC;      // 6316032
  unsigned short* cwpb = us; us += 2 * (size_t)NF * NKI;   // 10616832 (both layers)
  unsigned short* lwb  = us; us += 2 * (size_t)NC * NF;    // 1179648 (both layers)
  unsigned short* hb   = us; us += (size_t)16384 * NF; // 25165824
  unsigned short* qbb  = us; us += 6291456;            // q bf16 [16384][384]
  unsigned short* kbb  = us; us += 1572864;            // k bf16 [4096][384]
  unsigned short* vtb  = us; us += 1572864;            // v^T bf16 [32*192][512]
  unsigned short* qwb  = us; us += 294912;             // weights bf16 (contiguous qkvo)
  unsigned short* kwb  = us; us += 294912;
  unsigned short* vwb  = us; us += 294912;
  unsigned short* owb  = us; us += 294912;

  hipMemsetAsync(gl, 0, sizeof(float), stream);  // atomic accumulator, re-zeroed every launch
  k_zero_guard<<<96, 256, 0, stream>>>(ypad);
  k_add_pos2<<<12288, 256, 0, stream>>>(x1, alpha, x1a, NT1, 3145728);
  k_add_pos2_bf16<<<3072, 256, 0, stream>>>(x2, alpha, x2b, NT2, 786432);

  const float scaling = 0.07216878364870323f;   // 192^-0.5
  // weight conversions, both layers, hoisted + fused
  k_cvt_qkvo<<<4608, 256, 0, stream>>>(qw, kw, vw, ow, qwb, scaling);
  k_cvt<<<4608, 256, 0, stream>>>(lw, lwb, 1179648);
  k_pack_cw2<<<3072, 256, 0, stream>>>(cw, cwpb);

  for (int l = 0; l < 2; ++l) {
    k_ln_bf16<<<4096, 256, 0, stream>>>(x1a, ln1_g + l * 384, ln1_b + l * 384, tmpb);
    k_pgemm_qkv<<<dim3(3, 192), 256, 0, stream>>>(tmpb, x2b,
        qwb + (size_t)l * 147456, kwb + (size_t)l * 147456, vwb + (size_t)l * 147456,
        qbb, kbb, vtb);
    k_attn_mfma<<<512, 256, 0, stream>>>(qbb, kbb, vtb, tmpb, l == 0 ? 1 : 0, gl);
    k_pgemm_o<<<dim3(3, 128), 256, 0, stream>>>(tmpb, owb + (size_t)l * 147456, x1a);
    // FFN: ln2 -> bf16 padded, conv implicit GEMM (R2 dbuf), linear (MFMA)
    k_ln_bf16p<<<4096, 256, 0, stream>>>(x1a, ln2_g + l * 384, ln2_b + l * 384, ypad);
    k_conv_mfma<<<dim3(64, 12), 512, 0, stream>>>(ypad, cwpb + (size_t)l * 5308416, cb + l * 1536, hb);
    k_lin_mfma<<<dim3(3, 128), 256, 0, stream>>>(hb, lwb + (size_t)l * 589824, lb + l * 384, x1a);
  }
  k_ln<<<4096, 256, 0, stream>>>(x1a, lnf_g, lnf_b, out, 16384);
}

// Round 9
// 657.036 us; speedup vs baseline: 1.2096x; 1.0257x over previous
//
#include <hip/hip_runtime.h>
#include <math.h>

#define NB 8
#define NT1 2048
#define NT2 512
#define NC 384
#define ND 192
#define NF 1536
#define NKI 3456   // 9*384 implicit-GEMM K for conv
#define TPAD 2056  // 2048 + 4 guard rows top and bottom

typedef __attribute__((ext_vector_type(8))) short bf16x8;
typedef __attribute__((ext_vector_type(4))) float f32x4;

#define GLOAD16(gsrc, ldst) \
  __builtin_amdgcn_global_load_lds((const __attribute__((address_space(1))) void*)(gsrc), \
                                   (__attribute__((address_space(3))) void*)(ldst), 16, 0, 0)

static __device__ __forceinline__ unsigned short f2bf(float f) {
  unsigned int u = __float_as_uint(f);
  unsigned int r = (u + 0x7fffu + ((u >> 16) & 1u)) >> 16;
  return (unsigned short)r;
}

static __device__ __forceinline__ float warp_sum(float v) {
#pragma unroll
  for (int off = 32; off > 0; off >>= 1) v += __shfl_xor(v, off);
  return v;
}

// x += alpha * sin-pos; thread handles (t,j) pair: sin at c=j, cos at c=j+192
__global__ __launch_bounds__(256) void k_add_pos2(const float* __restrict__ x,
    const float* __restrict__ alpha_p, float* __restrict__ y, int T, int total2) {
  int i = blockIdx.x * 256 + threadIdx.x;
  if (i >= total2) return;
  int j = i % 192;
  int row = i / 192;
  int t = row % T;
  float freq = __expf(-0.0482216773f * (float)j);   // ln(10000)/191
  float ang = (float)(t + 1) * freq;
  float sn, cs;
  __sincosf(ang, &sn, &cs);
  float a = alpha_p[0];
  size_t base = (size_t)row * NC;
  y[base + j] = x[base + j] + a * sn;
  y[base + j + 192] = x[base + j + 192] + a * cs;
}

__global__ __launch_bounds__(256) void k_add_pos2_bf16(const float* __restrict__ x,
    const float* __restrict__ alpha_p, unsigned short* __restrict__ y, int T, int total2) {
  int i = blockIdx.x * 256 + threadIdx.x;
  if (i >= total2) return;
  int j = i % 192;
  int row = i / 192;
  int t = row % T;
  float freq = __expf(-0.0482216773f * (float)j);
  float ang = (float)(t + 1) * freq;
  float sn, cs;
  __sincosf(ang, &sn, &cs);
  float a = alpha_p[0];
  size_t base = (size_t)row * NC;
  y[base + j] = f2bf(x[base + j] + a * sn);
  y[base + j + 192] = f2bf(x[base + j + 192] + a * cs);
}

// LayerNorm over last dim (384). One wave per row. fp32 out (final LN).
__global__ __launch_bounds__(256) void k_ln(const float* __restrict__ x,
    const float* __restrict__ g, const float* __restrict__ b,
    float* __restrict__ y, int nrows) {
  int row = blockIdx.x * 4 + (threadIdx.x >> 6);
  int lane = threadIdx.x & 63;
  if (row >= nrows) return;
  const float* xr = x + (size_t)row * NC;
  float v[6];
  float s = 0.f, s2 = 0.f;
#pragma unroll
  for (int i = 0; i < 6; ++i) {
    float t = xr[lane + 64 * i];
    v[i] = t; s += t; s2 += t * t;
  }
  s = warp_sum(s); s2 = warp_sum(s2);
  float mean = s * (1.f / NC);
  float var = s2 * (1.f / NC) - mean * mean;
  float rs = rsqrtf(var + 1e-5f);
  float* yr = y + (size_t)row * NC;
#pragma unroll
  for (int i = 0; i < 6; ++i) {
    int cc = lane + 64 * i;
    yr[cc] = (v[i] - mean) * rs * g[cc] + b[cc];
  }
}

// LayerNorm -> bf16 (unpadded), feeds MFMA projections
__global__ __launch_bounds__(256) void k_ln_bf16(const float* __restrict__ x,
    const float* __restrict__ g, const float* __restrict__ b,
    unsigned short* __restrict__ y) {
  int row = blockIdx.x * 4 + (threadIdx.x >> 6);
  int lane = threadIdx.x & 63;
  const float* xr = x + (size_t)row * NC;
  float v[6];
  float s = 0.f, s2 = 0.f;
#pragma unroll
  for (int i = 0; i < 6; ++i) {
    float t = xr[lane + 64 * i];
    v[i] = t; s += t; s2 += t * t;
  }
  s = warp_sum(s); s2 = warp_sum(s2);
  float mean = s * (1.f / NC);
  float var = s2 * (1.f / NC) - mean * mean;
  float rs = rsqrtf(var + 1e-5f);
  unsigned short* yr = y + (size_t)row * NC;
#pragma unroll
  for (int i = 0; i < 6; ++i) {
    int cc = lane + 64 * i;
    yr[cc] = f2bf((v[i] - mean) * rs * g[cc] + b[cc]);
  }
}

// LayerNorm -> bf16 into guard-padded [8][2056][384] buffer (row t -> t+4)
__global__ __launch_bounds__(256) void k_ln_bf16p(const float* __restrict__ x,
    const float* __restrict__ g, const float* __restrict__ b,
    unsigned short* __restrict__ ypad) {
  int row = blockIdx.x * 4 + (threadIdx.x >> 6);
  int lane = threadIdx.x & 63;
  const float* xr = x + (size_t)row * NC;
  float v[6];
  float s = 0.f, s2 = 0.f;
#pragma unroll
  for (int i = 0; i < 6; ++i) {
    float t = xr[lane + 64 * i];
    v[i] = t; s += t; s2 += t * t;
  }
  s = warp_sum(s); s2 = warp_sum(s2);
  float mean = s * (1.f / NC);
  float var = s2 * (1.f / NC) - mean * mean;
  float rs = rsqrtf(var + 1e-5f);
  int bb = row >> 11, t = row & 2047;
  unsigned short* yr = ypad + ((size_t)(bb * TPAD + t + 4)) * NC;
#pragma unroll
  for (int i = 0; i < 6; ++i) {
    int cc = lane + 64 * i;
    yr[cc] = f2bf((v[i] - mean) * rs * g[cc] + b[cc]);
  }
}

// zero the 4 guard rows top+bottom of each batch slab in ypad
__global__ __launch_bounds__(256) void k_zero_guard(unsigned short* __restrict__ ypad) {
  int i = blockIdx.x * 256 + threadIdx.x;   // 8*8*384 = 24576
  if (i >= 24576) return;
  int c = i % NC;
  int r = (i / NC) % 8;
  int b = i / (NC * 8);
  int t = (r < 4) ? r : (2048 + r);         // rows 0..3 and 2052..2055
  ypad[((size_t)b * TPAD + t) * NC + c] = 0;
}

// pack + convert cw[f][c][kk] -> cwp[f][kk*384+c] bf16. One block per f-row,
// coalesced load -> LDS -> coalesced store (LDS read stride 9: conflict-free).
__global__ __launch_bounds__(256) void k_pack_cw2(const float* __restrict__ cw,
    unsigned short* __restrict__ cwp) {
  __shared__ float s[NKI];
  int f = blockIdx.x;
  const float* src = cw + (size_t)f * NKI;
  for (int i = threadIdx.x; i < NKI; i += 256) s[i] = src[i];
  __syncthreads();
  unsigned short* dst = cwp + (size_t)f * NKI;
  for (int i = threadIdx.x; i < NKI; i += 256) {
    int kk = i / NC, cc = i - kk * NC;
    dst[i] = f2bf(s[cc * 9 + kk]);
  }
}

// fused qkvo weight convert: dst = [qwb|kwb|vwb|owb] contiguous, q scaled
__global__ __launch_bounds__(256) void k_cvt_qkvo(const float* __restrict__ qw,
    const float* __restrict__ kw, const float* __restrict__ vw,
    const float* __restrict__ ow, unsigned short* __restrict__ dst, float qscale) {
  int i = blockIdx.x * 256 + threadIdx.x;
  if (i >= 4 * 294912) return;
  int w = i / 294912;
  int j = i - w * 294912;
  const float* s = (w == 0) ? qw : (w == 1) ? kw : (w == 2) ? vw : ow;
  float sc = (w == 0) ? qscale : 1.f;
  dst[i] = f2bf(s[j] * sc);
}

// fp32 -> bf16 plain
__global__ __launch_bounds__(256) void k_cvt(const float* __restrict__ x,
    unsigned short* __restrict__ y, int n) {
  int i = blockIdx.x * 256 + threadIdx.x;
  if (i < n) y[i] = f2bf(x[i]);
}

// Shared 128x128 GEMM inner loop, R2-proven structure: BK=64, double-buffered
// LDS, distance-2 prefetch, counted vmcnt(8) (8 loads/thread/tile, never 0
// mid-loop), granule-XOR swizzle (pre-swizzled global src + XOR'd ds_read).
// A rows bm..bm+127 of [*,K]; W rows bn..bn+127 of [*,K]. 256 threads, 4 waves
// (2M x 2N, 64x64 per wave). Accumulation order identical to the old BK=32
// loop (k = 0,32,64,... sequential) -> bitwise-identical results.
static __device__ __forceinline__ void gemm128_db(
    const unsigned short* __restrict__ A,
    const unsigned short* __restrict__ W,
    int K, int ntiles, int bm, int bn,
    unsigned short* AsB, unsigned short* BsB,
    f32x4 (&acc)[4][4]) {
  const int tid = threadIdx.x;
  const int lane = tid & 63, wv = tid >> 6;
  const int rsel = lane & 15, ghi = lane >> 4;
  const int l8 = lane >> 3, g8 = lane & 7;
  const int gsrc = (g8 ^ l8) * 8;              // pre-swizzled source granule
  const size_t abase = (size_t)(bm + wv * 32 + l8) * K + gsrc;
  const size_t bbase = (size_t)(bn + wv * 32 + l8) * K + gsrc;

#define GDB_STAGE(T, DB)                                                        \
  {                                                                             \
    const size_t k_ = (size_t)(T) * 64;                                         \
    GLOAD16(A + abase + k_, AsB + (DB) * 8192 + (wv * 32) * 64);                \
    GLOAD16(A + abase + k_ + (size_t)8 * K, AsB + (DB) * 8192 + (wv * 32 + 8) * 64);   \
    GLOAD16(A + abase + k_ + (size_t)16 * K, AsB + (DB) * 8192 + (wv * 32 + 16) * 64); \
    GLOAD16(A + abase + k_ + (size_t)24 * K, AsB + (DB) * 8192 + (wv * 32 + 24) * 64); \
    GLOAD16(W + bbase + k_, BsB + (DB) * 8192 + (wv * 32) * 64);                \
    GLOAD16(W + bbase + k_ + (size_t)8 * K, BsB + (DB) * 8192 + (wv * 32 + 8) * 64);   \
    GLOAD16(W + bbase + k_ + (size_t)16 * K, BsB + (DB) * 8192 + (wv * 32 + 16) * 64); \
    GLOAD16(W + bbase + k_ + (size_t)24 * K, BsB + (DB) * 8192 + (wv * 32 + 24) * 64); \
  }

  // prologue: stage tiles 0 and 1 (16 loads); wait the 8 oldest = tile 0
  GDB_STAGE(0, 0);
  GDB_STAGE(1, 1);
  asm volatile("s_waitcnt vmcnt(8)" ::: "memory");
  __builtin_amdgcn_sched_barrier(0);
  __builtin_amdgcn_s_barrier();

  const int arow = (wv >> 1) * 64;
  const int brow = (wv & 1) * 64;
  int db = 0;
  for (int t = 0; t < ntiles; ++t) {
    bf16x8 af[4][2], bfr[4][2];
#pragma unroll
    for (int m = 0; m < 4; ++m) {
      int r = arow + m * 16 + rsel;
#pragma unroll
      for (int k = 0; k < 2; ++k)
        af[m][k] = *(const bf16x8*)&AsB[db * 8192 + r * 64 + (((k * 4 + ghi) ^ (r & 7)) * 8)];
    }
#pragma unroll
    for (int n = 0; n < 4; ++n) {
      int r = brow + n * 16 + rsel;
#pragma unroll
      for (int k = 0; k < 2; ++k)
        bfr[n][k] = *(const bf16x8*)&BsB[db * 8192 + r * 64 + (((k * 4 + ghi) ^ (r & 7)) * 8)];
    }
    __builtin_amdgcn_s_setprio(1);
#pragma unroll
    for (int m = 0; m < 4; ++m)
#pragma unroll
      for (int n = 0; n < 4; ++n)
        acc[m][n] = __builtin_amdgcn_mfma_f32_16x16x32_bf16(af[m][0], bfr[n][0], acc[m][n], 0, 0, 0);
    __builtin_amdgcn_s_setprio(0);
    __builtin_amdgcn_sched_barrier(0);
    asm volatile("s_waitcnt lgkmcnt(0)" ::: "memory");   // all reads of buf[db] done
    __builtin_amdgcn_sched_barrier(0);
    __builtin_amdgcn_s_barrier();                        // ... in every wave
    if (t + 2 < ntiles) GDB_STAGE(t + 2, db);            // safe: buf[db] free now
    __builtin_amdgcn_s_setprio(1);
#pragma unroll
    for (int m = 0; m < 4; ++m)
#pragma unroll
      for (int n = 0; n < 4; ++n)
        acc[m][n] = __builtin_amdgcn_mfma_f32_16x16x32_bf16(af[m][1], bfr[n][1], acc[m][n], 0, 0, 0);
    __builtin_amdgcn_s_setprio(0);
    __builtin_amdgcn_sched_barrier(0);
    if (t + 2 < ntiles) {
      asm volatile("s_waitcnt vmcnt(8)" ::: "memory");   // tile t+1 landed; t+2 flying
    } else {
      asm volatile("s_waitcnt vmcnt(0)" ::: "memory");   // epilogue drain
    }
    __builtin_amdgcn_sched_barrier(0);
    __builtin_amdgcn_s_barrier();
    db ^= 1;
  }
#undef GDB_STAGE
}

// Merged q/k/v projection GEMM, one launch. grid (3, 192):
//   y in [0,128): q = LN1(x1) @ qw^T  -> qbb row-major      (M=16384)
//   y in [128,160): k = x2b @ kw^T    -> kbb row-major      (M=4096)
//   y in [160,192): v = x2b @ vw^T    -> vtb transposed     (M=4096)
__global__ __launch_bounds__(256) void k_pgemm_qkv(
    const unsigned short* __restrict__ Aq,
    const unsigned short* __restrict__ Akv,
    const unsigned short* __restrict__ Wq,
    const unsigned short* __restrict__ Wk,
    const unsigned short* __restrict__ Wv,
    unsigned short* __restrict__ Qb,
    unsigned short* __restrict__ Kb,
    unsigned short* __restrict__ Vtb) {
  __shared__ unsigned short As[2 * 8192];
  __shared__ unsigned short Bs[2 * 8192];
  const int y = blockIdx.y;
  const int which = (y < 128) ? 0 : (y < 160) ? 1 : 2;
  const unsigned short* A = (which == 0) ? Aq : Akv;
  const unsigned short* W = (which == 0) ? Wq : (which == 1) ? Wk : Wv;
  const int bm = ((which == 0) ? y : (which == 1) ? (y - 128) : (y - 160)) * 128;
  const int bn = blockIdx.x * 128;
  f32x4 acc[4][4] = {};
  gemm128_db(A, W, NC, 6, bm, bn, As, Bs, acc);

  const int lane = threadIdx.x & 63, wv = threadIdx.x >> 6;
  const int col0 = bn + (wv & 1) * 64 + (lane & 15);
  const int row0 = bm + (wv >> 1) * 64 + (lane >> 4) * 4;
#pragma unroll
  for (int m = 0; m < 4; ++m) {
#pragma unroll
    for (int n = 0; n < 4; ++n) {
      int col = col0 + n * 16;
#pragma unroll
      for (int r = 0; r < 4; ++r) {
        int row = row0 + m * 16 + r;
        unsigned short bv = f2bf(acc[m][n][r]);
        if (which == 0) {
          Qb[(size_t)row * NC + col] = bv;
        } else if (which == 1) {
          Kb[(size_t)row * NC + col] = bv;
        } else {
          // vtb[(b*384 + col)*512 + j], b = row>>9, j = row&511
          Vtb[((size_t)((row >> 9) * 384 + col)) * 512 + (row & 511)] = bv;
        }
      }
    }
  }
}

// o-projection GEMM: x1a += attn @ ow^T (fused residual).
__global__ __launch_bounds__(256) void k_pgemm_o(
    const unsigned short* __restrict__ A,
    const unsigned short* __restrict__ W,
    float* __restrict__ Cf) {
  __shared__ unsigned short As[2 * 8192];
  __shared__ unsigned short Bs[2 * 8192];
  const int bn = blockIdx.x * 128;
  const int bm = blockIdx.y * 128;
  f32x4 acc[4][4] = {};
  gemm128_db(A, W, NC, 6, bm, bn, As, Bs, acc);

  const int lane = threadIdx.x & 63, wv = threadIdx.x >> 6;
  const int col0 = bn + (wv & 1) * 64 + (lane & 15);
  const int row0 = bm + (wv >> 1) * 64 + (lane >> 4) * 4;
#pragma unroll
  for (int m = 0; m < 4; ++m) {
#pragma unroll
    for (int n = 0; n < 4; ++n) {
      int col = col0 + n * 16;
#pragma unroll
      for (int r = 0; r < 4; ++r) {
        int row = row0 + m * 16 + r;
        size_t oi = (size_t)row * NC + col;
        Cf[oi] = acc[m][n][r] + Cf[oi];
      }
    }
  }
}

// FFN linear: x1a[m][n] += H[m][:]@lw[n][:] + lb[n].
__global__ __launch_bounds__(256) void k_lin_mfma(
    const unsigned short* __restrict__ H,
    const unsigned short* __restrict__ Wb,
    const float* __restrict__ lb,
    float* __restrict__ x1a) {
  __shared__ unsigned short As[2 * 8192];
  __shared__ unsigned short Bs[2 * 8192];
  const int bn = blockIdx.x * 128;
  const int bm = blockIdx.y * 128;
  f32x4 acc[4][4] = {};
  gemm128_db(H, Wb, NF, 24, bm, bn, As, Bs, acc);

  const int lane = threadIdx.x & 63, wv = threadIdx.x >> 6;
  const int col0 = bn + (wv & 1) * 64 + (lane & 15);
  const int row0 = bm + (wv >> 1) * 64 + (lane >> 4) * 4;
#pragma unroll
  for (int m = 0; m < 4; ++m) {
#pragma unroll
    for (int n = 0; n < 4; ++n) {
      int col = col0 + n * 16;
      float lbv = lb[col];
#pragma unroll
      for (int r = 0; r < 4; ++r) {
        int row = row0 + m * 16 + r;
        size_t oi = (size_t)row * NC + col;
        x1a[oi] = acc[m][n][r] + lbv + x1a[oi];
      }
    }
  }
}

// Conv1d(C->4C,k=9,SAME) implicit GEMM. 256x128 tile, BK=64, 8 waves (4Mx2N),
// double-buffered LDS, distance-2 prefetch with counted vmcnt (never 0 mid-loop),
// granule-XOR swizzle (pre-swizzled global src + XOR'd ds_read).
// Fused (+cb)*9^-0.5 -> gelu(exact) -> bf16 store.  [R2 structure: 204 us]
__global__ __launch_bounds__(512) void k_conv_mfma(
    const unsigned short* __restrict__ Ypad,
    const unsigned short* __restrict__ Wp,
    const float* __restrict__ cb,
    unsigned short* __restrict__ H) {
  __shared__ unsigned short As[2][256 * 64];   // 64 KB
  __shared__ unsigned short Bs[2][128 * 64];   // 32 KB
  const int bm = blockIdx.x * 256;             // bm-fastest: XCD=id%8, A panels L2-hot
  const int bn = blockIdx.y * 128;
  const int b = bm >> 11, t0 = bm & 2047;
  const int tid = threadIdx.x;
  const int lane = tid & 63, wv = tid >> 6;
  const int wvM = wv >> 1, wvN = wv & 1;
  const int rsel = lane & 15, ghi = lane >> 4;
  const int l8 = lane >> 3, g8 = lane & 7;
  const int gsrc = (g8 ^ l8) * 8;              // pre-swizzled source granule (shorts)

  f32x4 acc[4][4] = {};

  const size_t arow0 = (size_t)(b * TPAD + t0 + wv * 32 + l8);   // A stage row (lane)
  const size_t brow0 = (size_t)(bn + wv * 16 + l8);              // B stage row (lane)

#define CONV_STAGE(T, DB)                                                     \
  {                                                                           \
    const int kt_ = (T) * 64;                                                 \
    const int kk_ = kt_ / NC;                                                 \
    const int c0_ = kt_ - kk_ * NC;                                           \
    const size_t asrc_ = (arow0 + kk_) * NC + c0_ + gsrc;                     \
    GLOAD16(Ypad + asrc_, &As[DB][(wv * 32) * 64]);                           \
    GLOAD16(Ypad + asrc_ + (size_t)8 * NC, &As[DB][(wv * 32 + 8) * 64]);      \
    GLOAD16(Ypad + asrc_ + (size_t)16 * NC, &As[DB][(wv * 32 + 16) * 64]);    \
    GLOAD16(Ypad + asrc_ + (size_t)24 * NC, &As[DB][(wv * 32 + 24) * 64]);    \
    const size_t bsrc_ = brow0 * NKI + kt_ + gsrc;                            \
    GLOAD16(Wp + bsrc_, &Bs[DB][(wv * 16) * 64]);                             \
    GLOAD16(Wp + bsrc_ + (size_t)8 * NKI, &Bs[DB][(wv * 16 + 8) * 64]);       \
  }

  // prologue: stage tiles 0 and 1 (12 loads); wait the 6 oldest = tile 0
  CONV_STAGE(0, 0);
  CONV_STAGE(1, 1);
  asm volatile("s_waitcnt vmcnt(6)" ::: "memory");
  __builtin_amdgcn_sched_barrier(0);
  __builtin_amdgcn_s_barrier();

  const int arow = wvM * 64;
  const int brow = wvN * 64;
  int db = 0;
  for (int t = 0; t < 54; ++t) {
    bf16x8 af[4][2], bfr[4][2];
#pragma unroll
    for (int m = 0; m < 4; ++m) {
      int r = arow + m * 16 + rsel;
#pragma unroll
      for (int k = 0; k < 2; ++k)
        af[m][k] = *(const bf16x8*)&As[db][r * 64 + (((k * 4 + ghi) ^ (r & 7)) * 8)];
    }
#pragma unroll
    for (int n = 0; n < 4; ++n) {
      int r = brow + n * 16 + rsel;
#pragma unroll
      for (int k = 0; k < 2; ++k)
        bfr[n][k] = *(const bf16x8*)&Bs[db][r * 64 + (((k * 4 + ghi) ^ (r & 7)) * 8)];
    }
    __builtin_amdgcn_s_setprio(1);
#pragma unroll
    for (int m = 0; m < 4; ++m)
#pragma unroll
      for (int n = 0; n < 4; ++n)
        acc[m][n] = __builtin_amdgcn_mfma_f32_16x16x32_bf16(af[m][0], bfr[n][0], acc[m][n], 0, 0, 0);
    __builtin_amdgcn_s_setprio(0);
    __builtin_amdgcn_sched_barrier(0);
    asm volatile("s_waitcnt lgkmcnt(0)" ::: "memory");   // all reads of buf[db] done
    __builtin_amdgcn_sched_barrier(0);
    __builtin_amdgcn_s_barrier();                        // ... in every wave
    if (t + 2 < 54) CONV_STAGE(t + 2, db);               // safe: buf[db] free now
    __builtin_amdgcn_s_setprio(1);
#pragma unroll
    for (int m = 0; m < 4; ++m)
#pragma unroll
      for (int n = 0; n < 4; ++n)
        acc[m][n] = __builtin_amdgcn_mfma_f32_16x16x32_bf16(af[m][1], bfr[n][1], acc[m][n], 0, 0, 0);
    __builtin_amdgcn_s_setprio(0);
    __builtin_amdgcn_sched_barrier(0);
    if (t + 2 < 54) {
      asm volatile("s_waitcnt vmcnt(6)" ::: "memory");   // all t+1 landed; t+2 in flight
    } else {
      asm volatile("s_waitcnt vmcnt(0)" ::: "memory");   // epilogue drain
    }
    __builtin_amdgcn_sched_barrier(0);
    __builtin_amdgcn_s_barrier();
    db ^= 1;
  }
#undef CONV_STAGE

  const int col0 = bn + wvN * 64 + rsel;
  const int row0 = bm + wvM * 64 + ghi * 4;
#pragma unroll
  for (int m = 0; m < 4; ++m) {
#pragma unroll
    for (int n = 0; n < 4; ++n) {
      int col = col0 + n * 16;
      float cbv = cb[col];
#pragma unroll
      for (int r = 0; r < 4; ++r) {
        int row = row0 + m * 16 + r;
        float xv = (acc[m][n][r] + cbv) * 0.33333333333333333f;
        float ge = 0.5f * xv * (1.f + erff(xv * 0.70710678118654752f));
        H[(size_t)row * NF + col] = f2bf(ge);
      }
    }
  }
}

// Windowed cross-attention, MFMA flash-style. bf16 output (feeds o-projection).
__global__ __launch_bounds__(256) void k_attn_mfma(
    const unsigned short* __restrict__ qbb,   // [8*2048][384] bf16 (q*scaling folded in W)
    const unsigned short* __restrict__ kbb,   // [8*512][384] bf16
    const unsigned short* __restrict__ vtb,   // [(b*2+h)*192+d][512] bf16
    unsigned short* __restrict__ o, int guided, float* __restrict__ gl) {
  __shared__ unsigned short lds[32768];
  const int tid = threadIdx.x;
  const int lane = tid & 63, wv = tid >> 6;
  const int rsel = lane & 15, ghi = lane >> 4;
  const int idx = blockIdx.x;
  const int tg = idx & 31;
  const int bh = idx >> 5;
  const int h = bh & 1, b = bh >> 1;
  const int t0 = tg * 64;
  const int c0 = t0 >> 2;
  int klo = c0 - 51; if (klo < 0) klo = 0;
  klo &= ~7;                       // 16B-align for global_load_lds on vtb
  if (klo > 384) klo = 384;        // keep window inside [0,512)

  // Q fragments: A-operand layout, row = lane&15, k = ghi*8 (+32 per step)
  const unsigned short* qrow = qbb + (size_t)(b * NT1 + t0 + wv * 16 + rsel) * NC + h * ND;
  bf16x8 qf[6];
#pragma unroll
  for (int kk = 0; kk < 6; ++kk)
    qf[kk] = *(const bf16x8*)(qrow + kk * 32 + ghi * 8);

  // stage K window [128 keys][192] bf16, source pre-swizzled (granule ^ row&7)
  {
    const size_t kbase = (size_t)(b * NT2 + klo) * NC + h * ND;
#pragma unroll
    for (int it = 0; it < 12; ++it) {
      int g = it * 256 + tid;
      int row = g / 24, go = g % 24;
      int gs = go ^ (row & 7);
      GLOAD16(kbb + kbase + (size_t)row * NC + gs * 8, &lds[(it * 256 + wv * 64) * 8]);
    }
  }
  __syncthreads();

  // QK^T: 16 queries x 128 keys per wave
  f32x4 accs[8] = {};
#pragma unroll
  for (int kk = 0; kk < 6; ++kk) {
#pragma unroll
    for (int n = 0; n < 8; ++n) {
      int row = n * 16 + rsel;
      bf16x8 bfr = *(const bf16x8*)&lds[row * 192 + (((kk * 4 + ghi) ^ (rsel & 7)) * 8)];
      accs[n] = __builtin_amdgcn_mfma_f32_16x16x32_bf16(qf[kk], bfr, accs[n], 0, 0, 0);
    }
  }

  // masked softmax per query row; rows live on 16-lane groups (row=ghi*4+r, col=rsel)
  unsigned short* pl = &lds[24576 + wv * 2048];
  float gacc = 0.f;
  const int t0w = t0 + wv * 16;
#pragma unroll
  for (int r = 0; r < 4; ++r) {
    int t = t0w + ghi * 4 + r;
    int c = t >> 2;
    int loq = c - 51; if (loq < 0) loq = 0;
    int hiq = c + 51; if (hiq > NT2) hiq = NT2;
    float sv[8];
    float mx = -1e30f;
#pragma unroll
    for (int n = 0; n < 8; ++n) {
      int j = klo + n * 16 + rsel;
      float s = (j >= loq && j < hiq) ? accs[n][r] : -1e30f;
      sv[n] = s; mx = fmaxf(mx, s);
    }
#pragma unroll
    for (int off = 1; off < 16; off <<= 1) mx = fmaxf(mx, __shfl_xor(mx, off));
    float e[8]; float se = 0.f;
#pragma unroll
    for (int n = 0; n < 8; ++n) { e[n] = __expf(sv[n] - mx); se += e[n]; }
#pragma unroll
    for (int off = 1; off < 16; off <<= 1) se += __shfl_xor(se, off);
    float inv = 1.f / se;
    int q = ghi * 4 + r;
#pragma unroll
    for (int n = 0; n < 8; ++n) {
      float pv = e[n] * inv;
      int klocal = n * 16 + rsel;
      pl[q * 128 + (((klocal >> 3) ^ (q & 7)) * 8) + (klocal & 7)] = f2bf(pv);
      if (guided) {
        int j = klo + klocal;
        float d = (float)j * (1.f / NT2) - (float)t * (1.f / NT1);
        gacc += pv * (1.f - __expf(-(d * d) * 5.5555555556f));
      }
    }
  }
  if (guided) {
    gacc = warp_sum(gacc);
    if (lane == 0) atomicAdd(gl, gacc * (1.f / 16777216.f));
  }
  __syncthreads();

  // stage VT window [192 chans][128 keys] bf16 into the K buffer (reuse)
  {
    const size_t vbase = ((size_t)(b * 2 + h) * ND) * NT2 + klo;
#pragma unroll
    for (int it = 0; it < 12; ++it) {
      int g = it * 256 + tid;
      int row = g >> 4, go = g & 15;
      int gs = go ^ (row & 7);
      GLOAD16(vtb + vbase + (size_t)row * NT2 + gs * 8, &lds[(it * 256 + wv * 64) * 8]);
    }
  }
  __syncthreads();

  // PV: P[16x128] @ V[128x192] -> O[16x192]
  f32x4 acco[12] = {};
#pragma unroll
  for (int kt = 0; kt < 4; ++kt) {
    bf16x8 pa = *(const bf16x8*)&pl[rsel * 128 + (((kt * 4 + ghi) ^ (rsel & 7)) * 8)];
#pragma unroll
    for (int n = 0; n < 12; ++n) {
      int row = n * 16 + rsel;
      bf16x8 bfr = *(const bf16x8*)&lds[row * 128 + (((kt * 4 + ghi) ^ (rsel & 7)) * 8)];
      acco[n] = __builtin_amdgcn_mfma_f32_16x16x32_bf16(pa, bfr, acco[n], 0, 0, 0);
    }
  }

  unsigned short* obase = o + (size_t)(b * NT1 + t0w + ghi * 4) * NC + h * ND;
#pragma unroll
  for (int n = 0; n < 12; ++n) {
#pragma unroll
    for (int r = 0; r < 4; ++r) {
      obase[(size_t)r * NC + n * 16 + rsel] = f2bf(acco[n][r]);
    }
  }
}

extern "C" void kernel_launch(void* const* d_in, const int* in_sizes, int n_in,
                              void* d_out, int out_size, void* d_ws, size_t ws_size,
                              hipStream_t stream) {
  (void)in_sizes; (void)n_in; (void)out_size; (void)ws_size;
  const float* x1    = (const float*)d_in[0];
  const float* x2    = (const float*)d_in[1];
  const float* alpha = (const float*)d_in[2];
  const float* ln1_g = (const float*)d_in[3];
  const float* ln1_b = (const float*)d_in[4];
  const float* qw    = (const float*)d_in[5];
  const float* kw    = (const float*)d_in[6];
  const float* vw    = (const float*)d_in[7];
  const float* ow    = (const float*)d_in[8];
  const float* ln2_g = (const float*)d_in[9];
  const float* ln2_b = (const float*)d_in[10];
  const float* cw    = (const float*)d_in[11];
  const float* cb    = (const float*)d_in[12];
  const float* lw    = (const float*)d_in[13];
  const float* lb    = (const float*)d_in[14];
  const float* lnf_g = (const float*)d_in[15];
  const float* lnf_b = (const float*)d_in[16];
  float* out = (float*)d_out;
  float* gl = out + 6291456;   // guided-loss scalar slot

  float* p = (float*)d_ws;
  float* x1a = p; p += 6291456;    // x1 state [16384,384] f32
  // bf16 region (16B-aligned)
  unsigned short* us = (unsigned short*)p;
  unsigned short* x2b  = us; us += 1572864;            // x2+pos bf16 [4096][384]
  unsigned short* tmpb = us; us += 6291456;            // LN1 out / attn out bf16
  unsigned short* ypad = us; us += 8 * TPAD * NC;      // 6316032
  unsigned short* cwpb = us; us += 2 * (size_t)NF * NKI;   // 10616832 (both layers)
  unsigned short* lwb  = us; us += 2 * (size_t)NC * NF;    // 1179648 (both layers)
  unsigned short* hb   = us; us += (size_t)16384 * NF; // 25165824
  unsigned short* qbb  = us; us += 6291456;            // q bf16 [16384][384]
  unsigned short* kbb  = us; us += 1572864;            // k bf16 [4096][384]
  unsigned short* vtb  = us; us += 1572864;            // v^T bf16 [32*192][512]
  unsigned short* qwb  = us; us += 294912;             // weights bf16 (contiguous qkvo)
  unsigned short* kwb  = us; us += 294912;
  unsigned short* vwb  = us; us += 294912;
  unsigned short* owb  = us; us += 294912;

  hipMemsetAsync(gl, 0, sizeof(float), stream);  // atomic accumulator, re-zeroed every launch
  k_zero_guard<<<96, 256, 0, stream>>>(ypad);
  k_add_pos2<<<12288, 256, 0, stream>>>(x1, alpha, x1a, NT1, 3145728);
  k_add_pos2_bf16<<<3072, 256, 0, stream>>>(x2, alpha, x2b, NT2, 786432);

  const float scaling = 0.07216878364870323f;   // 192^-0.5
  // weight conversions, both layers, hoisted + fused
  k_cvt_qkvo<<<4608, 256, 0, stream>>>(qw, kw, vw, ow, qwb, scaling);
  k_cvt<<<4608, 256, 0, stream>>>(lw, lwb, 1179648);
  k_pack_cw2<<<3072, 256, 0, stream>>>(cw, cwpb);

  for (int l = 0; l < 2; ++l) {
    k_ln_bf16<<<4096, 256, 0, stream>>>(x1a, ln1_g + l * 384, ln1_b + l * 384, tmpb);
    k_pgemm_qkv<<<dim3(3, 192), 256, 0, stream>>>(tmpb, x2b,
        qwb + (size_t)l * 147456, kwb + (size_t)l * 147456, vwb + (size_t)l * 147456,
        qbb, kbb, vtb);
    k_attn_mfma<<<512, 256, 0, stream>>>(qbb, kbb, vtb, tmpb, l == 0 ? 1 : 0, gl);
    k_pgemm_o<<<dim3(3, 128), 256, 0, stream>>>(tmpb, owb + (size_t)l * 147456, x1a);
    // FFN: ln2 -> bf16 padded, conv implicit GEMM (R2 dbuf), linear (dbuf MFMA)
    k_ln_bf16p<<<4096, 256, 0, stream>>>(x1a, ln2_g + l * 384, ln2_b + l * 384, ypad);
    k_conv_mfma<<<dim3(64, 12), 512, 0, stream>>>(ypad, cwpb + (size_t)l * 5308416, cb + l * 1536, hb);
    k_lin_mfma<<<dim3(3, 128), 256, 0, stream>>>(hb, lwb + (size_t)l * 589824, lb + l * 384, x1a);
  }
  k_ln<<<4096, 256, 0, stream>>>(x1a, lnf_g, lnf_b, out, 16384);
}

// Round 10
// 636.548 us; speedup vs baseline: 1.2486x; 1.0322x over previous
//
#include <hip/hip_runtime.h>
#include <math.h>

#define NB 8
#define NT1 2048
#define NT2 512
#define NC 384
#define ND 192
#define NF 1536
#define NKI 3456   // 9*384 implicit-GEMM K for conv
#define TPAD 2056  // 2048 + 4 guard rows top and bottom

typedef __attribute__((ext_vector_type(8))) short bf16x8;
typedef __attribute__((ext_vector_type(4))) float f32x4;

#define GLOAD16(gsrc, ldst) \
  __builtin_amdgcn_global_load_lds((const __attribute__((address_space(1))) void*)(gsrc), \
                                   (__attribute__((address_space(3))) void*)(ldst), 16, 0, 0)

static __device__ __forceinline__ unsigned short f2bf(float f) {
  unsigned int u = __float_as_uint(f);
  unsigned int r = (u + 0x7fffu + ((u >> 16) & 1u)) >> 16;
  return (unsigned short)r;
}

static __device__ __forceinline__ float warp_sum(float v) {
#pragma unroll
  for (int off = 32; off > 0; off >>= 1) v += __shfl_xor(v, off);
  return v;
}

// x += alpha * sin-pos; thread handles (t,j) pair: sin at c=j, cos at c=j+192
__global__ __launch_bounds__(256) void k_add_pos2(const float* __restrict__ x,
    const float* __restrict__ alpha_p, float* __restrict__ y, int T, int total2) {
  int i = blockIdx.x * 256 + threadIdx.x;
  if (i >= total2) return;
  int j = i % 192;
  int row = i / 192;
  int t = row % T;
  float freq = __expf(-0.0482216773f * (float)j);   // ln(10000)/191
  float ang = (float)(t + 1) * freq;
  float sn, cs;
  __sincosf(ang, &sn, &cs);
  float a = alpha_p[0];
  size_t base = (size_t)row * NC;
  y[base + j] = x[base + j] + a * sn;
  y[base + j + 192] = x[base + j + 192] + a * cs;
}

__global__ __launch_bounds__(256) void k_add_pos2_bf16(const float* __restrict__ x,
    const float* __restrict__ alpha_p, unsigned short* __restrict__ y, int T, int total2) {
  int i = blockIdx.x * 256 + threadIdx.x;
  if (i >= total2) return;
  int j = i % 192;
  int row = i / 192;
  int t = row % T;
  float freq = __expf(-0.0482216773f * (float)j);
  float ang = (float)(t + 1) * freq;
  float sn, cs;
  __sincosf(ang, &sn, &cs);
  float a = alpha_p[0];
  size_t base = (size_t)row * NC;
  y[base + j] = f2bf(x[base + j] + a * sn);
  y[base + j + 192] = f2bf(x[base + j + 192] + a * cs);
}

// LayerNorm over last dim (384). One wave per row. fp32 out (final LN).
__global__ __launch_bounds__(256) void k_ln(const float* __restrict__ x,
    const float* __restrict__ g, const float* __restrict__ b,
    float* __restrict__ y, int nrows) {
  int row = blockIdx.x * 4 + (threadIdx.x >> 6);
  int lane = threadIdx.x & 63;
  if (row >= nrows) return;
  const float* xr = x + (size_t)row * NC;
  float v[6];
  float s = 0.f, s2 = 0.f;
#pragma unroll
  for (int i = 0; i < 6; ++i) {
    float t = xr[lane + 64 * i];
    v[i] = t; s += t; s2 += t * t;
  }
  s = warp_sum(s); s2 = warp_sum(s2);
  float mean = s * (1.f / NC);
  float var = s2 * (1.f / NC) - mean * mean;
  float rs = rsqrtf(var + 1e-5f);
  float* yr = y + (size_t)row * NC;
#pragma unroll
  for (int i = 0; i < 6; ++i) {
    int cc = lane + 64 * i;
    yr[cc] = (v[i] - mean) * rs * g[cc] + b[cc];
  }
}

// LayerNorm -> bf16 (unpadded), feeds MFMA projections
__global__ __launch_bounds__(256) void k_ln_bf16(const float* __restrict__ x,
    const float* __restrict__ g, const float* __restrict__ b,
    unsigned short* __restrict__ y) {
  int row = blockIdx.x * 4 + (threadIdx.x >> 6);
  int lane = threadIdx.x & 63;
  const float* xr = x + (size_t)row * NC;
  float v[6];
  float s = 0.f, s2 = 0.f;
#pragma unroll
  for (int i = 0; i < 6; ++i) {
    float t = xr[lane + 64 * i];
    v[i] = t; s += t; s2 += t * t;
  }
  s = warp_sum(s); s2 = warp_sum(s2);
  float mean = s * (1.f / NC);
  float var = s2 * (1.f / NC) - mean * mean;
  float rs = rsqrtf(var + 1e-5f);
  unsigned short* yr = y + (size_t)row * NC;
#pragma unroll
  for (int i = 0; i < 6; ++i) {
    int cc = lane + 64 * i;
    yr[cc] = f2bf((v[i] - mean) * rs * g[cc] + b[cc]);
  }
}

// LayerNorm -> bf16 into guard-padded [8][2056][384] buffer (row t -> t+4)
__global__ __launch_bounds__(256) void k_ln_bf16p(const float* __restrict__ x,
    const float* __restrict__ g, const float* __restrict__ b,
    unsigned short* __restrict__ ypad) {
  int row = blockIdx.x * 4 + (threadIdx.x >> 6);
  int lane = threadIdx.x & 63;
  const float* xr = x + (size_t)row * NC;
  float v[6];
  float s = 0.f, s2 = 0.f;
#pragma unroll
  for (int i = 0; i < 6; ++i) {
    float t = xr[lane + 64 * i];
    v[i] = t; s += t; s2 += t * t;
  }
  s = warp_sum(s); s2 = warp_sum(s2);
  float mean = s * (1.f / NC);
  float var = s2 * (1.f / NC) - mean * mean;
  float rs = rsqrtf(var + 1e-5f);
  int bb = row >> 11, t = row & 2047;
  unsigned short* yr = ypad + ((size_t)(bb * TPAD + t + 4)) * NC;
#pragma unroll
  for (int i = 0; i < 6; ++i) {
    int cc = lane + 64 * i;
    yr[cc] = f2bf((v[i] - mean) * rs * g[cc] + b[cc]);
  }
}

// zero the 4 guard rows top+bottom of each batch slab in ypad
__global__ __launch_bounds__(256) void k_zero_guard(unsigned short* __restrict__ ypad) {
  int i = blockIdx.x * 256 + threadIdx.x;   // 8*8*384 = 24576
  if (i >= 24576) return;
  int c = i % NC;
  int r = (i / NC) % 8;
  int b = i / (NC * 8);
  int t = (r < 4) ? r : (2048 + r);         // rows 0..3 and 2052..2055
  ypad[((size_t)b * TPAD + t) * NC + c] = 0;
}

// pack + convert cw[f][c][kk] -> cwp[f][kk*384+c] bf16. One block per f-row,
// coalesced load -> LDS -> coalesced store (LDS read stride 9: conflict-free).
__global__ __launch_bounds__(256) void k_pack_cw2(const float* __restrict__ cw,
    unsigned short* __restrict__ cwp) {
  __shared__ float s[NKI];
  int f = blockIdx.x;
  const float* src = cw + (size_t)f * NKI;
  for (int i = threadIdx.x; i < NKI; i += 256) s[i] = src[i];
  __syncthreads();
  unsigned short* dst = cwp + (size_t)f * NKI;
  for (int i = threadIdx.x; i < NKI; i += 256) {
    int kk = i / NC, cc = i - kk * NC;
    dst[i] = f2bf(s[cc * 9 + kk]);
  }
}

// fused qkvo weight convert: dst = [qwb|kwb|vwb|owb] contiguous, q scaled
__global__ __launch_bounds__(256) void k_cvt_qkvo(const float* __restrict__ qw,
    const float* __restrict__ kw, const float* __restrict__ vw,
    const float* __restrict__ ow, unsigned short* __restrict__ dst, float qscale) {
  int i = blockIdx.x * 256 + threadIdx.x;
  if (i >= 4 * 294912) return;
  int w = i / 294912;
  int j = i - w * 294912;
  const float* s = (w == 0) ? qw : (w == 1) ? kw : (w == 2) ? vw : ow;
  float sc = (w == 0) ? qscale : 1.f;
  dst[i] = f2bf(s[j] * sc);
}

// fp32 -> bf16 plain
__global__ __launch_bounds__(256) void k_cvt(const float* __restrict__ x,
    unsigned short* __restrict__ y, int n) {
  int i = blockIdx.x * 256 + threadIdx.x;
  if (i < n) y[i] = f2bf(x[i]);
}

// Shared 128x128 GEMM inner loop, R2-proven structure: BK=64, double-buffered
// LDS, distance-2 prefetch, counted vmcnt(8) (8 loads/thread/tile, never 0
// mid-loop), granule-XOR swizzle (pre-swizzled global src + XOR'd ds_read).
// A rows bm..bm+127 of [*,K]; W rows bn..bn+127 of [*,K]. 256 threads, 4 waves
// (2M x 2N, 64x64 per wave).
static __device__ __forceinline__ void gemm128_db(
    const unsigned short* __restrict__ A,
    const unsigned short* __restrict__ W,
    int K, int ntiles, int bm, int bn,
    unsigned short* AsB, unsigned short* BsB,
    f32x4 (&acc)[4][4]) {
  const int tid = threadIdx.x;
  const int lane = tid & 63, wv = tid >> 6;
  const int rsel = lane & 15, ghi = lane >> 4;
  const int l8 = lane >> 3, g8 = lane & 7;
  const int gsrc = (g8 ^ l8) * 8;              // pre-swizzled source granule
  const size_t abase = (size_t)(bm + wv * 32 + l8) * K + gsrc;
  const size_t bbase = (size_t)(bn + wv * 32 + l8) * K + gsrc;

#define GDB_STAGE(T, DB)                                                        \
  {                                                                             \
    const size_t k_ = (size_t)(T) * 64;                                         \
    GLOAD16(A + abase + k_, AsB + (DB) * 8192 + (wv * 32) * 64);                \
    GLOAD16(A + abase + k_ + (size_t)8 * K, AsB + (DB) * 8192 + (wv * 32 + 8) * 64);   \
    GLOAD16(A + abase + k_ + (size_t)16 * K, AsB + (DB) * 8192 + (wv * 32 + 16) * 64); \
    GLOAD16(A + abase + k_ + (size_t)24 * K, AsB + (DB) * 8192 + (wv * 32 + 24) * 64); \
    GLOAD16(W + bbase + k_, BsB + (DB) * 8192 + (wv * 32) * 64);                \
    GLOAD16(W + bbase + k_ + (size_t)8 * K, BsB + (DB) * 8192 + (wv * 32 + 8) * 64);   \
    GLOAD16(W + bbase + k_ + (size_t)16 * K, BsB + (DB) * 8192 + (wv * 32 + 16) * 64); \
    GLOAD16(W + bbase + k_ + (size_t)24 * K, BsB + (DB) * 8192 + (wv * 32 + 24) * 64); \
  }

  // prologue: stage tiles 0 and 1 (16 loads); wait the 8 oldest = tile 0
  GDB_STAGE(0, 0);
  GDB_STAGE(1, 1);
  asm volatile("s_waitcnt vmcnt(8)" ::: "memory");
  __builtin_amdgcn_sched_barrier(0);
  __builtin_amdgcn_s_barrier();

  const int arow = (wv >> 1) * 64;
  const int brow = (wv & 1) * 64;
  int db = 0;
  for (int t = 0; t < ntiles; ++t) {
    bf16x8 af[4][2], bfr[4][2];
#pragma unroll
    for (int m = 0; m < 4; ++m) {
      int r = arow + m * 16 + rsel;
#pragma unroll
      for (int k = 0; k < 2; ++k)
        af[m][k] = *(const bf16x8*)&AsB[db * 8192 + r * 64 + (((k * 4 + ghi) ^ (r & 7)) * 8)];
    }
#pragma unroll
    for (int n = 0; n < 4; ++n) {
      int r = brow + n * 16 + rsel;
#pragma unroll
      for (int k = 0; k < 2; ++k)
        bfr[n][k] = *(const bf16x8*)&BsB[db * 8192 + r * 64 + (((k * 4 + ghi) ^ (r & 7)) * 8)];
    }
    __builtin_amdgcn_s_setprio(1);
#pragma unroll
    for (int m = 0; m < 4; ++m)
#pragma unroll
      for (int n = 0; n < 4; ++n)
        acc[m][n] = __builtin_amdgcn_mfma_f32_16x16x32_bf16(af[m][0], bfr[n][0], acc[m][n], 0, 0, 0);
    __builtin_amdgcn_s_setprio(0);
    __builtin_amdgcn_sched_barrier(0);
    asm volatile("s_waitcnt lgkmcnt(0)" ::: "memory");   // all reads of buf[db] done
    __builtin_amdgcn_sched_barrier(0);
    __builtin_amdgcn_s_barrier();                        // ... in every wave
    if (t + 2 < ntiles) GDB_STAGE(t + 2, db);            // safe: buf[db] free now
    __builtin_amdgcn_s_setprio(1);
#pragma unroll
    for (int m = 0; m < 4; ++m)
#pragma unroll
      for (int n = 0; n < 4; ++n)
        acc[m][n] = __builtin_amdgcn_mfma_f32_16x16x32_bf16(af[m][1], bfr[n][1], acc[m][n], 0, 0, 0);
    __builtin_amdgcn_s_setprio(0);
    __builtin_amdgcn_sched_barrier(0);
    if (t + 2 < ntiles) {
      asm volatile("s_waitcnt vmcnt(8)" ::: "memory");   // tile t+1 landed; t+2 flying
    } else {
      asm volatile("s_waitcnt vmcnt(0)" ::: "memory");   // epilogue drain
    }
    __builtin_amdgcn_sched_barrier(0);
    __builtin_amdgcn_s_barrier();
    db ^= 1;
  }
#undef GDB_STAGE
}

// Merged q/k/v projection GEMM, one launch. grid (3, 192):
//   y in [0,128): q = LN1(x1) @ qw^T  -> qbb row-major      (M=16384)
//   y in [128,160): k = x2b @ kw^T    -> kbb row-major      (M=4096)
//   y in [160,192): v = x2b @ vw^T    -> vtb transposed     (M=4096)
__global__ __launch_bounds__(256) void k_pgemm_qkv(
    const unsigned short* __restrict__ Aq,
    const unsigned short* __restrict__ Akv,
    const unsigned short* __restrict__ Wq,
    const unsigned short* __restrict__ Wk,
    const unsigned short* __restrict__ Wv,
    unsigned short* __restrict__ Qb,
    unsigned short* __restrict__ Kb,
    unsigned short* __restrict__ Vtb) {
  __shared__ unsigned short As[2 * 8192];
  __shared__ unsigned short Bs[2 * 8192];
  const int y = blockIdx.y;
  const int which = (y < 128) ? 0 : (y < 160) ? 1 : 2;
  const unsigned short* A = (which == 0) ? Aq : Akv;
  const unsigned short* W = (which == 0) ? Wq : (which == 1) ? Wk : Wv;
  const int bm = ((which == 0) ? y : (which == 1) ? (y - 128) : (y - 160)) * 128;
  const int bn = blockIdx.x * 128;
  f32x4 acc[4][4] = {};
  gemm128_db(A, W, NC, 6, bm, bn, As, Bs, acc);

  const int lane = threadIdx.x & 63, wv = threadIdx.x >> 6;
  const int col0 = bn + (wv & 1) * 64 + (lane & 15);
  const int row0 = bm + (wv >> 1) * 64 + (lane >> 4) * 4;
#pragma unroll
  for (int m = 0; m < 4; ++m) {
#pragma unroll
    for (int n = 0; n < 4; ++n) {
      int col = col0 + n * 16;
#pragma unroll
      for (int r = 0; r < 4; ++r) {
        int row = row0 + m * 16 + r;
        unsigned short bv = f2bf(acc[m][n][r]);
        if (which == 0) {
          Qb[(size_t)row * NC + col] = bv;
        } else if (which == 1) {
          Kb[(size_t)row * NC + col] = bv;
        } else {
          // vtb[(b*384 + col)*512 + j], b = row>>9, j = row&511
          Vtb[((size_t)((row >> 9) * 384 + col)) * 512 + (row & 511)] = bv;
        }
      }
    }
  }
}

// o-projection GEMM: x1a += attn @ ow^T (fused residual).
__global__ __launch_bounds__(256) void k_pgemm_o(
    const unsigned short* __restrict__ A,
    const unsigned short* __restrict__ W,
    float* __restrict__ Cf) {
  __shared__ unsigned short As[2 * 8192];
  __shared__ unsigned short Bs[2 * 8192];
  const int bn = blockIdx.x * 128;
  const int bm = blockIdx.y * 128;
  f32x4 acc[4][4] = {};
  gemm128_db(A, W, NC, 6, bm, bn, As, Bs, acc);

  const int lane = threadIdx.x & 63, wv = threadIdx.x >> 6;
  const int col0 = bn + (wv & 1) * 64 + (lane & 15);
  const int row0 = bm + (wv >> 1) * 64 + (lane >> 4) * 4;
#pragma unroll
  for (int m = 0; m < 4; ++m) {
#pragma unroll
    for (int n = 0; n < 4; ++n) {
      int col = col0 + n * 16;
#pragma unroll
      for (int r = 0; r < 4; ++r) {
        int row = row0 + m * 16 + r;
        size_t oi = (size_t)row * NC + col;
        Cf[oi] = acc[m][n][r] + Cf[oi];
      }
    }
  }
}

// FFN linear: x1a[m][n] += H[m][:]@lw[n][:] + lb[n].
__global__ __launch_bounds__(256) void k_lin_mfma(
    const unsigned short* __restrict__ H,
    const unsigned short* __restrict__ Wb,
    const float* __restrict__ lb,
    float* __restrict__ x1a) {
  __shared__ unsigned short As[2 * 8192];
  __shared__ unsigned short Bs[2 * 8192];
  const int bn = blockIdx.x * 128;
  const int bm = blockIdx.y * 128;
  f32x4 acc[4][4] = {};
  gemm128_db(H, Wb, NF, 24, bm, bn, As, Bs, acc);

  const int lane = threadIdx.x & 63, wv = threadIdx.x >> 6;
  const int col0 = bn + (wv & 1) * 64 + (lane & 15);
  const int row0 = bm + (wv >> 1) * 64 + (lane >> 4) * 4;
#pragma unroll
  for (int m = 0; m < 4; ++m) {
#pragma unroll
    for (int n = 0; n < 4; ++n) {
      int col = col0 + n * 16;
      float lbv = lb[col];
#pragma unroll
      for (int r = 0; r < 4; ++r) {
        int row = row0 + m * 16 + r;
        size_t oi = (size_t)row * NC + col;
        x1a[oi] = acc[m][n][r] + lbv + x1a[oi];
      }
    }
  }
}

// Conv1d(C->4C,k=9,SAME) implicit GEMM. 128x128 tile, BK=64, 4 waves (2Mx2N),
// same R2-proven schedule as gemm128_db (dbuf, distance-2 prefetch, counted
// vmcnt(8), granule-XOR swizzle) but with tap-aware A addressing. 64 KB LDS
// -> 2 blocks/CU: cross-block overlap hides the barrier drain (m114).
// Grid (128, 12) x-fastest = 1536 blocks = exactly 3 rounds at 2/CU.
// Fused (+cb)*9^-0.5 -> gelu(exact) -> bf16 store.
__global__ __launch_bounds__(256) void k_conv_mfma(
    const unsigned short* __restrict__ Ypad,
    const unsigned short* __restrict__ Wp,
    const float* __restrict__ cb,
    unsigned short* __restrict__ H) {
  __shared__ unsigned short As[2 * 8192];   // 32 KB
  __shared__ unsigned short Bs[2 * 8192];   // 32 KB
  const int bm = blockIdx.x * 128;          // x-fastest: XCD=id%8, A panels L2-hot
  const int bn = blockIdx.y * 128;
  const int b = bm >> 11, t0 = bm & 2047;
  const int tid = threadIdx.x;
  const int lane = tid & 63, wv = tid >> 6;
  const int rsel = lane & 15, ghi = lane >> 4;
  const int l8 = lane >> 3, g8 = lane & 7;
  const int gsrc = (g8 ^ l8) * 8;           // pre-swizzled source granule (shorts)

  f32x4 acc[4][4] = {};

  const size_t arow0 = (size_t)(b * TPAD + t0 + wv * 32 + l8);   // A stage row
  const size_t brow0 = (size_t)(bn + wv * 32 + l8);              // B stage row

#define CONV_STAGE(T, DB)                                                       \
  {                                                                             \
    const int kt_ = (T) * 64;                                                   \
    const int kk_ = kt_ / NC;                                                   \
    const int c0_ = kt_ - kk_ * NC;                                             \
    const size_t asrc_ = (arow0 + kk_) * NC + c0_ + gsrc;                       \
    GLOAD16(Ypad + asrc_, &As[(DB) * 8192 + (wv * 32) * 64]);                   \
    GLOAD16(Ypad + asrc_ + (size_t)8 * NC, &As[(DB) * 8192 + (wv * 32 + 8) * 64]);   \
    GLOAD16(Ypad + asrc_ + (size_t)16 * NC, &As[(DB) * 8192 + (wv * 32 + 16) * 64]); \
    GLOAD16(Ypad + asrc_ + (size_t)24 * NC, &As[(DB) * 8192 + (wv * 32 + 24) * 64]); \
    const size_t bsrc_ = brow0 * NKI + kt_ + gsrc;                              \
    GLOAD16(Wp + bsrc_, &Bs[(DB) * 8192 + (wv * 32) * 64]);                     \
    GLOAD16(Wp + bsrc_ + (size_t)8 * NKI, &Bs[(DB) * 8192 + (wv * 32 + 8) * 64]);    \
    GLOAD16(Wp + bsrc_ + (size_t)16 * NKI, &Bs[(DB) * 8192 + (wv * 32 + 16) * 64]);  \
    GLOAD16(Wp + bsrc_ + (size_t)24 * NKI, &Bs[(DB) * 8192 + (wv * 32 + 24) * 64]);  \
  }

  // prologue: stage tiles 0 and 1 (16 loads); wait the 8 oldest = tile 0
  CONV_STAGE(0, 0);
  CONV_STAGE(1, 1);
  asm volatile("s_waitcnt vmcnt(8)" ::: "memory");
  __builtin_amdgcn_sched_barrier(0);
  __builtin_amdgcn_s_barrier();

  const int arow = (wv >> 1) * 64;
  const int brow = (wv & 1) * 64;
  int db = 0;
  for (int t = 0; t < 54; ++t) {
    bf16x8 af[4][2], bfr[4][2];
#pragma unroll
    for (int m = 0; m < 4; ++m) {
      int r = arow + m * 16 + rsel;
#pragma unroll
      for (int k = 0; k < 2; ++k)
        af[m][k] = *(const bf16x8*)&As[db * 8192 + r * 64 + (((k * 4 + ghi) ^ (r & 7)) * 8)];
    }
#pragma unroll
    for (int n = 0; n < 4; ++n) {
      int r = brow + n * 16 + rsel;
#pragma unroll
      for (int k = 0; k < 2; ++k)
        bfr[n][k] = *(const bf16x8*)&Bs[db * 8192 + r * 64 + (((k * 4 + ghi) ^ (r & 7)) * 8)];
    }
    __builtin_amdgcn_s_setprio(1);
#pragma unroll
    for (int m = 0; m < 4; ++m)
#pragma unroll
      for (int n = 0; n < 4; ++n)
        acc[m][n] = __builtin_amdgcn_mfma_f32_16x16x32_bf16(af[m][0], bfr[n][0], acc[m][n], 0, 0, 0);
    __builtin_amdgcn_s_setprio(0);
    __builtin_amdgcn_sched_barrier(0);
    asm volatile("s_waitcnt lgkmcnt(0)" ::: "memory");   // all reads of buf[db] done
    __builtin_amdgcn_sched_barrier(0);
    __builtin_amdgcn_s_barrier();                        // ... in every wave
    if (t + 2 < 54) CONV_STAGE(t + 2, db);               // safe: buf[db] free now
    __builtin_amdgcn_s_setprio(1);
#pragma unroll
    for (int m = 0; m < 4; ++m)
#pragma unroll
      for (int n = 0; n < 4; ++n)
        acc[m][n] = __builtin_amdgcn_mfma_f32_16x16x32_bf16(af[m][1], bfr[n][1], acc[m][n], 0, 0, 0);
    __builtin_amdgcn_s_setprio(0);
    __builtin_amdgcn_sched_barrier(0);
    if (t + 2 < 54) {
      asm volatile("s_waitcnt vmcnt(8)" ::: "memory");   // tile t+1 landed; t+2 flying
    } else {
      asm volatile("s_waitcnt vmcnt(0)" ::: "memory");   // epilogue drain
    }
    __builtin_amdgcn_sched_barrier(0);
    __builtin_amdgcn_s_barrier();
    db ^= 1;
  }
#undef CONV_STAGE

  const int col0 = bn + (wv & 1) * 64 + rsel;
  const int row0 = bm + (wv >> 1) * 64 + ghi * 4;
#pragma unroll
  for (int m = 0; m < 4; ++m) {
#pragma unroll
    for (int n = 0; n < 4; ++n) {
      int col = col0 + n * 16;
      float cbv = cb[col];
#pragma unroll
      for (int r = 0; r < 4; ++r) {
        int row = row0 + m * 16 + r;
        float xv = (acc[m][n][r] + cbv) * 0.33333333333333333f;
        float ge = 0.5f * xv * (1.f + erff(xv * 0.70710678118654752f));
        H[(size_t)row * NF + col] = f2bf(ge);
      }
    }
  }
}

// Windowed cross-attention, MFMA flash-style. bf16 output (feeds o-projection).
__global__ __launch_bounds__(256) void k_attn_mfma(
    const unsigned short* __restrict__ qbb,   // [8*2048][384] bf16 (q*scaling folded in W)
    const unsigned short* __restrict__ kbb,   // [8*512][384] bf16
    const unsigned short* __restrict__ vtb,   // [(b*2+h)*192+d][512] bf16
    unsigned short* __restrict__ o, int guided, float* __restrict__ gl) {
  __shared__ unsigned short lds[32768];
  const int tid = threadIdx.x;
  const int lane = tid & 63, wv = tid >> 6;
  const int rsel = lane & 15, ghi = lane >> 4;
  const int idx = blockIdx.x;
  const int tg = idx & 31;
  const int bh = idx >> 5;
  const int h = bh & 1, b = bh >> 1;
  const int t0 = tg * 64;
  const int c0 = t0 >> 2;
  int klo = c0 - 51; if (klo < 0) klo = 0;
  klo &= ~7;                       // 16B-align for global_load_lds on vtb
  if (klo > 384) klo = 384;        // keep window inside [0,512)

  // Q fragments: A-operand layout, row = lane&15, k = ghi*8 (+32 per step)
  const unsigned short* qrow = qbb + (size_t)(b * NT1 + t0 + wv * 16 + rsel) * NC + h * ND;
  bf16x8 qf[6];
#pragma unroll
  for (int kk = 0; kk < 6; ++kk)
    qf[kk] = *(const bf16x8*)(qrow + kk * 32 + ghi * 8);

  // stage K window [128 keys][192] bf16, source pre-swizzled (granule ^ row&7)
  {
    const size_t kbase = (size_t)(b * NT2 + klo) * NC + h * ND;
#pragma unroll
    for (int it = 0; it < 12; ++it) {
      int g = it * 256 + tid;
      int row = g / 24, go = g % 24;
      int gs = go ^ (row & 7);
      GLOAD16(kbb + kbase + (size_t)row * NC + gs * 8, &lds[(it * 256 + wv * 64) * 8]);
    }
  }
  __syncthreads();

  // QK^T: 16 queries x 128 keys per wave
  f32x4 accs[8] = {};
#pragma unroll
  for (int kk = 0; kk < 6; ++kk) {
#pragma unroll
    for (int n = 0; n < 8; ++n) {
      int row = n * 16 + rsel;
      bf16x8 bfr = *(const bf16x8*)&lds[row * 192 + (((kk * 4 + ghi) ^ (rsel & 7)) * 8)];
      accs[n] = __builtin_amdgcn_mfma_f32_16x16x32_bf16(qf[kk], bfr, accs[n], 0, 0, 0);
    }
  }

  // masked softmax per query row; rows live on 16-lane groups (row=ghi*4+r, col=rsel)
  unsigned short* pl = &lds[24576 + wv * 2048];
  float gacc = 0.f;
  const int t0w = t0 + wv * 16;
#pragma unroll
  for (int r = 0; r < 4; ++r) {
    int t = t0w + ghi * 4 + r;
    int c = t >> 2;
    int loq = c - 51; if (loq < 0) loq = 0;
    int hiq = c + 51; if (hiq > NT2) hiq = NT2;
    float sv[8];
    float mx = -1e30f;
#pragma unroll
    for (int n = 0; n < 8; ++n) {
      int j = klo + n * 16 + rsel;
      float s = (j >= loq && j < hiq) ? accs[n][r] : -1e30f;
      sv[n] = s; mx = fmaxf(mx, s);
    }
#pragma unroll
    for (int off = 1; off < 16; off <<= 1) mx = fmaxf(mx, __shfl_xor(mx, off));
    float e[8]; float se = 0.f;
#pragma unroll
    for (int n = 0; n < 8; ++n) { e[n] = __expf(sv[n] - mx); se += e[n]; }
#pragma unroll
    for (int off = 1; off < 16; off <<= 1) se += __shfl_xor(se, off);
    float inv = 1.f / se;
    int q = ghi * 4 + r;
#pragma unroll
    for (int n = 0; n < 8; ++n) {
      float pv = e[n] * inv;
      int klocal = n * 16 + rsel;
      pl[q * 128 + (((klocal >> 3) ^ (q & 7)) * 8) + (klocal & 7)] = f2bf(pv);
      if (guided) {
        int j = klo + klocal;
        float d = (float)j * (1.f / NT2) - (float)t * (1.f / NT1);
        gacc += pv * (1.f - __expf(-(d * d) * 5.5555555556f));
      }
    }
  }
  if (guided) {
    gacc = warp_sum(gacc);
    if (lane == 0) atomicAdd(gl, gacc * (1.f / 16777216.f));
  }
  __syncthreads();

  // stage VT window [192 chans][128 keys] bf16 into the K buffer (reuse)
  {
    const size_t vbase = ((size_t)(b * 2 + h) * ND) * NT2 + klo;
#pragma unroll
    for (int it = 0; it < 12; ++it) {
      int g = it * 256 + tid;
      int row = g >> 4, go = g & 15;
      int gs = go ^ (row & 7);
      GLOAD16(vtb + vbase + (size_t)row * NT2 + gs * 8, &lds[(it * 256 + wv * 64) * 8]);
    }
  }
  __syncthreads();

  // PV: P[16x128] @ V[128x192] -> O[16x192]
  f32x4 acco[12] = {};
#pragma unroll
  for (int kt = 0; kt < 4; ++kt) {
    bf16x8 pa = *(const bf16x8*)&pl[rsel * 128 + (((kt * 4 + ghi) ^ (rsel & 7)) * 8)];
#pragma unroll
    for (int n = 0; n < 12; ++n) {
      int row = n * 16 + rsel;
      bf16x8 bfr = *(const bf16x8*)&lds[row * 128 + (((kt * 4 + ghi) ^ (rsel & 7)) * 8)];
      acco[n] = __builtin_amdgcn_mfma_f32_16x16x32_bf16(pa, bfr, acco[n], 0, 0, 0);
    }
  }

  unsigned short* obase = o + (size_t)(b * NT1 + t0w + ghi * 4) * NC + h * ND;
#pragma unroll
  for (int n = 0; n < 12; ++n) {
#pragma unroll
    for (int r = 0; r < 4; ++r) {
      obase[(size_t)r * NC + n * 16 + rsel] = f2bf(acco[n][r]);
    }
  }
}

extern "C" void kernel_launch(void* const* d_in, const int* in_sizes, int n_in,
                              void* d_out, int out_size, void* d_ws, size_t ws_size,
                              hipStream_t stream) {
  (void)in_sizes; (void)n_in; (void)out_size; (void)ws_size;
  const float* x1    = (const float*)d_in[0];
  const float* x2    = (const float*)d_in[1];
  const float* alpha = (const float*)d_in[2];
  const float* ln1_g = (const float*)d_in[3];
  const float* ln1_b = (const float*)d_in[4];
  const float* qw    = (const float*)d_in[5];
  const float* kw    = (const float*)d_in[6];
  const float* vw    = (const float*)d_in[7];
  const float* ow    = (const float*)d_in[8];
  const float* ln2_g = (const float*)d_in[9];
  const float* ln2_b = (const float*)d_in[10];
  const float* cw    = (const float*)d_in[11];
  const float* cb    = (const float*)d_in[12];
  const float* lw    = (const float*)d_in[13];
  const float* lb    = (const float*)d_in[14];
  const float* lnf_g = (const float*)d_in[15];
  const float* lnf_b = (const float*)d_in[16];
  float* out = (float*)d_out;
  float* gl = out + 6291456;   // guided-loss scalar slot

  float* p = (float*)d_ws;
  float* x1a = p; p += 6291456;    // x1 state [16384,384] f32
  // bf16 region (16B-aligned)
  unsigned short* us = (unsigned short*)p;
  unsigned short* x2b  = us; us += 1572864;            // x2+pos bf16 [4096][384]
  unsigned short* tmpb = us; us += 6291456;            // LN1 out / attn out bf16
  unsigned short* ypad = us; us += 8 * TPAD * NC;      // 6316032
  unsigned short* cwpb = us; us += 2 * (size_t)NF * NKI;   // 10616832 (both layers)
  unsigned short* lwb  = us; us += 2 * (size_t)NC * NF;    // 1179648 (both layers)
  unsigned short* hb   = us; us += (size_t)16384 * NF; // 25165824
  unsigned short* qbb  = us; us += 6291456;            // q bf16 [16384][384]
  unsigned short* kbb  = us; us += 1572864;            // k bf16 [4096][384]
  unsigned short* vtb  = us; us += 1572864;            // v^T bf16 [32*192][512]
  unsigned short* qwb  = us; us += 294912;             // weights bf16 (contiguous qkvo)
  unsigned short* kwb  = us; us += 294912;
  unsigned short* vwb  = us; us += 294912;
  unsigned short* owb  = us; us += 294912;

  hipMemsetAsync(gl, 0, sizeof(float), stream);  // atomic accumulator, re-zeroed every launch
  k_zero_guard<<<96, 256, 0, stream>>>(ypad);
  k_add_pos2<<<12288, 256, 0, stream>>>(x1, alpha, x1a, NT1, 3145728);
  k_add_pos2_bf16<<<3072, 256, 0, stream>>>(x2, alpha, x2b, NT2, 786432);

  const float scaling = 0.07216878364870323f;   // 192^-0.5
  // weight conversions, both layers, hoisted + fused
  k_cvt_qkvo<<<4608, 256, 0, stream>>>(qw, kw, vw, ow, qwb, scaling);
  k_cvt<<<4608, 256, 0, stream>>>(lw, lwb, 1179648);
  k_pack_cw2<<<3072, 256, 0, stream>>>(cw, cwpb);

  for (int l = 0; l < 2; ++l) {
    k_ln_bf16<<<4096, 256, 0, stream>>>(x1a, ln1_g + l * 384, ln1_b + l * 384, tmpb);
    k_pgemm_qkv<<<dim3(3, 192), 256, 0, stream>>>(tmpb, x2b,
        qwb + (size_t)l * 147456, kwb + (size_t)l * 147456, vwb + (size_t)l * 147456,
        qbb, kbb, vtb);
    k_attn_mfma<<<512, 256, 0, stream>>>(qbb, kbb, vtb, tmpb, l == 0 ? 1 : 0, gl);
    k_pgemm_o<<<dim3(3, 128), 256, 0, stream>>>(tmpb, owb + (size_t)l * 147456, x1a);
    // FFN: ln2 -> bf16 padded, conv implicit GEMM (128² dbuf, 2 blocks/CU), linear
    k_ln_bf16p<<<4096, 256, 0, stream>>>(x1a, ln2_g + l * 384, ln2_b + l * 384, ypad);
    k_conv_mfma<<<dim3(128, 12), 256, 0, stream>>>(ypad, cwpb + (size_t)l * 5308416, cb + l * 1536, hb);
    k_lin_mfma<<<dim3(3, 128), 256, 0, stream>>>(hb, lwb + (size_t)l * 589824, lb + l * 384, x1a);
  }
  k_ln<<<4096, 256, 0, stream>>>(x1a, lnf_g, lnf_b, out, 16384);
}

// Round 11
// 627.657 us; speedup vs baseline: 1.2662x; 1.0142x over previous
//
#include <hip/hip_runtime.h>
#include <math.h>

#define NB 8
#define NT1 2048
#define NT2 512
#define NC 384
#define ND 192
#define NF 1536
#define NKI 3456   // 9*384 implicit-GEMM K for conv
#define TPAD 2056  // 2048 + 4 guard rows top and bottom

typedef __attribute__((ext_vector_type(8))) short bf16x8;
typedef __attribute__((ext_vector_type(4))) float f32x4;

#define GLOAD16(gsrc, ldst) \
  __builtin_amdgcn_global_load_lds((const __attribute__((address_space(1))) void*)(gsrc), \
                                   (__attribute__((address_space(3))) void*)(ldst), 16, 0, 0)

static __device__ __forceinline__ unsigned short f2bf(float f) {
  unsigned int u = __float_as_uint(f);
  unsigned int r = (u + 0x7fffu + ((u >> 16) & 1u)) >> 16;
  return (unsigned short)r;
}

static __device__ __forceinline__ float warp_sum(float v) {
#pragma unroll
  for (int off = 32; off > 0; off >>= 1) v += __shfl_xor(v, off);
  return v;
}

// x += alpha * sin-pos; thread handles (t,j) pair: sin at c=j, cos at c=j+192
__global__ __launch_bounds__(256) void k_add_pos2(const float* __restrict__ x,
    const float* __restrict__ alpha_p, float* __restrict__ y, int T, int total2) {
  int i = blockIdx.x * 256 + threadIdx.x;
  if (i >= total2) return;
  int j = i % 192;
  int row = i / 192;
  int t = row % T;
  float freq = __expf(-0.0482216773f * (float)j);   // ln(10000)/191
  float ang = (float)(t + 1) * freq;
  float sn, cs;
  __sincosf(ang, &sn, &cs);
  float a = alpha_p[0];
  size_t base = (size_t)row * NC;
  y[base + j] = x[base + j] + a * sn;
  y[base + j + 192] = x[base + j + 192] + a * cs;
}

// x2+pos -> bf16; trailing threads zero the ypad guard rows (fused k_zero_guard)
__global__ __launch_bounds__(256) void k_add_pos2_bf16(const float* __restrict__ x,
    const float* __restrict__ alpha_p, unsigned short* __restrict__ y, int T, int total2,
    unsigned short* __restrict__ ypad) {
  int i = blockIdx.x * 256 + threadIdx.x;
  if (i >= total2) {
    int g = i - total2;                       // 24576 guard elements
    if (g < 24576) {
      int c = g % NC;
      int r = (g / NC) % 8;
      int b = g / (NC * 8);
      int t = (r < 4) ? r : (2048 + r);       // rows 0..3 and 2052..2055
      ypad[((size_t)b * TPAD + t) * NC + c] = 0;
    }
    return;
  }
  int j = i % 192;
  int row = i / 192;
  int t = row % T;
  float freq = __expf(-0.0482216773f * (float)j);
  float ang = (float)(t + 1) * freq;
  float sn, cs;
  __sincosf(ang, &sn, &cs);
  float a = alpha_p[0];
  size_t base = (size_t)row * NC;
  y[base + j] = f2bf(x[base + j] + a * sn);
  y[base + j + 192] = f2bf(x[base + j + 192] + a * cs);
}

// LayerNorm over last dim (384). One wave per row. fp32 out (final LN).
__global__ __launch_bounds__(256) void k_ln(const float* __restrict__ x,
    const float* __restrict__ g, const float* __restrict__ b,
    float* __restrict__ y, int nrows) {
  int row = blockIdx.x * 4 + (threadIdx.x >> 6);
  int lane = threadIdx.x & 63;
  if (row >= nrows) return;
  const float* xr = x + (size_t)row * NC;
  float v[6];
  float s = 0.f, s2 = 0.f;
#pragma unroll
  for (int i = 0; i < 6; ++i) {
    float t = xr[lane + 64 * i];
    v[i] = t; s += t; s2 += t * t;
  }
  s = warp_sum(s); s2 = warp_sum(s2);
  float mean = s * (1.f / NC);
  float var = s2 * (1.f / NC) - mean * mean;
  float rs = rsqrtf(var + 1e-5f);
  float* yr = y + (size_t)row * NC;
#pragma unroll
  for (int i = 0; i < 6; ++i) {
    int cc = lane + 64 * i;
    yr[cc] = (v[i] - mean) * rs * g[cc] + b[cc];
  }
}

// LayerNorm -> bf16 (unpadded), feeds MFMA projections
__global__ __launch_bounds__(256) void k_ln_bf16(const float* __restrict__ x,
    const float* __restrict__ g, const float* __restrict__ b,
    unsigned short* __restrict__ y) {
  int row = blockIdx.x * 4 + (threadIdx.x >> 6);
  int lane = threadIdx.x & 63;
  const float* xr = x + (size_t)row * NC;
  float v[6];
  float s = 0.f, s2 = 0.f;
#pragma unroll
  for (int i = 0; i < 6; ++i) {
    float t = xr[lane + 64 * i];
    v[i] = t; s += t; s2 += t * t;
  }
  s = warp_sum(s); s2 = warp_sum(s2);
  float mean = s * (1.f / NC);
  float var = s2 * (1.f / NC) - mean * mean;
  float rs = rsqrtf(var + 1e-5f);
  unsigned short* yr = y + (size_t)row * NC;
#pragma unroll
  for (int i = 0; i < 6; ++i) {
    int cc = lane + 64 * i;
    yr[cc] = f2bf((v[i] - mean) * rs * g[cc] + b[cc]);
  }
}

// LayerNorm -> bf16 into guard-padded [8][2056][384] buffer (row t -> t+4)
__global__ __launch_bounds__(256) void k_ln_bf16p(const float* __restrict__ x,
    const float* __restrict__ g, const float* __restrict__ b,
    unsigned short* __restrict__ ypad) {
  int row = blockIdx.x * 4 + (threadIdx.x >> 6);
  int lane = threadIdx.x & 63;
  const float* xr = x + (size_t)row * NC;
  float v[6];
  float s = 0.f, s2 = 0.f;
#pragma unroll
  for (int i = 0; i < 6; ++i) {
    float t = xr[lane + 64 * i];
    v[i] = t; s += t; s2 += t * t;
  }
  s = warp_sum(s); s2 = warp_sum(s2);
  float mean = s * (1.f / NC);
  float var = s2 * (1.f / NC) - mean * mean;
  float rs = rsqrtf(var + 1e-5f);
  int bb = row >> 11, t = row & 2047;
  unsigned short* yr = ypad + ((size_t)(bb * TPAD + t + 4)) * NC;
#pragma unroll
  for (int i = 0; i < 6; ++i) {
    int cc = lane + 64 * i;
    yr[cc] = f2bf((v[i] - mean) * rs * g[cc] + b[cc]);
  }
}

// pack + convert cw[f][c][kk] -> cwp[f][kk*384+c] bf16. One block per f-row,
// coalesced load -> LDS -> coalesced store (LDS read stride 9: conflict-free).
__global__ __launch_bounds__(256) void k_pack_cw2(const float* __restrict__ cw,
    unsigned short* __restrict__ cwp) {
  __shared__ float s[NKI];
  int f = blockIdx.x;
  const float* src = cw + (size_t)f * NKI;
  for (int i = threadIdx.x; i < NKI; i += 256) s[i] = src[i];
  __syncthreads();
  unsigned short* dst = cwp + (size_t)f * NKI;
  for (int i = threadIdx.x; i < NKI; i += 256) {
    int kk = i / NC, cc = i - kk * NC;
    dst[i] = f2bf(s[cc * 9 + kk]);
  }
}

// merged weight convert: lw (1179648) -> lwb, then qkvo (4x294912) -> qkvob, q scaled
__global__ __launch_bounds__(256) void k_cvt_all(const float* __restrict__ qw,
    const float* __restrict__ kw, const float* __restrict__ vw,
    const float* __restrict__ ow, const float* __restrict__ lw,
    unsigned short* __restrict__ qkvob, unsigned short* __restrict__ lwb, float qscale) {
  int i = blockIdx.x * 256 + threadIdx.x;
  if (i >= 2359296) return;
  if (i < 1179648) { lwb[i] = f2bf(lw[i]); return; }
  int k = i - 1179648;
  int w = k / 294912;
  int j = k - w * 294912;
  const float* s = (w == 0) ? qw : (w == 1) ? kw : (w == 2) ? vw : ow;
  float sc = (w == 0) ? qscale : 1.f;
  qkvob[k] = f2bf(s[j] * sc);
}

// Shared 128x128 GEMM inner loop, R2-proven structure: BK=64, double-buffered
// LDS, distance-2 prefetch, counted vmcnt(8) (8 loads/thread/tile, never 0
// mid-loop), granule-XOR swizzle (pre-swizzled global src + XOR'd ds_read).
// 256 threads, 4 waves (2M x 2N, 64x64 per wave).
static __device__ __forceinline__ void gemm128_db(
    const unsigned short* __restrict__ A,
    const unsigned short* __restrict__ W,
    int K, int ntiles, int bm, int bn,
    unsigned short* AsB, unsigned short* BsB,
    f32x4 (&acc)[4][4]) {
  const int tid = threadIdx.x;
  const int lane = tid & 63, wv = tid >> 6;
  const int rsel = lane & 15, ghi = lane >> 4;
  const int l8 = lane >> 3, g8 = lane & 7;
  const int gsrc = (g8 ^ l8) * 8;              // pre-swizzled source granule
  const size_t abase = (size_t)(bm + wv * 32 + l8) * K + gsrc;
  const size_t bbase = (size_t)(bn + wv * 32 + l8) * K + gsrc;

#define GDB_STAGE(T, DB)                                                        \
  {                                                                             \
    const size_t k_ = (size_t)(T) * 64;                                         \
    GLOAD16(A + abase + k_, AsB + (DB) * 8192 + (wv * 32) * 64);                \
    GLOAD16(A + abase + k_ + (size_t)8 * K, AsB + (DB) * 8192 + (wv * 32 + 8) * 64);   \
    GLOAD16(A + abase + k_ + (size_t)16 * K, AsB + (DB) * 8192 + (wv * 32 + 16) * 64); \
    GLOAD16(A + abase + k_ + (size_t)24 * K, AsB + (DB) * 8192 + (wv * 32 + 24) * 64); \
    GLOAD16(W + bbase + k_, BsB + (DB) * 8192 + (wv * 32) * 64);                \
    GLOAD16(W + bbase + k_ + (size_t)8 * K, BsB + (DB) * 8192 + (wv * 32 + 8) * 64);   \
    GLOAD16(W + bbase + k_ + (size_t)16 * K, BsB + (DB) * 8192 + (wv * 32 + 16) * 64); \
    GLOAD16(W + bbase + k_ + (size_t)24 * K, BsB + (DB) * 8192 + (wv * 32 + 24) * 64); \
  }

  GDB_STAGE(0, 0);
  GDB_STAGE(1, 1);
  asm volatile("s_waitcnt vmcnt(8)" ::: "memory");
  __builtin_amdgcn_sched_barrier(0);
  __builtin_amdgcn_s_barrier();

  const int arow = (wv >> 1) * 64;
  const int brow = (wv & 1) * 64;
  int db = 0;
  for (int t = 0; t < ntiles; ++t) {
    bf16x8 af[4][2], bfr[4][2];
#pragma unroll
    for (int m = 0; m < 4; ++m) {
      int r = arow + m * 16 + rsel;
#pragma unroll
      for (int k = 0; k < 2; ++k)
        af[m][k] = *(const bf16x8*)&AsB[db * 8192 + r * 64 + (((k * 4 + ghi) ^ (r & 7)) * 8)];
    }
#pragma unroll
    for (int n = 0; n < 4; ++n) {
      int r = brow + n * 16 + rsel;
#pragma unroll
      for (int k = 0; k < 2; ++k)
        bfr[n][k] = *(const bf16x8*)&BsB[db * 8192 + r * 64 + (((k * 4 + ghi) ^ (r & 7)) * 8)];
    }
    __builtin_amdgcn_s_setprio(1);
#pragma unroll
    for (int m = 0; m < 4; ++m)
#pragma unroll
      for (int n = 0; n < 4; ++n)
        acc[m][n] = __builtin_amdgcn_mfma_f32_16x16x32_bf16(af[m][0], bfr[n][0], acc[m][n], 0, 0, 0);
    __builtin_amdgcn_s_setprio(0);
    __builtin_amdgcn_sched_barrier(0);
    asm volatile("s_waitcnt lgkmcnt(0)" ::: "memory");
    __builtin_amdgcn_sched_barrier(0);
    __builtin_amdgcn_s_barrier();
    if (t + 2 < ntiles) GDB_STAGE(t + 2, db);
    __builtin_amdgcn_s_setprio(1);
#pragma unroll
    for (int m = 0; m < 4; ++m)
#pragma unroll
      for (int n = 0; n < 4; ++n)
        acc[m][n] = __builtin_amdgcn_mfma_f32_16x16x32_bf16(af[m][1], bfr[n][1], acc[m][n], 0, 0, 0);
    __builtin_amdgcn_s_setprio(0);
    __builtin_amdgcn_sched_barrier(0);
    if (t + 2 < ntiles) {
      asm volatile("s_waitcnt vmcnt(8)" ::: "memory");
    } else {
      asm volatile("s_waitcnt vmcnt(0)" ::: "memory");
    }
    __builtin_amdgcn_sched_barrier(0);
    __builtin_amdgcn_s_barrier();
    db ^= 1;
  }
#undef GDB_STAGE
}

// Merged q/k/v projection GEMM, one launch. grid (3, 192):
//   y in [0,128): q = LN1(x1) @ qw^T  -> qbb row-major      (M=16384)
//   y in [128,160): k = x2b @ kw^T    -> kbb row-major      (M=4096)
//   y in [160,192): v = x2b @ vw^T    -> vtb transposed     (M=4096)
__global__ __launch_bounds__(256) void k_pgemm_qkv(
    const unsigned short* __restrict__ Aq,
    const unsigned short* __restrict__ Akv,
    const unsigned short* __restrict__ Wq,
    const unsigned short* __restrict__ Wk,
    const unsigned short* __restrict__ Wv,
    unsigned short* __restrict__ Qb,
    unsigned short* __restrict__ Kb,
    unsigned short* __restrict__ Vtb) {
  __shared__ unsigned short As[2 * 8192];
  __shared__ unsigned short Bs[2 * 8192];
  const int y = blockIdx.y;
  const int which = (y < 128) ? 0 : (y < 160) ? 1 : 2;
  const unsigned short* A = (which == 0) ? Aq : Akv;
  const unsigned short* W = (which == 0) ? Wq : (which == 1) ? Wk : Wv;
  const int bm = ((which == 0) ? y : (which == 1) ? (y - 128) : (y - 160)) * 128;
  const int bn = blockIdx.x * 128;
  f32x4 acc[4][4] = {};
  gemm128_db(A, W, NC, 6, bm, bn, As, Bs, acc);

  const int lane = threadIdx.x & 63, wv = threadIdx.x >> 6;
  const int col0 = bn + (wv & 1) * 64 + (lane & 15);
  const int row0 = bm + (wv >> 1) * 64 + (lane >> 4) * 4;
#pragma unroll
  for (int m = 0; m < 4; ++m) {
#pragma unroll
    for (int n = 0; n < 4; ++n) {
      int col = col0 + n * 16;
#pragma unroll
      for (int r = 0; r < 4; ++r) {
        int row = row0 + m * 16 + r;
        unsigned short bv = f2bf(acc[m][n][r]);
        if (which == 0) {
          Qb[(size_t)row * NC + col] = bv;
        } else if (which == 1) {
          Kb[(size_t)row * NC + col] = bv;
        } else {
          // vtb[(b*384 + col)*512 + j], b = row>>9, j = row&511
          Vtb[((size_t)((row >> 9) * 384 + col)) * 512 + (row & 511)] = bv;
        }
      }
    }
  }
}

// o-projection GEMM: x1a += attn @ ow^T (fused residual).
__global__ __launch_bounds__(256) void k_pgemm_o(
    const unsigned short* __restrict__ A,
    const unsigned short* __restrict__ W,
    float* __restrict__ Cf) {
  __shared__ unsigned short As[2 * 8192];
  __shared__ unsigned short Bs[2 * 8192];
  const int bn = blockIdx.x * 128;
  const int bm = blockIdx.y * 128;
  f32x4 acc[4][4] = {};
  gemm128_db(A, W, NC, 6, bm, bn, As, Bs, acc);

  const int lane = threadIdx.x & 63, wv = threadIdx.x >> 6;
  const int col0 = bn + (wv & 1) * 64 + (lane & 15);
  const int row0 = bm + (wv >> 1) * 64 + (lane >> 4) * 4;
#pragma unroll
  for (int m = 0; m < 4; ++m) {
#pragma unroll
    for (int n = 0; n < 4; ++n) {
      int col = col0 + n * 16;
#pragma unroll
      for (int r = 0; r < 4; ++r) {
        int row = row0 + m * 16 + r;
        size_t oi = (size_t)row * NC + col;
        Cf[oi] = acc[m][n][r] + Cf[oi];
      }
    }
  }
}

// FFN linear: x1a[m][n] += H[m][:]@lw[n][:] + lb[n].
// 128x96 tile (N split 4 ways) -> grid (4,128)=512 blocks = exactly 2/CU,
// no idle-CU tail. Same R2 schedule; 7 loads/thread/tile -> vmcnt(7).
// LDS 32+24 = 56 KB (2 blocks/CU). Per wave 64x48 (acc[4][3]).
__global__ __launch_bounds__(256) void k_lin_mfma(
    const unsigned short* __restrict__ H,
    const unsigned short* __restrict__ Wb,
    const float* __restrict__ lb,
    float* __restrict__ x1a) {
  __shared__ unsigned short As[2 * 8192];   // 32 KB
  __shared__ unsigned short Bs[2 * 6144];   // 24 KB
  const int bn = blockIdx.x * 96;
  const int bm = blockIdx.y * 128;
  const int tid = threadIdx.x;
  const int lane = tid & 63, wv = tid >> 6;
  const int rsel = lane & 15, ghi = lane >> 4;
  const int l8 = lane >> 3, g8 = lane & 7;
  const int gsrc = (g8 ^ l8) * 8;
  const size_t abase = (size_t)(bm + wv * 32 + l8) * NF + gsrc;
  const size_t bbase = (size_t)(bn + wv * 24 + l8) * NF + gsrc;

  f32x4 acc[4][3] = {};

#define LIN_STAGE(T, DB)                                                        \
  {                                                                             \
    const size_t k_ = (size_t)(T) * 64;                                         \
    GLOAD16(H + abase + k_, &As[(DB) * 8192 + (wv * 32) * 64]);                 \
    GLOAD16(H + abase + k_ + (size_t)8 * NF, &As[(DB) * 8192 + (wv * 32 + 8) * 64]);   \
    GLOAD16(H + abase + k_ + (size_t)16 * NF, &As[(DB) * 8192 + (wv * 32 + 16) * 64]); \
    GLOAD16(H + abase + k_ + (size_t)24 * NF, &As[(DB) * 8192 + (wv * 32 + 24) * 64]); \
    GLOAD16(Wb + bbase + k_, &Bs[(DB) * 6144 + (wv * 24) * 64]);                \
    GLOAD16(Wb + bbase + k_ + (size_t)8 * NF, &Bs[(DB) * 6144 + (wv * 24 + 8) * 64]);  \
    GLOAD16(Wb + bbase + k_ + (size_t)16 * NF, &Bs[(DB) * 6144 + (wv * 24 + 16) * 64]); \
  }

  LIN_STAGE(0, 0);
  LIN_STAGE(1, 1);
  asm volatile("s_waitcnt vmcnt(7)" ::: "memory");
  __builtin_amdgcn_sched_barrier(0);
  __builtin_amdgcn_s_barrier();

  const int arow = (wv >> 1) * 64;
  const int brow = (wv & 1) * 48;
  int db = 0;
  for (int t = 0; t < 24; ++t) {
    bf16x8 af[4][2], bfr[3][2];
#pragma unroll
    for (int m = 0; m < 4; ++m) {
      int r = arow + m * 16 + rsel;
#pragma unroll
      for (int k = 0; k < 2; ++k)
        af[m][k] = *(const bf16x8*)&As[db * 8192 + r * 64 + (((k * 4 + ghi) ^ (r & 7)) * 8)];
    }
#pragma unroll
    for (int n = 0; n < 3; ++n) {
      int r = brow + n * 16 + rsel;
#pragma unroll
      for (int k = 0; k < 2; ++k)
        bfr[n][k] = *(const bf16x8*)&Bs[db * 6144 + r * 64 + (((k * 4 + ghi) ^ (r & 7)) * 8)];
    }
    __builtin_amdgcn_s_setprio(1);
#pragma unroll
    for (int m = 0; m < 4; ++m)
#pragma unroll
      for (int n = 0; n < 3; ++n)
        acc[m][n] = __builtin_amdgcn_mfma_f32_16x16x32_bf16(af[m][0], bfr[n][0], acc[m][n], 0, 0, 0);
    __builtin_amdgcn_s_setprio(0);
    __builtin_amdgcn_sched_barrier(0);
    asm volatile("s_waitcnt lgkmcnt(0)" ::: "memory");
    __builtin_amdgcn_sched_barrier(0);
    __builtin_amdgcn_s_barrier();
    if (t + 2 < 24) LIN_STAGE(t + 2, db);
    __builtin_amdgcn_s_setprio(1);
#pragma unroll
    for (int m = 0; m < 4; ++m)
#pragma unroll
      for (int n = 0; n < 3; ++n)
        acc[m][n] = __builtin_amdgcn_mfma_f32_16x16x32_bf16(af[m][1], bfr[n][1], acc[m][n], 0, 0, 0);
    __builtin_amdgcn_s_setprio(0);
    __builtin_amdgcn_sched_barrier(0);
    if (t + 2 < 24) {
      asm volatile("s_waitcnt vmcnt(7)" ::: "memory");
    } else {
      asm volatile("s_waitcnt vmcnt(0)" ::: "memory");
    }
    __builtin_amdgcn_sched_barrier(0);
    __builtin_amdgcn_s_barrier();
    db ^= 1;
  }
#undef LIN_STAGE

  const int col0 = bn + (wv & 1) * 48 + rsel;
  const int row0 = bm + (wv >> 1) * 64 + ghi * 4;
#pragma unroll
  for (int m = 0; m < 4; ++m) {
#pragma unroll
    for (int n = 0; n < 3; ++n) {
      int col = col0 + n * 16;
      float lbv = lb[col];
#pragma unroll
      for (int r = 0; r < 4; ++r) {
        int row = row0 + m * 16 + r;
        size_t oi = (size_t)row * NC + col;
        x1a[oi] = acc[m][n][r] + lbv + x1a[oi];
      }
    }
  }
}

// Conv1d(C->4C,k=9,SAME) implicit GEMM. 128x128 tile, BK=64, 4 waves (2Mx2N),
// R2 schedule (dbuf, distance-2 prefetch, counted vmcnt(8), granule-XOR
// swizzle), tap-aware A addressing. 64 KB LDS -> 2 blocks/CU (m114 overlap).
// Grid (128, 12) x-fastest = 1536 blocks = exactly 3 rounds at 2/CU.
// Fused (+cb)*9^-0.5 -> gelu(exact) -> bf16 store.  [R10: 186 us, 935 TF]
__global__ __launch_bounds__(256) void k_conv_mfma(
    const unsigned short* __restrict__ Ypad,
    const unsigned short* __restrict__ Wp,
    const float* __restrict__ cb,
    unsigned short* __restrict__ H) {
  __shared__ unsigned short As[2 * 8192];   // 32 KB
  __shared__ unsigned short Bs[2 * 8192];   // 32 KB
  const int bm = blockIdx.x * 128;          // x-fastest: XCD=id%8, A panels L2-hot
  const int bn = blockIdx.y * 128;
  const int b = bm >> 11, t0 = bm & 2047;
  const int tid = threadIdx.x;
  const int lane = tid & 63, wv = tid >> 6;
  const int rsel = lane & 15, ghi = lane >> 4;
  const int l8 = lane >> 3, g8 = lane & 7;
  const int gsrc = (g8 ^ l8) * 8;           // pre-swizzled source granule (shorts)

  f32x4 acc[4][4] = {};

  const size_t arow0 = (size_t)(b * TPAD + t0 + wv * 32 + l8);   // A stage row
  const size_t brow0 = (size_t)(bn + wv * 32 + l8);              // B stage row

#define CONV_STAGE(T, DB)                                                       \
  {                                                                             \
    const int kt_ = (T) * 64;                                                   \
    const int kk_ = kt_ / NC;                                                   \
    const int c0_ = kt_ - kk_ * NC;                                             \
    const size_t asrc_ = (arow0 + kk_) * NC + c0_ + gsrc;                       \
    GLOAD16(Ypad + asrc_, &As[(DB) * 8192 + (wv * 32) * 64]);                   \
    GLOAD16(Ypad + asrc_ + (size_t)8 * NC, &As[(DB) * 8192 + (wv * 32 + 8) * 64]);   \
    GLOAD16(Ypad + asrc_ + (size_t)16 * NC, &As[(DB) * 8192 + (wv * 32 + 16) * 64]); \
    GLOAD16(Ypad + asrc_ + (size_t)24 * NC, &As[(DB) * 8192 + (wv * 32 + 24) * 64]); \
    const size_t bsrc_ = brow0 * NKI + kt_ + gsrc;                              \
    GLOAD16(Wp + bsrc_, &Bs[(DB) * 8192 + (wv * 32) * 64]);                     \
    GLOAD16(Wp + bsrc_ + (size_t)8 * NKI, &Bs[(DB) * 8192 + (wv * 32 + 8) * 64]);    \
    GLOAD16(Wp + bsrc_ + (size_t)16 * NKI, &Bs[(DB) * 8192 + (wv * 32 + 16) * 64]);  \
    GLOAD16(Wp + bsrc_ + (size_t)24 * NKI, &Bs[(DB) * 8192 + (wv * 32 + 24) * 64]);  \
  }

  CONV_STAGE(0, 0);
  CONV_STAGE(1, 1);
  asm volatile("s_waitcnt vmcnt(8)" ::: "memory");
  __builtin_amdgcn_sched_barrier(0);
  __builtin_amdgcn_s_barrier();

  const int arow = (wv >> 1) * 64;
  const int brow = (wv & 1) * 64;
  int db = 0;
  for (int t = 0; t < 54; ++t) {
    bf16x8 af[4][2], bfr[4][2];
#pragma unroll
    for (int m = 0; m < 4; ++m) {
      int r = arow + m * 16 + rsel;
#pragma unroll
      for (int k = 0; k < 2; ++k)
        af[m][k] = *(const bf16x8*)&As[db * 8192 + r * 64 + (((k * 4 + ghi) ^ (r & 7)) * 8)];
    }
#pragma unroll
    for (int n = 0; n < 4; ++n) {
      int r = brow + n * 16 + rsel;
#pragma unroll
      for (int k = 0; k < 2; ++k)
        bfr[n][k] = *(const bf16x8*)&Bs[db * 8192 + r * 64 + (((k * 4 + ghi) ^ (r & 7)) * 8)];
    }
    __builtin_amdgcn_s_setprio(1);
#pragma unroll
    for (int m = 0; m < 4; ++m)
#pragma unroll
      for (int n = 0; n < 4; ++n)
        acc[m][n] = __builtin_amdgcn_mfma_f32_16x16x32_bf16(af[m][0], bfr[n][0], acc[m][n], 0, 0, 0);
    __builtin_amdgcn_s_setprio(0);
    __builtin_amdgcn_sched_barrier(0);
    asm volatile("s_waitcnt lgkmcnt(0)" ::: "memory");
    __builtin_amdgcn_sched_barrier(0);
    __builtin_amdgcn_s_barrier();
    if (t + 2 < 54) CONV_STAGE(t + 2, db);
    __builtin_amdgcn_s_setprio(1);
#pragma unroll
    for (int m = 0; m < 4; ++m)
#pragma unroll
      for (int n = 0; n < 4; ++n)
        acc[m][n] = __builtin_amdgcn_mfma_f32_16x16x32_bf16(af[m][1], bfr[n][1], acc[m][n], 0, 0, 0);
    __builtin_amdgcn_s_setprio(0);
    __builtin_amdgcn_sched_barrier(0);
    if (t + 2 < 54) {
      asm volatile("s_waitcnt vmcnt(8)" ::: "memory");
    } else {
      asm volatile("s_waitcnt vmcnt(0)" ::: "memory");
    }
    __builtin_amdgcn_sched_barrier(0);
    __builtin_amdgcn_s_barrier();
    db ^= 1;
  }
#undef CONV_STAGE

  const int col0 = bn + (wv & 1) * 64 + rsel;
  const int row0 = bm + (wv >> 1) * 64 + ghi * 4;
#pragma unroll
  for (int m = 0; m < 4; ++m) {
#pragma unroll
    for (int n = 0; n < 4; ++n) {
      int col = col0 + n * 16;
      float cbv = cb[col];
#pragma unroll
      for (int r = 0; r < 4; ++r) {
        int row = row0 + m * 16 + r;
        float xv = (acc[m][n][r] + cbv) * 0.33333333333333333f;
        float ge = 0.5f * xv * (1.f + erff(xv * 0.70710678118654752f));
        H[(size_t)row * NF + col] = f2bf(ge);
      }
    }
  }
}

// Windowed cross-attention, MFMA flash-style. bf16 output (feeds o-projection).
__global__ __launch_bounds__(256) void k_attn_mfma(
    const unsigned short* __restrict__ qbb,   // [8*2048][384] bf16 (q*scaling folded in W)
    const unsigned short* __restrict__ kbb,   // [8*512][384] bf16
    const unsigned short* __restrict__ vtb,   // [(b*2+h)*192+d][512] bf16
    unsigned short* __restrict__ o, int guided, float* __restrict__ gl) {
  __shared__ unsigned short lds[32768];
  const int tid = threadIdx.x;
  const int lane = tid & 63, wv = tid >> 6;
  const int rsel = lane & 15, ghi = lane >> 4;
  const int idx = blockIdx.x;
  const int tg = idx & 31;
  const int bh = idx >> 5;
  const int h = bh & 1, b = bh >> 1;
  const int t0 = tg * 64;
  const int c0 = t0 >> 2;
  int klo = c0 - 51; if (klo < 0) klo = 0;
  klo &= ~7;                       // 16B-align for global_load_lds on vtb
  if (klo > 384) klo = 384;        // keep window inside [0,512)

  // Q fragments: A-operand layout, row = lane&15, k = ghi*8 (+32 per step)
  const unsigned short* qrow = qbb + (size_t)(b * NT1 + t0 + wv * 16 + rsel) * NC + h * ND;
  bf16x8 qf[6];
#pragma unroll
  for (int kk = 0; kk < 6; ++kk)
    qf[kk] = *(const bf16x8*)(qrow + kk * 32 + ghi * 8);

  // stage K window [128 keys][192] bf16, source pre-swizzled (granule ^ row&7)
  {
    const size_t kbase = (size_t)(b * NT2 + klo) * NC + h * ND;
#pragma unroll
    for (int it = 0; it < 12; ++it) {
      int g = it * 256 + tid;
      int row = g / 24, go = g % 24;
      int gs = go ^ (row & 7);
      GLOAD16(kbb + kbase + (size_t)row * NC + gs * 8, &lds[(it * 256 + wv * 64) * 8]);
    }
  }
  __syncthreads();

  // QK^T: 16 queries x 128 keys per wave
  f32x4 accs[8] = {};
#pragma unroll
  for (int kk = 0; kk < 6; ++kk) {
#pragma unroll
    for (int n = 0; n < 8; ++n) {
      int row = n * 16 + rsel;
      bf16x8 bfr = *(const bf16x8*)&lds[row * 192 + (((kk * 4 + ghi) ^ (rsel & 7)) * 8)];
      accs[n] = __builtin_amdgcn_mfma_f32_16x16x32_bf16(qf[kk], bfr, accs[n], 0, 0, 0);
    }
  }

  // masked softmax per query row; rows live on 16-lane groups (row=ghi*4+r, col=rsel)
  unsigned short* pl = &lds[24576 + wv * 2048];
  float gacc = 0.f;
  const int t0w = t0 + wv * 16;
#pragma unroll
  for (int r = 0; r < 4; ++r) {
    int t = t0w + ghi * 4 + r;
    int c = t >> 2;
    int loq = c - 51; if (loq < 0) loq = 0;
    int hiq = c + 51; if (hiq > NT2) hiq = NT2;
    float sv[8];
    float mx = -1e30f;
#pragma unroll
    for (int n = 0; n < 8; ++n) {
      int j = klo + n * 16 + rsel;
      float s = (j >= loq && j < hiq) ? accs[n][r] : -1e30f;
      sv[n] = s; mx = fmaxf(mx, s);
    }
#pragma unroll
    for (int off = 1; off < 16; off <<= 1) mx = fmaxf(mx, __shfl_xor(mx, off));
    float e[8]; float se = 0.f;
#pragma unroll
    for (int n = 0; n < 8; ++n) { e[n] = __expf(sv[n] - mx); se += e[n]; }
#pragma unroll
    for (int off = 1; off < 16; off <<= 1) se += __shfl_xor(se, off);
    float inv = 1.f / se;
    int q = ghi * 4 + r;
#pragma unroll
    for (int n = 0; n < 8; ++n) {
      float pv = e[n] * inv;
      int klocal = n * 16 + rsel;
      pl[q * 128 + (((klocal >> 3) ^ (q & 7)) * 8) + (klocal & 7)] = f2bf(pv);
      if (guided) {
        int j = klo + klocal;
        float d = (float)j * (1.f / NT2) - (float)t * (1.f / NT1);
        gacc += pv * (1.f - __expf(-(d * d) * 5.5555555556f));
      }
    }
  }
  if (guided) {
    gacc = warp_sum(gacc);
    if (lane == 0) atomicAdd(gl, gacc * (1.f / 16777216.f));
  }
  __syncthreads();

  // stage VT window [192 chans][128 keys] bf16 into the K buffer (reuse)
  {
    const size_t vbase = ((size_t)(b * 2 + h) * ND) * NT2 + klo;
#pragma unroll
    for (int it = 0; it < 12; ++it) {
      int g = it * 256 + tid;
      int row = g >> 4, go = g & 15;
      int gs = go ^ (row & 7);
      GLOAD16(vtb + vbase + (size_t)row * NT2 + gs * 8, &lds[(it * 256 + wv * 64) * 8]);
    }
  }
  __syncthreads();

  // PV: P[16x128] @ V[128x192] -> O[16x192]
  f32x4 acco[12] = {};
#pragma unroll
  for (int kt = 0; kt < 4; ++kt) {
    bf16x8 pa = *(const bf16x8*)&pl[rsel * 128 + (((kt * 4 + ghi) ^ (rsel & 7)) * 8)];
#pragma unroll
    for (int n = 0; n < 12; ++n) {
      int row = n * 16 + rsel;
      bf16x8 bfr = *(const bf16x8*)&lds[row * 128 + (((kt * 4 + ghi) ^ (rsel & 7)) * 8)];
      acco[n] = __builtin_amdgcn_mfma_f32_16x16x32_bf16(pa, bfr, acco[n], 0, 0, 0);
    }
  }

  unsigned short* obase = o + (size_t)(b * NT1 + t0w + ghi * 4) * NC + h * ND;
#pragma unroll
  for (int n = 0; n < 12; ++n) {
#pragma unroll
    for (int r = 0; r < 4; ++r) {
      obase[(size_t)r * NC + n * 16 + rsel] = f2bf(acco[n][r]);
    }
  }
}

extern "C" void kernel_launch(void* const* d_in, const int* in_sizes, int n_in,
                              void* d_out, int out_size, void* d_ws, size_t ws_size,
                              hipStream_t stream) {
  (void)in_sizes; (void)n_in; (void)out_size; (void)ws_size;
  const float* x1    = (const float*)d_in[0];
  const float* x2    = (const float*)d_in[1];
  const float* alpha = (const float*)d_in[2];
  const float* ln1_g = (const float*)d_in[3];
  const float* ln1_b = (const float*)d_in[4];
  const float* qw    = (const float*)d_in[5];
  const float* kw    = (const float*)d_in[6];
  const float* vw    = (const float*)d_in[7];
  const float* ow    = (const float*)d_in[8];
  const float* ln2_g = (const float*)d_in[9];
  const float* ln2_b = (const float*)d_in[10];
  const float* cw    = (const float*)d_in[11];
  const float* cb    = (const float*)d_in[12];
  const float* lw    = (const float*)d_in[13];
  const float* lb    = (const float*)d_in[14];
  const float* lnf_g = (const float*)d_in[15];
  const float* lnf_b = (const float*)d_in[16];
  float* out = (float*)d_out;
  float* gl = out + 6291456;   // guided-loss scalar slot

  float* p = (float*)d_ws;
  float* x1a = p; p += 6291456;    // x1 state [16384,384] f32
  // bf16 region (16B-aligned)
  unsigned short* us = (unsigned short*)p;
  unsigned short* x2b  = us; us += 1572864;            // x2+pos bf16 [4096][384]
  unsigned short* tmpb = us; us += 6291456;            // LN1 out / attn out bf16
  unsigned short* ypad = us; us += 8 * TPAD * NC;      // 6316032
  unsigned short* cwpb = us; us += 2 * (size_t)NF * NKI;   // 10616832 (both layers)
  unsigned short* lwb  = us; us += 2 * (size_t)NC * NF;    // 1179648 (both layers)
  unsigned short* hb   = us; us += (size_t)16384 * NF; // 25165824
  unsigned short* qbb  = us; us += 6291456;            // q bf16 [16384][384]
  unsigned short* kbb  = us; us += 1572864;            // k bf16 [4096][384]
  unsigned short* vtb  = us; us += 1572864;            // v^T bf16 [32*192][512]
  unsigned short* qwb  = us; us += 294912;             // weights bf16 (contiguous qkvo)
  unsigned short* kwb  = us; us += 294912;
  unsigned short* vwb  = us; us += 294912;
  unsigned short* owb  = us; us += 294912;

  hipMemsetAsync(gl, 0, sizeof(float), stream);  // atomic accumulator, re-zeroed every launch
  k_add_pos2<<<12288, 256, 0, stream>>>(x1, alpha, x1a, NT1, 3145728);
  k_add_pos2_bf16<<<3168, 256, 0, stream>>>(x2, alpha, x2b, NT2, 786432, ypad);

  const float scaling = 0.07216878364870323f;   // 192^-0.5
  // weight conversions, both layers, hoisted + fused into 2 launches
  k_cvt_all<<<9216, 256, 0, stream>>>(qw, kw, vw, ow, lw, qwb, lwb, scaling);
  k_pack_cw2<<<3072, 256, 0, stream>>>(cw, cwpb);

  for (int l = 0; l < 2; ++l) {
    k_ln_bf16<<<4096, 256, 0, stream>>>(x1a, ln1_g + l * 384, ln1_b + l * 384, tmpb);
    k_pgemm_qkv<<<dim3(3, 192), 256, 0, stream>>>(tmpb, x2b,
        qwb + (size_t)l * 147456, kwb + (size_t)l * 147456, vwb + (size_t)l * 147456,
        qbb, kbb, vtb);
    k_attn_mfma<<<512, 256, 0, stream>>>(qbb, kbb, vtb, tmpb, l == 0 ? 1 : 0, gl);
    k_pgemm_o<<<dim3(3, 128), 256, 0, stream>>>(tmpb, owb + (size_t)l * 147456, x1a);
    // FFN: ln2 -> bf16 padded, conv implicit GEMM (128² dbuf, 2/CU), linear (96-N split)
    k_ln_bf16p<<<4096, 256, 0, stream>>>(x1a, ln2_g + l * 384, ln2_b + l * 384, ypad);
    k_conv_mfma<<<dim3(128, 12), 256, 0, stream>>>(ypad, cwpb + (size_t)l * 5308416, cb + l * 1536, hb);
    k_lin_mfma<<<dim3(4, 128), 256, 0, stream>>>(hb, lwb + (size_t)l * 589824, lb + l * 384, x1a);
  }
  k_ln<<<4096, 256, 0, stream>>>(x1a, lnf_g, lnf_b, out, 16384);
}

// Round 12
// 627.584 us; speedup vs baseline: 1.2664x; 1.0001x over previous
//
#include <hip/hip_runtime.h>
#include <math.h>

#define NB 8
#define NT1 2048
#define NT2 512
#define NC 384
#define ND 192
#define NF 1536
#define NKI 3456   // 9*384 implicit-GEMM K for conv
#define TPAD 2056  // 2048 + 4 guard rows top and bottom

typedef __attribute__((ext_vector_type(8))) short bf16x8;
typedef __attribute__((ext_vector_type(4))) float f32x4;

#define GLOAD16(gsrc, ldst) \
  __builtin_amdgcn_global_load_lds((const __attribute__((address_space(1))) void*)(gsrc), \
                                   (__attribute__((address_space(3))) void*)(ldst), 16, 0, 0)

static __device__ __forceinline__ unsigned short f2bf(float f) {
  unsigned int u = __float_as_uint(f);
  unsigned int r = (u + 0x7fffu + ((u >> 16) & 1u)) >> 16;
  return (unsigned short)r;
}

static __device__ __forceinline__ float warp_sum(float v) {
#pragma unroll
  for (int off = 32; off > 0; off >>= 1) v += __shfl_xor(v, off);
  return v;
}

// x += alpha * sin-pos; thread handles (t,j) pair: sin at c=j, cos at c=j+192
__global__ __launch_bounds__(256) void k_add_pos2(const float* __restrict__ x,
    const float* __restrict__ alpha_p, float* __restrict__ y, int T, int total2) {
  int i = blockIdx.x * 256 + threadIdx.x;
  if (i >= total2) return;
  int j = i % 192;
  int row = i / 192;
  int t = row % T;
  float freq = __expf(-0.0482216773f * (float)j);   // ln(10000)/191
  float ang = (float)(t + 1) * freq;
  float sn, cs;
  __sincosf(ang, &sn, &cs);
  float a = alpha_p[0];
  size_t base = (size_t)row * NC;
  y[base + j] = x[base + j] + a * sn;
  y[base + j + 192] = x[base + j + 192] + a * cs;
}

// x2+pos -> bf16; trailing threads zero the ypad guard rows (fused k_zero_guard)
__global__ __launch_bounds__(256) void k_add_pos2_bf16(const float* __restrict__ x,
    const float* __restrict__ alpha_p, unsigned short* __restrict__ y, int T, int total2,
    unsigned short* __restrict__ ypad) {
  int i = blockIdx.x * 256 + threadIdx.x;
  if (i >= total2) {
    int g = i - total2;                       // 24576 guard elements
    if (g < 24576) {
      int c = g % NC;
      int r = (g / NC) % 8;
      int b = g / (NC * 8);
      int t = (r < 4) ? r : (2048 + r);       // rows 0..3 and 2052..2055
      ypad[((size_t)b * TPAD + t) * NC + c] = 0;
    }
    return;
  }
  int j = i % 192;
  int row = i / 192;
  int t = row % T;
  float freq = __expf(-0.0482216773f * (float)j);
  float ang = (float)(t + 1) * freq;
  float sn, cs;
  __sincosf(ang, &sn, &cs);
  float a = alpha_p[0];
  size_t base = (size_t)row * NC;
  y[base + j] = f2bf(x[base + j] + a * sn);
  y[base + j + 192] = f2bf(x[base + j + 192] + a * cs);
}

// LayerNorm over last dim (384). One wave per row. fp32 out (final LN).
__global__ __launch_bounds__(256) void k_ln(const float* __restrict__ x,
    const float* __restrict__ g, const float* __restrict__ b,
    float* __restrict__ y, int nrows) {
  int row = blockIdx.x * 4 + (threadIdx.x >> 6);
  int lane = threadIdx.x & 63;
  if (row >= nrows) return;
  const float* xr = x + (size_t)row * NC;
  float v[6];
  float s = 0.f, s2 = 0.f;
#pragma unroll
  for (int i = 0; i < 6; ++i) {
    float t = xr[lane + 64 * i];
    v[i] = t; s += t; s2 += t * t;
  }
  s = warp_sum(s); s2 = warp_sum(s2);
  float mean = s * (1.f / NC);
  float var = s2 * (1.f / NC) - mean * mean;
  float rs = rsqrtf(var + 1e-5f);
  float* yr = y + (size_t)row * NC;
#pragma unroll
  for (int i = 0; i < 6; ++i) {
    int cc = lane + 64 * i;
    yr[cc] = (v[i] - mean) * rs * g[cc] + b[cc];
  }
}

// LayerNorm -> bf16 (unpadded), feeds MFMA projections
__global__ __launch_bounds__(256) void k_ln_bf16(const float* __restrict__ x,
    const float* __restrict__ g, const float* __restrict__ b,
    unsigned short* __restrict__ y) {
  int row = blockIdx.x * 4 + (threadIdx.x >> 6);
  int lane = threadIdx.x & 63;
  const float* xr = x + (size_t)row * NC;
  float v[6];
  float s = 0.f, s2 = 0.f;
#pragma unroll
  for (int i = 0; i < 6; ++i) {
    float t = xr[lane + 64 * i];
    v[i] = t; s += t; s2 += t * t;
  }
  s = warp_sum(s); s2 = warp_sum(s2);
  float mean = s * (1.f / NC);
  float var = s2 * (1.f / NC) - mean * mean;
  float rs = rsqrtf(var + 1e-5f);
  unsigned short* yr = y + (size_t)row * NC;
#pragma unroll
  for (int i = 0; i < 6; ++i) {
    int cc = lane + 64 * i;
    yr[cc] = f2bf((v[i] - mean) * rs * g[cc] + b[cc]);
  }
}

// LayerNorm -> bf16 into guard-padded [8][2056][384] buffer (row t -> t+4)
__global__ __launch_bounds__(256) void k_ln_bf16p(const float* __restrict__ x,
    const float* __restrict__ g, const float* __restrict__ b,
    unsigned short* __restrict__ ypad) {
  int row = blockIdx.x * 4 + (threadIdx.x >> 6);
  int lane = threadIdx.x & 63;
  const float* xr = x + (size_t)row * NC;
  float v[6];
  float s = 0.f, s2 = 0.f;
#pragma unroll
  for (int i = 0; i < 6; ++i) {
    float t = xr[lane + 64 * i];
    v[i] = t; s += t; s2 += t * t;
  }
  s = warp_sum(s); s2 = warp_sum(s2);
  float mean = s * (1.f / NC);
  float var = s2 * (1.f / NC) - mean * mean;
  float rs = rsqrtf(var + 1e-5f);
  int bb = row >> 11, t = row & 2047;
  unsigned short* yr = ypad + ((size_t)(bb * TPAD + t + 4)) * NC;
#pragma unroll
  for (int i = 0; i < 6; ++i) {
    int cc = lane + 64 * i;
    yr[cc] = f2bf((v[i] - mean) * rs * g[cc] + b[cc]);
  }
}

// pack + convert cw[f][c][kk] -> cwp[f][kk*384+c] bf16. One block per f-row,
// coalesced load -> LDS -> coalesced store (LDS read stride 9: conflict-free).
__global__ __launch_bounds__(256) void k_pack_cw2(const float* __restrict__ cw,
    unsigned short* __restrict__ cwp) {
  __shared__ float s[NKI];
  int f = blockIdx.x;
  const float* src = cw + (size_t)f * NKI;
  for (int i = threadIdx.x; i < NKI; i += 256) s[i] = src[i];
  __syncthreads();
  unsigned short* dst = cwp + (size_t)f * NKI;
  for (int i = threadIdx.x; i < NKI; i += 256) {
    int kk = i / NC, cc = i - kk * NC;
    dst[i] = f2bf(s[cc * 9 + kk]);
  }
}

// merged weight convert: lw (1179648) -> lwb, then qkvo (4x294912) -> qkvob, q scaled
__global__ __launch_bounds__(256) void k_cvt_all(const float* __restrict__ qw,
    const float* __restrict__ kw, const float* __restrict__ vw,
    const float* __restrict__ ow, const float* __restrict__ lw,
    unsigned short* __restrict__ qkvob, unsigned short* __restrict__ lwb, float qscale) {
  int i = blockIdx.x * 256 + threadIdx.x;
  if (i >= 2359296) return;
  if (i < 1179648) { lwb[i] = f2bf(lw[i]); return; }
  int k = i - 1179648;
  int w = k / 294912;
  int j = k - w * 294912;
  const float* s = (w == 0) ? qw : (w == 1) ? kw : (w == 2) ? vw : ow;
  float sc = (w == 0) ? qscale : 1.f;
  qkvob[k] = f2bf(s[j] * sc);
}

// Shared 128x96 GEMM inner loop, R2-proven schedule: BK=64, double-buffered
// LDS, distance-2 prefetch, counted vmcnt(7) (7 loads/thread/tile, never 0
// mid-loop), granule-XOR swizzle (pre-swizzled global src + XOR'd ds_read).
// A rows bm..bm+127 of [*,K]; W rows bn..bn+95 of [*,K]. 256 threads, 4 waves
// (2M x 2N, 64x48 per wave). LDS 32+24 = 56 KB -> 2 blocks/CU.
static __device__ __forceinline__ void gemm96_db(
    const unsigned short* __restrict__ A,
    const unsigned short* __restrict__ W,
    int K, int ntiles, int bm, int bn,
    unsigned short* AsB, unsigned short* BsB,
    f32x4 (&acc)[4][3]) {
  const int tid = threadIdx.x;
  const int lane = tid & 63, wv = tid >> 6;
  const int rsel = lane & 15, ghi = lane >> 4;
  const int l8 = lane >> 3, g8 = lane & 7;
  const int gsrc = (g8 ^ l8) * 8;              // pre-swizzled source granule
  const size_t abase = (size_t)(bm + wv * 32 + l8) * K + gsrc;
  const size_t bbase = (size_t)(bn + wv * 24 + l8) * K + gsrc;

#define G96_STAGE(T, DB)                                                        \
  {                                                                             \
    const size_t k_ = (size_t)(T) * 64;                                         \
    GLOAD16(A + abase + k_, AsB + (DB) * 8192 + (wv * 32) * 64);                \
    GLOAD16(A + abase + k_ + (size_t)8 * K, AsB + (DB) * 8192 + (wv * 32 + 8) * 64);   \
    GLOAD16(A + abase + k_ + (size_t)16 * K, AsB + (DB) * 8192 + (wv * 32 + 16) * 64); \
    GLOAD16(A + abase + k_ + (size_t)24 * K, AsB + (DB) * 8192 + (wv * 32 + 24) * 64); \
    GLOAD16(W + bbase + k_, BsB + (DB) * 6144 + (wv * 24) * 64);                \
    GLOAD16(W + bbase + k_ + (size_t)8 * K, BsB + (DB) * 6144 + (wv * 24 + 8) * 64);   \
    GLOAD16(W + bbase + k_ + (size_t)16 * K, BsB + (DB) * 6144 + (wv * 24 + 16) * 64); \
  }

  G96_STAGE(0, 0);
  G96_STAGE(1, 1);
  asm volatile("s_waitcnt vmcnt(7)" ::: "memory");
  __builtin_amdgcn_sched_barrier(0);
  __builtin_amdgcn_s_barrier();

  const int arow = (wv >> 1) * 64;
  const int brow = (wv & 1) * 48;
  int db = 0;
  for (int t = 0; t < ntiles; ++t) {
    bf16x8 af[4][2], bfr[3][2];
#pragma unroll
    for (int m = 0; m < 4; ++m) {
      int r = arow + m * 16 + rsel;
#pragma unroll
      for (int k = 0; k < 2; ++k)
        af[m][k] = *(const bf16x8*)&AsB[db * 8192 + r * 64 + (((k * 4 + ghi) ^ (r & 7)) * 8)];
    }
#pragma unroll
    for (int n = 0; n < 3; ++n) {
      int r = brow + n * 16 + rsel;
#pragma unroll
      for (int k = 0; k < 2; ++k)
        bfr[n][k] = *(const bf16x8*)&BsB[db * 6144 + r * 64 + (((k * 4 + ghi) ^ (r & 7)) * 8)];
    }
    __builtin_amdgcn_s_setprio(1);
#pragma unroll
    for (int m = 0; m < 4; ++m)
#pragma unroll
      for (int n = 0; n < 3; ++n)
        acc[m][n] = __builtin_amdgcn_mfma_f32_16x16x32_bf16(af[m][0], bfr[n][0], acc[m][n], 0, 0, 0);
    __builtin_amdgcn_s_setprio(0);
    __builtin_amdgcn_sched_barrier(0);
    asm volatile("s_waitcnt lgkmcnt(0)" ::: "memory");
    __builtin_amdgcn_sched_barrier(0);
    __builtin_amdgcn_s_barrier();
    if (t + 2 < ntiles) G96_STAGE(t + 2, db);
    __builtin_amdgcn_s_setprio(1);
#pragma unroll
    for (int m = 0; m < 4; ++m)
#pragma unroll
      for (int n = 0; n < 3; ++n)
        acc[m][n] = __builtin_amdgcn_mfma_f32_16x16x32_bf16(af[m][1], bfr[n][1], acc[m][n], 0, 0, 0);
    __builtin_amdgcn_s_setprio(0);
    __builtin_amdgcn_sched_barrier(0);
    if (t + 2 < ntiles) {
      asm volatile("s_waitcnt vmcnt(7)" ::: "memory");
    } else {
      asm volatile("s_waitcnt vmcnt(0)" ::: "memory");
    }
    __builtin_amdgcn_sched_barrier(0);
    __builtin_amdgcn_s_barrier();
    db ^= 1;
  }
#undef G96_STAGE
}

// Merged q/k/v projection GEMM, one launch. grid (4, 192), 96-wide N tiles:
//   y in [0,128): q = LN1(x1) @ qw^T  -> qbb row-major      (M=16384)
//   y in [128,160): k = x2b @ kw^T    -> kbb row-major      (M=4096)
//   y in [160,192): v = x2b @ vw^T    -> vtb transposed     (M=4096)
// 768 blocks = exactly 1.5 packed rounds at 2 blocks/CU.
__global__ __launch_bounds__(256) void k_pgemm_qkv(
    const unsigned short* __restrict__ Aq,
    const unsigned short* __restrict__ Akv,
    const unsigned short* __restrict__ Wq,
    const unsigned short* __restrict__ Wk,
    const unsigned short* __restrict__ Wv,
    unsigned short* __restrict__ Qb,
    unsigned short* __restrict__ Kb,
    unsigned short* __restrict__ Vtb) {
  __shared__ unsigned short As[2 * 8192];
  __shared__ unsigned short Bs[2 * 6144];
  const int y = blockIdx.y;
  const int which = (y < 128) ? 0 : (y < 160) ? 1 : 2;
  const unsigned short* A = (which == 0) ? Aq : Akv;
  const unsigned short* W = (which == 0) ? Wq : (which == 1) ? Wk : Wv;
  const int bm = ((which == 0) ? y : (which == 1) ? (y - 128) : (y - 160)) * 128;
  const int bn = blockIdx.x * 96;
  f32x4 acc[4][3] = {};
  gemm96_db(A, W, NC, 6, bm, bn, As, Bs, acc);

  const int lane = threadIdx.x & 63, wv = threadIdx.x >> 6;
  const int col0 = bn + (wv & 1) * 48 + (lane & 15);
  const int row0 = bm + (wv >> 1) * 64 + (lane >> 4) * 4;
#pragma unroll
  for (int m = 0; m < 4; ++m) {
#pragma unroll
    for (int n = 0; n < 3; ++n) {
      int col = col0 + n * 16;
#pragma unroll
      for (int r = 0; r < 4; ++r) {
        int row = row0 + m * 16 + r;
        unsigned short bv = f2bf(acc[m][n][r]);
        if (which == 0) {
          Qb[(size_t)row * NC + col] = bv;
        } else if (which == 1) {
          Kb[(size_t)row * NC + col] = bv;
        } else {
          // vtb[(b*384 + col)*512 + j], b = row>>9, j = row&511
          Vtb[((size_t)((row >> 9) * 384 + col)) * 512 + (row & 511)] = bv;
        }
      }
    }
  }
}

// o-projection GEMM: x1a += attn @ ow^T (fused residual). grid (4,128) = 512
// blocks = exactly one packed round at 2 blocks/CU.
__global__ __launch_bounds__(256) void k_pgemm_o(
    const unsigned short* __restrict__ A,
    const unsigned short* __restrict__ W,
    float* __restrict__ Cf) {
  __shared__ unsigned short As[2 * 8192];
  __shared__ unsigned short Bs[2 * 6144];
  const int bn = blockIdx.x * 96;
  const int bm = blockIdx.y * 128;
  f32x4 acc[4][3] = {};
  gemm96_db(A, W, NC, 6, bm, bn, As, Bs, acc);

  const int lane = threadIdx.x & 63, wv = threadIdx.x >> 6;
  const int col0 = bn + (wv & 1) * 48 + (lane & 15);
  const int row0 = bm + (wv >> 1) * 64 + (lane >> 4) * 4;
#pragma unroll
  for (int m = 0; m < 4; ++m) {
#pragma unroll
    for (int n = 0; n < 3; ++n) {
      int col = col0 + n * 16;
#pragma unroll
      for (int r = 0; r < 4; ++r) {
        int row = row0 + m * 16 + r;
        size_t oi = (size_t)row * NC + col;
        Cf[oi] = acc[m][n][r] + Cf[oi];
      }
    }
  }
}

// FFN linear: x1a[m][n] += H[m][:]@lw[n][:] + lb[n]. grid (4,128) = 512 = 2/CU.
__global__ __launch_bounds__(256) void k_lin_mfma(
    const unsigned short* __restrict__ H,
    const unsigned short* __restrict__ Wb,
    const float* __restrict__ lb,
    float* __restrict__ x1a) {
  __shared__ unsigned short As[2 * 8192];
  __shared__ unsigned short Bs[2 * 6144];
  const int bn = blockIdx.x * 96;
  const int bm = blockIdx.y * 128;
  f32x4 acc[4][3] = {};
  gemm96_db(H, Wb, NF, 24, bm, bn, As, Bs, acc);

  const int lane = threadIdx.x & 63, wv = threadIdx.x >> 6;
  const int col0 = bn + (wv & 1) * 48 + (lane & 15);
  const int row0 = bm + (wv >> 1) * 64 + (lane >> 4) * 4;
#pragma unroll
  for (int m = 0; m < 4; ++m) {
#pragma unroll
    for (int n = 0; n < 3; ++n) {
      int col = col0 + n * 16;
      float lbv = lb[col];
#pragma unroll
      for (int r = 0; r < 4; ++r) {
        int row = row0 + m * 16 + r;
        size_t oi = (size_t)row * NC + col;
        x1a[oi] = acc[m][n][r] + lbv + x1a[oi];
      }
    }
  }
}

// Conv1d(C->4C,k=9,SAME) implicit GEMM. 128x128 tile, BK=64, 4 waves (2Mx2N),
// R2 schedule (dbuf, distance-2 prefetch, counted vmcnt(8), granule-XOR
// swizzle), tap-aware A addressing. 64 KB LDS -> 2 blocks/CU (m114 overlap).
// Grid (128, 12) x-fastest = 1536 blocks = exactly 3 rounds at 2/CU.
// Fused (+cb)*9^-0.5 -> gelu(exact) -> bf16 store.  [R10: 186 us, 935 TF]
__global__ __launch_bounds__(256) void k_conv_mfma(
    const unsigned short* __restrict__ Ypad,
    const unsigned short* __restrict__ Wp,
    const float* __restrict__ cb,
    unsigned short* __restrict__ H) {
  __shared__ unsigned short As[2 * 8192];   // 32 KB
  __shared__ unsigned short Bs[2 * 8192];   // 32 KB
  const int bm = blockIdx.x * 128;          // x-fastest: XCD=id%8, A panels L2-hot
  const int bn = blockIdx.y * 128;
  const int b = bm >> 11, t0 = bm & 2047;
  const int tid = threadIdx.x;
  const int lane = tid & 63, wv = tid >> 6;
  const int rsel = lane & 15, ghi = lane >> 4;
  const int l8 = lane >> 3, g8 = lane & 7;
  const int gsrc = (g8 ^ l8) * 8;           // pre-swizzled source granule (shorts)

  f32x4 acc[4][4] = {};

  const size_t arow0 = (size_t)(b * TPAD + t0 + wv * 32 + l8);   // A stage row
  const size_t brow0 = (size_t)(bn + wv * 32 + l8);              // B stage row

#define CONV_STAGE(T, DB)                                                       \
  {                                                                             \
    const int kt_ = (T) * 64;                                                   \
    const int kk_ = kt_ / NC;                                                   \
    const int c0_ = kt_ - kk_ * NC;                                             \
    const size_t asrc_ = (arow0 + kk_) * NC + c0_ + gsrc;                       \
    GLOAD16(Ypad + asrc_, &As[(DB) * 8192 + (wv * 32) * 64]);                   \
    GLOAD16(Ypad + asrc_ + (size_t)8 * NC, &As[(DB) * 8192 + (wv * 32 + 8) * 64]);   \
    GLOAD16(Ypad + asrc_ + (size_t)16 * NC, &As[(DB) * 8192 + (wv * 32 + 16) * 64]); \
    GLOAD16(Ypad + asrc_ + (size_t)24 * NC, &As[(DB) * 8192 + (wv * 32 + 24) * 64]); \
    const size_t bsrc_ = brow0 * NKI + kt_ + gsrc;                              \
    GLOAD16(Wp + bsrc_, &Bs[(DB) * 8192 + (wv * 32) * 64]);                     \
    GLOAD16(Wp + bsrc_ + (size_t)8 * NKI, &Bs[(DB) * 8192 + (wv * 32 + 8) * 64]);    \
    GLOAD16(Wp + bsrc_ + (size_t)16 * NKI, &Bs[(DB) * 8192 + (wv * 32 + 16) * 64]);  \
    GLOAD16(Wp + bsrc_ + (size_t)24 * NKI, &Bs[(DB) * 8192 + (wv * 32 + 24) * 64]);  \
  }

  CONV_STAGE(0, 0);
  CONV_STAGE(1, 1);
  asm volatile("s_waitcnt vmcnt(8)" ::: "memory");
  __builtin_amdgcn_sched_barrier(0);
  __builtin_amdgcn_s_barrier();

  const int arow = (wv >> 1) * 64;
  const int brow = (wv & 1) * 64;
  int db = 0;
  for (int t = 0; t < 54; ++t) {
    bf16x8 af[4][2], bfr[4][2];
#pragma unroll
    for (int m = 0; m < 4; ++m) {
      int r = arow + m * 16 + rsel;
#pragma unroll
      for (int k = 0; k < 2; ++k)
        af[m][k] = *(const bf16x8*)&As[db * 8192 + r * 64 + (((k * 4 + ghi) ^ (r & 7)) * 8)];
    }
#pragma unroll
    for (int n = 0; n < 4; ++n) {
      int r = brow + n * 16 + rsel;
#pragma unroll
      for (int k = 0; k < 2; ++k)
        bfr[n][k] = *(const bf16x8*)&Bs[db * 8192 + r * 64 + (((k * 4 + ghi) ^ (r & 7)) * 8)];
    }
    __builtin_amdgcn_s_setprio(1);
#pragma unroll
    for (int m = 0; m < 4; ++m)
#pragma unroll
      for (int n = 0; n < 4; ++n)
        acc[m][n] = __builtin_amdgcn_mfma_f32_16x16x32_bf16(af[m][0], bfr[n][0], acc[m][n], 0, 0, 0);
    __builtin_amdgcn_s_setprio(0);
    __builtin_amdgcn_sched_barrier(0);
    asm volatile("s_waitcnt lgkmcnt(0)" ::: "memory");
    __builtin_amdgcn_sched_barrier(0);
    __builtin_amdgcn_s_barrier();
    if (t + 2 < 54) CONV_STAGE(t + 2, db);
    __builtin_amdgcn_s_setprio(1);
#pragma unroll
    for (int m = 0; m < 4; ++m)
#pragma unroll
      for (int n = 0; n < 4; ++n)
        acc[m][n] = __builtin_amdgcn_mfma_f32_16x16x32_bf16(af[m][1], bfr[n][1], acc[m][n], 0, 0, 0);
    __builtin_amdgcn_s_setprio(0);
    __builtin_amdgcn_sched_barrier(0);
    if (t + 2 < 54) {
      asm volatile("s_waitcnt vmcnt(8)" ::: "memory");
    } else {
      asm volatile("s_waitcnt vmcnt(0)" ::: "memory");
    }
    __builtin_amdgcn_sched_barrier(0);
    __builtin_amdgcn_s_barrier();
    db ^= 1;
  }
#undef CONV_STAGE

  const int col0 = bn + (wv & 1) * 64 + rsel;
  const int row0 = bm + (wv >> 1) * 64 + ghi * 4;
#pragma unroll
  for (int m = 0; m < 4; ++m) {
#pragma unroll
    for (int n = 0; n < 4; ++n) {
      int col = col0 + n * 16;
      float cbv = cb[col];
#pragma unroll
      for (int r = 0; r < 4; ++r) {
        int row = row0 + m * 16 + r;
        float xv = (acc[m][n][r] + cbv) * 0.33333333333333333f;
        float ge = 0.5f * xv * (1.f + erff(xv * 0.70710678118654752f));
        H[(size_t)row * NF + col] = f2bf(ge);
      }
    }
  }
}

// Windowed cross-attention, MFMA flash-style. bf16 output (feeds o-projection).
__global__ __launch_bounds__(256) void k_attn_mfma(
    const unsigned short* __restrict__ qbb,   // [8*2048][384] bf16 (q*scaling folded in W)
    const unsigned short* __restrict__ kbb,   // [8*512][384] bf16
    const unsigned short* __restrict__ vtb,   // [(b*2+h)*192+d][512] bf16
    unsigned short* __restrict__ o, int guided, float* __restrict__ gl) {
  __shared__ unsigned short lds[32768];
  const int tid = threadIdx.x;
  const int lane = tid & 63, wv = tid >> 6;
  const int rsel = lane & 15, ghi = lane >> 4;
  const int idx = blockIdx.x;
  const int tg = idx & 31;
  const int bh = idx >> 5;
  const int h = bh & 1, b = bh >> 1;
  const int t0 = tg * 64;
  const int c0 = t0 >> 2;
  int klo = c0 - 51; if (klo < 0) klo = 0;
  klo &= ~7;                       // 16B-align for global_load_lds on vtb
  if (klo > 384) klo = 384;        // keep window inside [0,512)

  // Q fragments: A-operand layout, row = lane&15, k = ghi*8 (+32 per step)
  const unsigned short* qrow = qbb + (size_t)(b * NT1 + t0 + wv * 16 + rsel) * NC + h * ND;
  bf16x8 qf[6];
#pragma unroll
  for (int kk = 0; kk < 6; ++kk)
    qf[kk] = *(const bf16x8*)(qrow + kk * 32 + ghi * 8);

  // stage K window [128 keys][192] bf16, source pre-swizzled (granule ^ row&7)
  {
    const size_t kbase = (size_t)(b * NT2 + klo) * NC + h * ND;
#pragma unroll
    for (int it = 0; it < 12; ++it) {
      int g = it * 256 + tid;
      int row = g / 24, go = g % 24;
      int gs = go ^ (row & 7);
      GLOAD16(kbb + kbase + (size_t)row * NC + gs * 8, &lds[(it * 256 + wv * 64) * 8]);
    }
  }
  __syncthreads();

  // QK^T: 16 queries x 128 keys per wave
  f32x4 accs[8] = {};
#pragma unroll
  for (int kk = 0; kk < 6; ++kk) {
#pragma unroll
    for (int n = 0; n < 8; ++n) {
      int row = n * 16 + rsel;
      bf16x8 bfr = *(const bf16x8*)&lds[row * 192 + (((kk * 4 + ghi) ^ (rsel & 7)) * 8)];
      accs[n] = __builtin_amdgcn_mfma_f32_16x16x32_bf16(qf[kk], bfr, accs[n], 0, 0, 0);
    }
  }

  // masked softmax per query row; rows live on 16-lane groups (row=ghi*4+r, col=rsel)
  unsigned short* pl = &lds[24576 + wv * 2048];
  float gacc = 0.f;
  const int t0w = t0 + wv * 16;
#pragma unroll
  for (int r = 0; r < 4; ++r) {
    int t = t0w + ghi * 4 + r;
    int c = t >> 2;
    int loq = c - 51; if (loq < 0) loq = 0;
    int hiq = c + 51; if (hiq > NT2) hiq = NT2;
    float sv[8];
    float mx = -1e30f;
#pragma unroll
    for (int n = 0; n < 8; ++n) {
      int j = klo + n * 16 + rsel;
      float s = (j >= loq && j < hiq) ? accs[n][r] : -1e30f;
      sv[n] = s; mx = fmaxf(mx, s);
    }
#pragma unroll
    for (int off = 1; off < 16; off <<= 1) mx = fmaxf(mx, __shfl_xor(mx, off));
    float e[8]; float se = 0.f;
#pragma unroll
    for (int n = 0; n < 8; ++n) { e[n] = __expf(sv[n] - mx); se += e[n]; }
#pragma unroll
    for (int off = 1; off < 16; off <<= 1) se += __shfl_xor(se, off);
    float inv = 1.f / se;
    int q = ghi * 4 + r;
#pragma unroll
    for (int n = 0; n < 8; ++n) {
      float pv = e[n] * inv;
      int klocal = n * 16 + rsel;
      pl[q * 128 + (((klocal >> 3) ^ (q & 7)) * 8) + (klocal & 7)] = f2bf(pv);
      if (guided) {
        int j = klo + klocal;
        float d = (float)j * (1.f / NT2) - (float)t * (1.f / NT1);
        gacc += pv * (1.f - __expf(-(d * d) * 5.5555555556f));
      }
    }
  }
  if (guided) {
    gacc = warp_sum(gacc);
    if (lane == 0) atomicAdd(gl, gacc * (1.f / 16777216.f));
  }
  __syncthreads();

  // stage VT window [192 chans][128 keys] bf16 into the K buffer (reuse)
  {
    const size_t vbase = ((size_t)(b * 2 + h) * ND) * NT2 + klo;
#pragma unroll
    for (int it = 0; it < 12; ++it) {
      int g = it * 256 + tid;
      int row = g >> 4, go = g & 15;
      int gs = go ^ (row & 7);
      GLOAD16(vtb + vbase + (size_t)row * NT2 + gs * 8, &lds[(it * 256 + wv * 64) * 8]);
    }
  }
  __syncthreads();

  // PV: P[16x128] @ V[128x192] -> O[16x192]
  f32x4 acco[12] = {};
#pragma unroll
  for (int kt = 0; kt < 4; ++kt) {
    bf16x8 pa = *(const bf16x8*)&pl[rsel * 128 + (((kt * 4 + ghi) ^ (rsel & 7)) * 8)];
#pragma unroll
    for (int n = 0; n < 12; ++n) {
      int row = n * 16 + rsel;
      bf16x8 bfr = *(const bf16x8*)&lds[row * 128 + (((kt * 4 + ghi) ^ (rsel & 7)) * 8)];
      acco[n] = __builtin_amdgcn_mfma_f32_16x16x32_bf16(pa, bfr, acco[n], 0, 0, 0);
    }
  }

  unsigned short* obase = o + (size_t)(b * NT1 + t0w + ghi * 4) * NC + h * ND;
#pragma unroll
  for (int n = 0; n < 12; ++n) {
#pragma unroll
    for (int r = 0; r < 4; ++r) {
      obase[(size_t)r * NC + n * 16 + rsel] = f2bf(acco[n][r]);
    }
  }
}

extern "C" void kernel_launch(void* const* d_in, const int* in_sizes, int n_in,
                              void* d_out, int out_size, void* d_ws, size_t ws_size,
                              hipStream_t stream) {
  (void)in_sizes; (void)n_in; (void)out_size; (void)ws_size;
  const float* x1    = (const float*)d_in[0];
  const float* x2    = (const float*)d_in[1];
  const float* alpha = (const float*)d_in[2];
  const float* ln1_g = (const float*)d_in[3];
  const float* ln1_b = (const float*)d_in[4];
  const float* qw    = (const float*)d_in[5];
  const float* kw    = (const float*)d_in[6];
  const float* vw    = (const float*)d_in[7];
  const float* ow    = (const float*)d_in[8];
  const float* ln2_g = (const float*)d_in[9];
  const float* ln2_b = (const float*)d_in[10];
  const float* cw    = (const float*)d_in[11];
  const float* cb    = (const float*)d_in[12];
  const float* lw    = (const float*)d_in[13];
  const float* lb    = (const float*)d_in[14];
  const float* lnf_g = (const float*)d_in[15];
  const float* lnf_b = (const float*)d_in[16];
  float* out = (float*)d_out;
  float* gl = out + 6291456;   // guided-loss scalar slot

  float* p = (float*)d_ws;
  float* x1a = p; p += 6291456;    // x1 state [16384,384] f32
  // bf16 region (16B-aligned)
  unsigned short* us = (unsigned short*)p;
  unsigned short* x2b  = us; us += 1572864;            // x2+pos bf16 [4096][384]
  unsigned short* tmpb = us; us += 6291456;            // LN1 out / attn out bf16
  unsigned short* ypad = us; us += 8 * TPAD * NC;      // 6316032
  unsigned short* cwpb = us; us += 2 * (size_t)NF * NKI;   // 10616832 (both layers)
  unsigned short* lwb  = us; us += 2 * (size_t)NC * NF;    // 1179648 (both layers)
  unsigned short* hb   = us; us += (size_t)16384 * NF; // 25165824
  unsigned short* qbb  = us; us += 6291456;            // q bf16 [16384][384]
  unsigned short* kbb  = us; us += 1572864;            // k bf16 [4096][384]
  unsigned short* vtb  = us; us += 1572864;            // v^T bf16 [32*192][512]
  unsigned short* qwb  = us; us += 294912;             // weights bf16 (contiguous qkvo)
  unsigned short* kwb  = us; us += 294912;
  unsigned short* vwb  = us; us += 294912;
  unsigned short* owb  = us; us += 294912;

  hipMemsetAsync(gl, 0, sizeof(float), stream);  // atomic accumulator, re-zeroed every launch
  k_add_pos2<<<12288, 256, 0, stream>>>(x1, alpha, x1a, NT1, 3145728);
  k_add_pos2_bf16<<<3168, 256, 0, stream>>>(x2, alpha, x2b, NT2, 786432, ypad);

  const float scaling = 0.07216878364870323f;   // 192^-0.5
  // weight conversions, both layers, hoisted + fused into 2 launches
  k_cvt_all<<<9216, 256, 0, stream>>>(qw, kw, vw, ow, lw, qwb, lwb, scaling);
  k_pack_cw2<<<3072, 256, 0, stream>>>(cw, cwpb);

  for (int l = 0; l < 2; ++l) {
    k_ln_bf16<<<4096, 256, 0, stream>>>(x1a, ln1_g + l * 384, ln1_b + l * 384, tmpb);
    k_pgemm_qkv<<<dim3(4, 192), 256, 0, stream>>>(tmpb, x2b,
        qwb + (size_t)l * 147456, kwb + (size_t)l * 147456, vwb + (size_t)l * 147456,
        qbb, kbb, vtb);
    k_attn_mfma<<<512, 256, 0, stream>>>(qbb, kbb, vtb, tmpb, l == 0 ? 1 : 0, gl);
    k_pgemm_o<<<dim3(4, 128), 256, 0, stream>>>(tmpb, owb + (size_t)l * 147456, x1a);
    // FFN: ln2 -> bf16 padded, conv implicit GEMM (128² dbuf, 2/CU), linear (96-N split)
    k_ln_bf16p<<<4096, 256, 0, stream>>>(x1a, ln2_g + l * 384, ln2_b + l * 384, ypad);
    k_conv_mfma<<<dim3(128, 12), 256, 0, stream>>>(ypad, cwpb + (size_t)l * 5308416, cb + l * 1536, hb);
    k_lin_mfma<<<dim3(4, 128), 256, 0, stream>>>(hb, lwb + (size_t)l * 589824, lb + l * 384, x1a);
  }
  k_ln<<<4096, 256, 0, stream>>>(x1a, lnf_g, lnf_b, out, 16384);
}